// Round 6
// baseline (630.989 us; speedup 1.0000x reference)
//
#include <hip/hip_runtime.h>
#include <math.h>

#define B_ 4
#define NTOK 6273
#define DIMD 768
#define HEADS 8
#define HD 96
#define NPOOL 1569
#define NPAD 1600
#define HID 3072
#define MROWS (B_*NTOK)   // 25092
#define M2 (B_*NPOOL)     // 6276
#define SCALE_ 0.10206207261596575f

typedef float f32x4 __attribute__((ext_vector_type(4)));
typedef short s16x8 __attribute__((ext_vector_type(8)));
typedef short s16x4 __attribute__((ext_vector_type(4)));
typedef unsigned u32x3 __attribute__((ext_vector_type(3)));

__device__ __forceinline__ short f2bf(float f){
  unsigned u = __builtin_bit_cast(unsigned, f);
  u = (u + 0x7fffu + ((u >> 16) & 1u)) >> 16;
  return (short)u;
}
__device__ __forceinline__ float bf2f(short s){
  unsigned u = ((unsigned)(unsigned short)s) << 16;
  return __builtin_bit_cast(float, u);
}
__device__ __forceinline__ float bfsel(unsigned u, int hi){
  unsigned r = hi ? (u & 0xffff0000u) : (u << 16);
  return __builtin_bit_cast(float, r);
}
__device__ __forceinline__ unsigned pack2(float lo, float hi){
  return (unsigned)(unsigned short)f2bf(lo) | ((unsigned)(unsigned short)f2bf(hi) << 16);
}

__device__ __forceinline__ void gld16(const void* g, void* l){
  __builtin_amdgcn_global_load_lds((const __attribute__((address_space(1))) unsigned*)g,
                                   (__attribute__((address_space(3))) unsigned*)l, 16, 0, 0);
}

#if defined(__has_builtin)
#if __has_builtin(__builtin_amdgcn_mfma_f32_16x16x16bf16_1k)
#define MFMA16K(a,b,c) __builtin_amdgcn_mfma_f32_16x16x16bf16_1k(a,b,c,0,0,0)
#endif
#endif
#ifndef MFMA16K
__device__ __forceinline__ f32x4 mfma16k_asm(s16x4 a, s16x4 b, f32x4 c){
  asm volatile("v_mfma_f32_16x16x16_bf16 %0, %1, %2, %0\n\ts_nop 7\n\ts_nop 7"
               : "+v"(c) : "v"(a), "v"(b));
  return c;
}
#define MFMA16K(a,b,c) mfma16k_asm(a,b,c)
#endif

template<int NT>
__device__ __forceinline__ float block_sum(float v, float* red){
  int t = threadIdx.x;
  red[t] = v; __syncthreads();
  #pragma unroll
  for (int s = NT/2; s > 0; s >>= 1){
    if (t < s) red[t] += red[t+s];
    __syncthreads();
  }
  float r = red[0];
  __syncthreads();
  return r;
}

// ---- XCD-chunked serial (m204 bijection): contiguous serial range per XCD ----
__device__ __forceinline__ unsigned xcd_serial(unsigned bid, unsigned nwg){
  unsigned q = nwg >> 3, r8 = nwg & 7;
  unsigned xcd = bid & 7, idx = bid >> 3;
  return (xcd < r8 ? xcd*(q+1) : r8*(q+1) + (xcd-r8)*q) + idx;
}

// supertile decode: STR x STC tiles per supertile, row-fast within col.
template<int STR, int STC>
__device__ __forceinline__ void tile_decode(unsigned serial, int& rowT, int& colT){
  const int nStC = (int)gridDim.x / STC;
  int st = (int)serial / (STR*STC);
  int t  = (int)serial - st*(STR*STC);
  int stR = st / nStC, stC = st - stR*nStC;
  int c = t / STR, r = t - c*STR;
  rowT = stR*STR + r;
  colT = stC*STC + c;
}

// ---- cast 6 weight matrices fp32 -> bf16 ----
__global__ void castw(const float* s0,const float* s1,const float* s2,const float* s3,
                      const float* s4,const float* s5,
                      short* d0,short* d1,short* d2,short* d3,short* d4,short* d5){
  const float* s; short* d; int n;
  switch(blockIdx.y){
    case 0: s=s0; d=d0; n=589824; break;
    case 1: s=s1; d=d1; n=589824; break;
    case 2: s=s2; d=d2; n=589824; break;
    case 3: s=s3; d=d3; n=589824; break;
    case 4: s=s4; d=d4; n=2359296; break;
    default: s=s5; d=d5; n=2359296; break;
  }
  for (int i = blockIdx.x*blockDim.x + threadIdx.x; i < n; i += gridDim.x*blockDim.x)
    d[i] = f2bf(s[i]);
}

// ---- pack 3 bias vectors into one contiguous [2304] buffer ----
__global__ __launch_bounds__(256) void packb(const float* b0, const float* b1, const float* b2, float* o){
  int i = blockIdx.x*256 + threadIdx.x;   // 9 blocks -> 2304
  if (i < 768) o[i] = b0[i];
  else if (i < 1536) o[i] = b1[i-768];
  else if (i < 2304) o[i] = b2[i-1536];
}

// ---- LayerNorm over 768, wave-per-row (4 rows/block): zero LDS, zero barriers ----
__global__ __launch_bounds__(256) void ln768(const float* __restrict__ x, const float* __restrict__ w,
                      const float* __restrict__ b, short* __restrict__ out){
  int row = blockIdx.x*4 + (threadIdx.x >> 6);
  int lane = threadIdx.x & 63;
  const float* xr = x + (size_t)row*DIMD + lane*12;
  f32x4 v0 = *(const f32x4*)(xr);
  f32x4 v1 = *(const f32x4*)(xr + 4);
  f32x4 v2 = *(const f32x4*)(xr + 8);
  float v[12] = { v0[0],v0[1],v0[2],v0[3], v1[0],v1[1],v1[2],v1[3], v2[0],v2[1],v2[2],v2[3] };
  float s = 0.f;
  #pragma unroll
  for (int j=0;j<12;j++) s += v[j];
  #pragma unroll
  for (int m=1; m<64; m<<=1) s += __shfl_xor(s, m);
  float mu = s * (1.f/768.f);
  float sq = 0.f;
  #pragma unroll
  for (int j=0;j<12;j++){ float d = v[j]-mu; sq += d*d; }
  #pragma unroll
  for (int m=1; m<64; m<<=1) sq += __shfl_xor(sq, m);
  float rstd = rsqrtf(sq*(1.f/768.f) + 1e-5f);
  int c0 = lane*12;
  float o[12];
  #pragma unroll
  for (int j=0;j<12;j++) o[j] = (v[j]-mu)*rstd*w[c0+j] + b[c0+j];
  unsigned* po = (unsigned*)(out + (size_t)row*DIMD + c0);
  #pragma unroll
  for (int k=0;k<6;k++) po[k] = pack2(o[2*k], o[2*k+1]);
}

// ---- 8-phase helpers (compile-time indices only; rule #20) ----
template<int MH>
__device__ __forceinline__ void ld_af(s16x8 (&af)[4][2], const short* lA, int lane){
  #pragma unroll
  for (int m2=0;m2<4;m2++)
    #pragma unroll
    for (int ks=0;ks<2;ks++)
      af[m2][ks] = *(const s16x8*)(lA + ((MH*4+m2)*2+ks)*512 + lane*8);
}
template<int NH>
__device__ __forceinline__ void ld_bf(s16x8 (&bf)[2][2], const short* lB, int wc1, int lane){
  #pragma unroll
  for (int n2=0;n2<2;n2++)
    #pragma unroll
    for (int ks=0;ks<2;ks++)
      bf[n2][ks] = *(const s16x8*)(lB + ((wc1*4+NH*2+n2)*2+ks)*512 + lane*8);
}
template<int MH,int NH>
__device__ __forceinline__ void mm_phase(f32x4 (&acc)[2][2][4][2], const s16x8 (&af)[4][2], const s16x8 (&bf)[2][2]){
  asm volatile("s_waitcnt lgkmcnt(0)" ::: "memory");
  __builtin_amdgcn_sched_barrier(0);       // rule #18: keep MFMA below the lgkmcnt
  __builtin_amdgcn_s_setprio(1);
  #pragma unroll
  for (int m2=0;m2<4;m2++)
    #pragma unroll
    for (int n2=0;n2<2;n2++)
      #pragma unroll
      for (int ks=0;ks<2;ks++)
        acc[MH][NH][m2][n2] = __builtin_amdgcn_mfma_f32_16x16x32_bf16(af[m2][ks], bf[n2][ks], acc[MH][NH][m2][n2], 0,0,0);
  __builtin_amdgcn_s_setprio(0);
}

// ================= 256x256 GEMM, 8 waves, 8-PHASE schedule (T3+T4 port) ==================
// R5 post-mortem: the BK32 depth-3 loop lands at exactly the catalog's 2-phase-class level
// (612 TF ~ m233's 607). This is the m201-style 8-phase: 2 K-tiles/iter, quadrant order
// (m0n0,m0n1,m1n1,m1n0) for register reuse, ONE half-tile staged per phase in last-read
// order, vmcnt(2) only at phases 4/8 (no mid-loop drain), double-barrier MFMA clusters
// with setprio. Stage targets verified disjoint from each phase's reads; every half lands
// (vmcnt+barrier) before its next read. LDS: [buf:2][A0,A1,B0,B1][16KB] = 128KB.
__global__ __launch_bounds__(512) void gemm8(const short* __restrict__ A, const short* __restrict__ Bw,
                        const float* __restrict__ bias, short* __restrict__ Cb,
                        int M, int N, int K){   // K == 768
  __shared__ short lds[65536];
  int tid = threadIdx.x;
  int w = tid >> 6, lane = tid & 63;
  int l15 = lane & 15, g = (lane >> 4) & 3;
  int wr = w >> 2, wc = w & 3, wc1 = wc & 1;

  unsigned nwg = gridDim.x * gridDim.y;
  unsigned bid = blockIdx.y * gridDim.x + blockIdx.x;
  unsigned serial = bid;
  if (nwg >= 512) serial = xcd_serial(bid, nwg);
  int rowBase = (int)(serial / gridDim.x) * 256;
  int colBase = (int)(serial % gridDim.x) * 256;

  // staging sources: half h (128 rows/cols), chunk c; frag block fb=(c*8+w)>>1, ks=(c*8+w)&1
  const short* pa[2][2]; const short* pb[2][2];
  #pragma unroll
  for (int h=0;h<2;h++){
    #pragma unroll
    for (int c=0;c<2;c++){
      int fw = c*8 + w;
      int fb = fw >> 1, ks = fw & 1;
      int mr = rowBase + h*128 + fb*16 + l15; if (mr >= M) mr = M-1;
      int nr = colBase + h*128 + fb*16 + l15;     // N multiple of 256
      pa[h][c] = A  + (size_t)mr*K + ks*32 + g*8;
      pb[h][c] = Bw + (size_t)nr*K + ks*32 + g*8;
    }
  }

  // half slots: A0=0 A1=1 B0=2 B1=3 ; one half-tile = 2 gld16/thread (16KB)
  auto stageA = [&](int buf, int h, int kt){
    short* dst = &lds[buf*32768 + h*8192 + tid*8];
    gld16(pa[h][0] + kt*64, dst);
    gld16(pa[h][1] + kt*64, dst + 4096);
  };
  auto stageB = [&](int buf, int h, int kt){
    short* dst = &lds[buf*32768 + (2+h)*8192 + tid*8];
    gld16(pb[h][0] + kt*64, dst);
    gld16(pb[h][1] + kt*64, dst + 4096);
  };

  f32x4 acc[2][2][4][2] = {};
  s16x8 af[4][2], bf[2][2];

  // per-wave LDS read bases (this wave's A-half and B-half within each buffer)
  const short* lAx = &lds[wr*8192];
  const short* lBx = &lds[16384 + (wc>>1)*8192];
  const short* lAy = lAx + 32768;
  const short* lBy = lBx + 32768;

  // prologue: X(kt0) all 4 halves + Y(kt1).A0 ; keep Y.A0 (2 loads) in flight
  stageA(0,0,0); stageA(0,1,0); stageB(0,0,0); stageB(0,1,0);
  stageA(1,0,1);
  asm volatile("s_waitcnt vmcnt(2)" ::: "memory");
  __builtin_amdgcn_s_barrier();

  // K = 768 -> 12 K-tiles -> 6 iterations of (kx=2i in buf0, ky=2i+1 in buf1)
  for (int i = 0; i < 6; i++){
    int kx = 2*i;
    const bool full = (i < 5);

    // ph1: X q(m0,n0); stage Y[kx+1].A1
    ld_af<0>(af, lAx, lane); ld_bf<0>(bf, lBx, wc1, lane);
    stageA(1,1,kx+1);
    __builtin_amdgcn_s_barrier();
    mm_phase<0,0>(acc, af, bf);
    __builtin_amdgcn_s_barrier();
    // ph2: X q(m0,n1); stage Y.B0   (af(m0) reused from regs)
    ld_bf<1>(bf, lBx, wc1, lane);
    stageB(1,0,kx+1);
    __builtin_amdgcn_s_barrier();
    mm_phase<0,1>(acc, af, bf);
    __builtin_amdgcn_s_barrier();
    // ph3: X q(m1,n1); stage Y.B1   (bf(n1) reused)
    ld_af<1>(af, lAx, lane);
    stageB(1,1,kx+1);
    __builtin_amdgcn_s_barrier();
    mm_phase<1,1>(acc, af, bf);
    __builtin_amdgcn_s_barrier();
    // ph4: X q(m1,n0); stage X'[kx+2].A0; vmcnt(2) -> all Y[kx+1] halves landed before ph5
    ld_bf<0>(bf, lBx, wc1, lane);
    if (full){ stageA(0,0,kx+2); asm volatile("s_waitcnt vmcnt(2)" ::: "memory"); }
    else     { asm volatile("s_waitcnt vmcnt(0)" ::: "memory"); }
    __builtin_amdgcn_s_barrier();
    mm_phase<1,0>(acc, af, bf);
    __builtin_amdgcn_s_barrier();
    // ph5: Y q(m0,n0); stage X'.A1
    ld_af<0>(af, lAy, lane); ld_bf<0>(bf, lBy, wc1, lane);
    if (full) stageA(0,1,kx+2);
    __builtin_amdgcn_s_barrier();
    mm_phase<0,0>(acc, af, bf);
    __builtin_amdgcn_s_barrier();
    // ph6: Y q(m0,n1); stage X'.B0
    ld_bf<1>(bf, lBy, wc1, lane);
    if (full) stageB(0,0,kx+2);
    __builtin_amdgcn_s_barrier();
    mm_phase<0,1>(acc, af, bf);
    __builtin_amdgcn_s_barrier();
    // ph7: Y q(m1,n1); stage X'.B1
    ld_af<1>(af, lAy, lane);
    if (full) stageB(0,1,kx+2);
    __builtin_amdgcn_s_barrier();
    mm_phase<1,1>(acc, af, bf);
    __builtin_amdgcn_s_barrier();
    // ph8: Y q(m1,n0); stage Y'[kx+3].A0; vmcnt(2) -> all X'[kx+2] landed before next ph1
    ld_bf<0>(bf, lBy, wc1, lane);
    if (full){ stageA(1,0,kx+3); asm volatile("s_waitcnt vmcnt(2)" ::: "memory"); }
    __builtin_amdgcn_s_barrier();
    mm_phase<1,0>(acc, af, bf);
    __builtin_amdgcn_s_barrier();
  }

  // ---- wide epilogue: reuse full 128KB as C tile (no DMA outstanding; lgkm waited) ----
  __syncthreads();
  short* ldsC = &lds[0];   // 65536 shorts; row = 256 shorts (512B), chunk = 8 shorts (16B)
  #pragma unroll
  for (int mh=0; mh<2; mh++){
    #pragma unroll
    for (int m2=0; m2<4; m2++){
      int rowL0 = wr*128 + mh*64 + m2*16 + g*4;
      #pragma unroll
      for (int nh=0; nh<2; nh++){
        #pragma unroll
        for (int n2=0; n2<2; n2++){
          int colL = wc*64 + nh*32 + n2*16 + l15;
          float bv = bias[colBase + colL];
          int ch = colL >> 3, in8 = colL & 7;
          #pragma unroll
          for (int r=0;r<4;r++){
            int rL = rowL0 + r;
            int chs = ch ^ ((rL >> 2) & 7);
            ldsC[rL*256 + chs*8 + in8] = f2bf(acc[mh][nh][m2][n2][r] + bv);
          }
        }
      }
    }
  }
  __syncthreads();
  int ch2 = tid & 31, rg = tid >> 5;   // 32 chunks/row; 16 rows per pass
  #pragma unroll
  for (int i=0;i<16;i++){
    int rowL = rg + i*16;
    int chs = ch2 ^ ((rowL >> 2) & 7);
    s16x8 v = *(const s16x8*)(ldsC + rowL*256 + chs*8);
    int rr = rowBase + rowL;
    if (rr < M) *(s16x8*)(Cb + (size_t)rr*N + colBase + ch2*8) = v;
  }
}

// ---- bf16 GEMM, 2-phase 128x128 (proven m97 structure): proj, fc1, fc2.
// bf16 outputs via R4 wide LDS-transposed epilogue.
template<int GELU, int OUTBF16, int RESID, int STR, int STC>
__global__ __launch_bounds__(256) void gemm_bt(const short* __restrict__ A, const short* __restrict__ Bw,
                        const float* __restrict__ bias, const float* __restrict__ resid,
                        float* __restrict__ Cf, short* __restrict__ Cb,
                        int M, int N, int K){
  __shared__ short lds[3][8192];   // [buf][ A:0..4095 | B:4096..8191 ]; epilogue reuses 32KB as C tile
  int tid = threadIdx.x;
  int lane = tid & 63, wv = tid >> 6;
  int wr = wv >> 1, wc = wv & 1;
  int l15 = lane & 15, g = lane >> 4;

  unsigned nwg = gridDim.x * gridDim.y;
  unsigned bid = blockIdx.y * gridDim.x + blockIdx.x;
  unsigned serial = xcd_serial(bid, nwg);
  int rowT, colT;
  tile_decode<STR,STC>(serial, rowT, colT);
  int rowBase = rowT * 128;
  int colBase = colT * 128;

  f32x4 acc[4][4] = {};
  int srow = (tid & 15) | ((tid >> 6) << 4);   // 0..63
  int scol = ((tid >> 4) & 3) * 8;
  int ldsoff = tid * 8;

  int ar0 = rowBase + srow;      if (ar0 >= M) ar0 = M-1;
  int ar1 = rowBase + srow + 64; if (ar1 >= M) ar1 = M-1;
  int br0 = colBase + srow;      // N always multiple of 128
  const short* pa0 = A  + (size_t)ar0*K + scol;
  const short* pa1 = A  + (size_t)ar1*K + scol;
  const short* pb0 = Bw + (size_t)br0*K + scol;
  const short* pb1 = Bw + (size_t)(br0+64)*K + scol;

  auto stage = [&](int s, int kt){
    gld16(pa0 + kt, &lds[s][ldsoff]);
    gld16(pa1 + kt, &lds[s][ldsoff + 2048]);
    gld16(pb0 + kt, &lds[s][4096 + ldsoff]);
    gld16(pb1 + kt, &lds[s][4096 + ldsoff + 2048]);
  };

  int nk = K >> 5;
  stage(0, 0);
  if (nk > 1) stage(1, 32);
  for (int kt = 0; kt < nk; kt++){
    int cur = kt % 3;
    if (kt + 2 < nk){
      stage((kt+2)%3, (kt+2)*32);
      asm volatile("s_waitcnt vmcnt(8)" ::: "memory");
    } else if (kt + 1 < nk){
      asm volatile("s_waitcnt vmcnt(4)" ::: "memory");
    } else {
      asm volatile("s_waitcnt vmcnt(0)" ::: "memory");
    }
    __builtin_amdgcn_s_barrier();
    const short* la = lds[cur];
    const short* lb = lds[cur] + 4096;
    s16x8 af[4], bfr[4];
    #pragma unroll
    for (int m=0;m<4;m++) af[m]  = *(const s16x8*)(la + (wr*4 + m)*512 + g*128 + l15*8);
    #pragma unroll
    for (int n=0;n<4;n++) bfr[n] = *(const s16x8*)(lb + (wc*4 + n)*512 + g*128 + l15*8);
    #pragma unroll
    for (int m=0;m<4;m++)
      #pragma unroll
      for (int n=0;n<4;n++)
        acc[m][n] = __builtin_amdgcn_mfma_f32_16x16x32_bf16(af[m], bfr[n], acc[m][n], 0,0,0);
    __builtin_amdgcn_s_barrier();
  }

  if (OUTBF16){
    short* ldsC = &lds[0][0];
    #pragma unroll
    for (int n=0;n<4;n++){
      int colL = wc*64 + n*16 + l15;
      float bv = bias[colBase + colL];
      #pragma unroll
      for (int m=0;m<4;m++){
        #pragma unroll
        for (int r=0;r<4;r++){
          int rowL = wr*64 + m*16 + g*4 + r;
          float v = acc[m][n][r] + bv;
          if (GELU) v = 0.5f*v*(1.f + erff(v*0.70710678118654752f));
          int ch = colL >> 3, in8 = colL & 7;
          int chs = ch ^ (((rowL >> 2) & 3) << 2);
          ldsC[rowL*128 + chs*8 + in8] = f2bf(v);
        }
      }
    }
    __syncthreads();
    int ch = tid & 15, rg = tid >> 4;
    #pragma unroll
    for (int i=0;i<8;i++){
      int rowL = rg + i*16;
      int chs = ch ^ (((rowL >> 2) & 3) << 2);
      s16x8 v = *(const s16x8*)(ldsC + rowL*128 + chs*8);
      int rr = rowBase + rowL;
      if (rr < M) *(s16x8*)(Cb + (size_t)rr*N + colBase + ch*8) = v;
    }
  } else {
    #pragma unroll
    for (int m=0;m<4;m++){
      int row = rowBase + wr*64 + m*16 + g*4;
      #pragma unroll
      for (int n=0;n<4;n++){
        int col = colBase + wc*64 + n*16 + l15;
        float bv = bias[col];
        #pragma unroll
        for (int r=0;r<4;r++){
          int rr = row + r;
          if (rr < M){
            float v = acc[m][n][r] + bv;
            if (GELU) v = 0.5f*v*(1.f + erff(v*0.70710678118654752f));
            if (RESID) v += resid[(size_t)rr*N + col];
            Cf[(size_t)rr*N + col] = v;
          }
        }
      }
    }
  }
}

// ---- fused attention pooling conv for q,k,v (one launch) + LN over 96.
// Reads the LINEAR qkv buffer [b*NTOK+tok][2304] (col = z*768 + h*96 + d).
__global__ __launch_bounds__(256, 2) void pool_conv3(
    const short* __restrict__ raw,
    const float* __restrict__ cwq, const float* __restrict__ cwk, const float* __restrict__ cwv,
    const float* __restrict__ nqw, const float* __restrict__ nqb,
    const float* __restrict__ nkw, const float* __restrict__ nkb,
    const float* __restrict__ nvw, const float* __restrict__ nvb,
    short* __restrict__ qo, short* __restrict__ ko, short* __restrict__ vo){
  unsigned nwg = gridDim.x * gridDim.y * gridDim.z;   // 1344
  unsigned lin = (blockIdx.z*gridDim.y + blockIdx.y)*gridDim.x + blockIdx.x;
  unsigned serial = xcd_serial(lin, nwg);
  int ho = (int)(serial % 14);
  unsigned rest = serial / 14;
  int bh = (int)(rest & 31);
  int z  = (int)(rest >> 5);
  int t = threadIdx.x;
  int g = t >> 4;        // wo
  if (g >= 14) return;
  int s = t & 15, d = s*6;
  const float* cw = (z==0) ? cwq : (z==1) ? cwk : cwv;
  const float* nw = (z==0) ? nqw : (z==1) ? nkw : nvw;
  const float* nb = (z==0) ? nqb : (z==1) ? nkb : nvb;
  const short* base = raw + (size_t)(bh>>3)*NTOK*2304 + z*768 + (bh&7)*96 + d;
  float acc[8][6] = {};
  #pragma unroll
  for (int dh=0; dh<3; dh++){
    int ih = 2*ho - 1 + dh;
    if (ih < 0 || ih >= 28) continue;
    #pragma unroll
    for (int dw=0; dw<3; dw++){
      int iw = 2*g - 1 + dw;
      if (iw < 0 || iw >= 28) continue;
      float w[3][6];
      #pragma unroll
      for (int dt=0; dt<3; dt++)
        #pragma unroll
        for (int j=0;j<6;j++)
          w[dt][j] = cw[(d+j)*27 + dt*9 + dh*3 + dw];
      #pragma unroll
      for (int it=0; it<8; it++){
        u32x3 u = *(const u32x3*)(base + (size_t)(1 + (it*28+ih)*28 + iw)*2304);
        float in[6] = { bfsel(u[0],0), bfsel(u[0],1), bfsel(u[1],0),
                        bfsel(u[1],1), bfsel(u[2],0), bfsel(u[2],1) };
        #pragma unroll
        for (int dt=0; dt<3; dt++){
          int to = it + 1 - dt;                // compile-time per unrolled iter
          if (to < 0 || to > 7) continue;
          #pragma unroll
          for (int j=0;j<6;j++) acc[to][j] = fmaf(in[j], w[dt][j], acc[to][j]);
        }
      }
    }
  }
  float nwv[6], nbv[6];
  #pragma unroll
  for (int j=0;j<6;j++){ nwv[j] = nw[d+j]; nbv[j] = nb[d+j]; }
  #pragma unroll
  for (int to=0; to<8; to++){
    float sm = acc[to][0]+acc[to][1]+acc[to][2]+acc[to][3]+acc[to][4]+acc[to][5];
    #pragma unroll
    for (int m=1; m<16; m<<=1) sm += __shfl_xor(sm, m);
    float mu = sm*(1.f/96.f);
    float vr = 0.f;
    #pragma unroll
    for (int j=0;j<6;j++){ float dd = acc[to][j]-mu; vr += dd*dd; }
    #pragma unroll
    for (int m=1; m<16; m<<=1) vr += __shfl_xor(vr, m);
    float rstd = rsqrtf(vr*(1.f/96.f) + 1e-5f);
    int tok = 1 + to*196 + ho*14 + g;
    if (z == 0){
      short o[6];
      #pragma unroll
      for (int j=0;j<6;j++) o[j] = f2bf((acc[to][j]-mu)*rstd*nwv[j] + nbv[j]);
      unsigned* q32 = (unsigned*)(qo + ((size_t)bh*NPAD + tok)*96 + d);
      #pragma unroll
      for (int w2=0; w2<3; w2++)
        q32[w2] = (unsigned)(unsigned short)o[2*w2] | ((unsigned)(unsigned short)o[2*w2+1] << 16);
    } else if (z == 1){
      size_t kb = (size_t)bh*NPAD*96 + (size_t)(tok>>4)*1536 + (tok&15)*8;
      #pragma unroll
      for (int j=0;j<6;j++){
        int dj = d + j;
        ko[kb + (dj>>5)*512 + ((dj>>3)&3)*128 + (dj&7)] = f2bf((acc[to][j]-mu)*rstd*nwv[j] + nbv[j]);
      }
    } else {
      size_t vb = (size_t)bh*NPAD*96 + (size_t)(tok>>6)*6144 + ((tok>>4)&3)*256 + ((tok>>2)&3)*64 + (tok&3);
      #pragma unroll
      for (int j=0;j<6;j++){
        int dj = d + j;
        vo[vb + (dj>>4)*1024 + (dj&15)*4] = f2bf((acc[to][j]-mu)*rstd*nwv[j] + nbv[j]);
      }
    }
  }
}

// ---- cls token (tok=0): LN of linear-qkv row 0 for q,k,v; 4 blocks x 128 threads ----
__global__ __launch_bounds__(128) void cls3(
    const short* __restrict__ raw,
    const float* __restrict__ nqw, const float* __restrict__ nqb,
    const float* __restrict__ nkw, const float* __restrict__ nkb,
    const float* __restrict__ nvw, const float* __restrict__ nvb,
    short* __restrict__ qo, short* __restrict__ ko, short* __restrict__ vo){
  int b = blockIdx.x, t = threadIdx.x;
  int h = t >> 4, s = t & 15, d = s*6;
  int bh = b*8 + h;
  const float* nws[3] = { nqw, nkw, nvw };
  const float* nbs[3] = { nqb, nkb, nvb };
  #pragma unroll
  for (int ten=0; ten<3; ten++){
    const short* row = raw + (size_t)b*NTOK*2304 + ten*768 + h*96 + d;
    u32x3 u = *(const u32x3*)(row);
    float a[6] = { bfsel(u[0],0), bfsel(u[0],1), bfsel(u[1],0), bfsel(u[1],1), bfsel(u[2],0), bfsel(u[2],1) };
    float sm = a[0]+a[1]+a[2]+a[3]+a[4]+a[5];
    #pragma unroll
    for (int m=1; m<16; m<<=1) sm += __shfl_xor(sm, m);
    float mu = sm*(1.f/96.f);
    float vr2 = 0.f;
    #pragma unroll
    for (int j=0;j<6;j++){ float dd = a[j]-mu; vr2 += dd*dd; }
    #pragma unroll
    for (int m=1; m<16; m<<=1) vr2 += __shfl_xor(vr2, m);
    float rstd = rsqrtf(vr2*(1.f/96.f) + 1e-5f);
    #pragma unroll
    for (int j=0;j<6;j++){
      int dj = d + j;
      short o = f2bf((a[j]-mu)*rstd*nws[ten][dj] + nbs[ten][dj]);
      if (ten == 0)      qo[((size_t)bh*NPAD)*96 + dj] = o;
      else if (ten == 1) ko[(size_t)bh*NPAD*96 + (dj>>5)*512 + ((dj>>3)&3)*128 + (dj&7)] = o;
      else               vo[(size_t)bh*NPAD*96 + (dj>>4)*1024 + (dj&15)*4] = o;
    }
  }
}

// ---- zero-fill padded tokens NPOOL..NPAD-1 in all three layouts ----
__global__ __launch_bounds__(96) void padfill(short* __restrict__ qo, short* __restrict__ ko, short* __restrict__ vo){
  int tok = NPOOL + blockIdx.x;   // 31 blocks
  int bh = blockIdx.y;
  int d = threadIdx.x;            // 96
  qo[((size_t)bh*NPAD + tok)*96 + d] = 0;
  size_t kb = (size_t)bh*NPAD*96 + (size_t)(tok>>4)*1536 + (tok&15)*8;
  ko[kb + (d>>5)*512 + ((d>>3)&3)*128 + (d&7)] = 0;
  size_t vb = (size_t)bh*NPAD*96 + (size_t)(tok>>6)*6144 + ((tok>>4)&3)*256 + ((tok>>2)&3)*64 + (tok&3);
  vo[vb + (d>>4)*1024 + (d&15)*4] = 0;
}

// ---- flash attention, 8 waves/block (128 q-rows).
// XCD mapping: bh-major chunks -> each XCD owns exactly 4 bh; K/V L2-resident.
__global__ __launch_bounds__(512) void attn_k(const short* __restrict__ qp, const short* __restrict__ kp,
                       const short* __restrict__ vp, short* __restrict__ oattn){
  const float M0 = 6.0f;
  __shared__ short lkv[2][12288];   // [buf][ K:0..6143 | V:6144..12287 ]
  unsigned nwg = gridDim.x * gridDim.y;   // 13*32 = 416
  unsigned bid0 = blockIdx.y * gridDim.x + blockIdx.x;
  unsigned serial = xcd_serial(bid0, nwg);
  int bh = (int)(serial / 13);
  int qblk = (int)(serial - (unsigned)bh*13);
  int b = bh >> 3, h = bh & 7;
  int tid = threadIdx.x;
  int lane = tid & 63, wv = tid >> 6;
  int l15 = lane & 15, g = lane >> 4;
  int qi = qblk*128 + wv*16 + l15;
  int qi_ld = qi < NPAD ? qi : NPAD-1;        // clamp; pad rows are zeroed, writes masked below
  const short* qbase = qp + (size_t)bh*NPAD*HD;
  const short* kbase = kp + (size_t)bh*NPAD*HD;
  const short* vbase = vp + (size_t)bh*NPAD*HD;
  s16x8 qf[3];
  #pragma unroll
  for (int f=0; f<3; f++)
    qf[f] = *(const s16x8*)(qbase + (size_t)qi_ld*HD + f*32 + g*8);

  // stage chunk t: 12288 shorts (K 6144 | V 6144); 512 threads x 3 gld16, wave-uniform K/V branch
  auto stage = [&](int bsel, int t){
    #pragma unroll
    for (int i=0;i<3;i++){
      int off = i*4096 + tid*8;
      const short* src = (off < 6144) ? (kbase + t*6144 + off) : (vbase + t*6144 + off - 6144);
      gld16(src, &lkv[bsel][off]);
    }
  };

  f32x4 accO[6] = {};
  float tsum = 0.f;

  stage(0, 0);
  asm volatile("s_waitcnt vmcnt(0)" ::: "memory");
  __builtin_amdgcn_s_barrier();

  for (int kt = 0; kt < 25; kt++){
    int cur = kt & 1;
    if (kt < 24){
      stage(cur^1, kt+1);
      asm volatile("s_waitcnt vmcnt(3)" ::: "memory");   // current chunk done; next 3 in flight
    } else {
      asm volatile("s_waitcnt vmcnt(0)" ::: "memory");
    }
    __builtin_amdgcn_s_barrier();

    const short* lkc = &lkv[cur][0];
    const short* lvc = &lkv[cur][6144];
    f32x4 sacc[4];
    #pragma unroll
    for (int sub=0; sub<4; sub++){
      sacc[sub] = (f32x4){0.f,0.f,0.f,0.f};
      #pragma unroll
      for (int f=0; f<3; f++){
        s16x8 kf = *(const s16x8*)(lkc + sub*1536 + f*512 + lane*8);
        sacc[sub] = __builtin_amdgcn_mfma_f32_16x16x32_bf16(kf, qf[f], sacc[sub], 0,0,0);
      }
    }
    s16x4 pf[4];
    if (kt < 24){
      #pragma unroll
      for (int sub=0; sub<4; sub++){
        #pragma unroll
        for (int r=0; r<4; r++){
          float p = __expf(sacc[sub][r]*SCALE_ - M0);
          tsum += p;
          pf[sub][r] = f2bf(p);
        }
      }
    } else {
      #pragma unroll
      for (int sub=0; sub<4; sub++){
        #pragma unroll
        for (int r=0; r<4; r++){
          int ki = kt*64 + sub*16 + g*4 + r;
          float p = (ki < NPOOL) ? __expf(sacc[sub][r]*SCALE_ - M0) : 0.f;
          tsum += p;
          pf[sub][r] = f2bf(p);
        }
      }
    }
    #pragma unroll
    for (int dt=0; dt<6; dt++){
      #pragma unroll
      for (int sub=0; sub<4; sub++){
        s16x4 vf = *(const s16x4*)(lvc + dt*1024 + sub*256 + lane*4);
        accO[dt] = MFMA16K(vf, pf[sub], accO[dt]);
      }
    }
    __builtin_amdgcn_s_barrier();
  }

  tsum += __shfl_xor(tsum, 16);
  tsum += __shfl_xor(tsum, 32);
  if (qi < NPOOL){
    float inv = 1.f / tsum;
    #pragma unroll
    for (int dt=0; dt<6; dt++){
      #pragma unroll
      for (int r=0; r<4; r++){
        int dd = dt*16 + g*4 + r;
        oattn[((size_t)b*NPOOL + qi)*DIMD + h*96 + dd] = f2bf(accO[dt][r] * inv);
      }
    }
  }
}

// ---- maxpool(3x3/s2 over h,w) skip + add proj-out + LN2; writes x2 fp32 and xn2 bf16 ----
__global__ __launch_bounds__(256) void skip_ln2(const float* __restrict__ x, const float* __restrict__ oproj,
                         const float* __restrict__ w, const float* __restrict__ bb,
                         float* __restrict__ x2, short* __restrict__ xn2){
  unsigned nwg = gridDim.x * gridDim.y;   // NPOOL*4
  unsigned bid = blockIdx.y * gridDim.x + blockIdx.x;
  unsigned serial = xcd_serial(bid, nwg);
  int b = (int)(serial / NPOOL);
  int tok = (int)(serial - (unsigned)b*NPOOL);
  int t = threadIdx.x;
  __shared__ float red[256];
  float v[3];
  int ot = tok - 1;
  int to = ot/196, rem = ot%196, ho = rem/14, wo = rem%14;
  #pragma unroll
  for (int i=0;i<3;i++){
    int c = t + i*256;
    float mv;
    if (tok == 0){
      mv = x[(size_t)b*NTOK*DIMD + c];
    } else {
      mv = -INFINITY;
      #pragma unroll
      for (int dh=0; dh<3; dh++){
        int ih = 2*ho - 1 + dh; if (ih < 0 || ih >= 28) continue;
        #pragma unroll
        for (int dw=0; dw<3; dw++){
          int iw = 2*wo - 1 + dw; if (iw < 0 || iw >= 28) continue;
          int n = 1 + (to*28 + ih)*28 + iw;
          mv = fmaxf(mv, x[((size_t)b*NTOK + n)*DIMD + c]);
        }
      }
    }
    float val = mv + oproj[((size_t)b*NPOOL + tok)*DIMD + c];
    x2[((size_t)b*NPOOL + tok)*DIMD + c] = val;
    v[i] = val;
  }
  float s = v[0]+v[1]+v[2];
  s = block_sum<256>(s, red);
  float mu = s * (1.f/768.f);
  float sq = 0.f;
  #pragma unroll
  for (int i=0;i<3;i++){ float d = v[i]-mu; sq += d*d; }
  sq = block_sum<256>(sq, red);
  float rstd = rsqrtf(sq*(1.f/768.f) + 1e-5f);
  #pragma unroll
  for (int i=0;i<3;i++){
    int c = t + i*256;
    xn2[((size_t)b*NPOOL + tok)*DIMD + c] = f2bf((v[i]-mu)*rstd*w[c] + bb[c]);
  }
}

extern "C" void kernel_launch(void* const* d_in, const int* in_sizes, int n_in,
                              void* d_out, int out_size, void* d_ws, size_t ws_size,
                              hipStream_t stream){
  (void)in_sizes; (void)n_in; (void)out_size; (void)ws_size;
  const float* x      = (const float*)d_in[0];
  const float* n1_w   = (const float*)d_in[1];
  const float* n1_b   = (const float*)d_in[2];
  const float* wq     = (const float*)d_in[3];
  const float* bq     = (const float*)d_in[4];
  const float* wk     = (const float*)d_in[5];
  const float* bk     = (const float*)d_in[6];
  const float* wv     = (const float*)d_in[7];
  const float* bv     = (const float*)d_in[8];
  const float* pq_w   = (const float*)d_in[9];
  const float* pk_w   = (const float*)d_in[10];
  const float* pv_w   = (const float*)d_in[11];
  const float* nq_w   = (const float*)d_in[12];
  const float* nq_b   = (const float*)d_in[13];
  const float* nk_w   = (const float*)d_in[14];
  const float* nk_b   = (const float*)d_in[15];
  const float* nv_w   = (const float*)d_in[16];
  const float* nv_b   = (const float*)d_in[17];
  const float* proj_w = (const float*)d_in[18];
  const float* proj_b = (const float*)d_in[19];
  const float* n2_w   = (const float*)d_in[20];
  const float* n2_b   = (const float*)d_in[21];
  const float* fc1_w  = (const float*)d_in[22];
  const float* fc1_b  = (const float*)d_in[23];
  const float* fc2_w  = (const float*)d_in[24];
  const float* fc2_b  = (const float*)d_in[25];
  float* out = (float*)d_out;

  char* ws = (char*)d_ws;
  size_t off = 0;
  auto take = [&](size_t bytes)->char*{
    char* p = ws + off; off = (off + bytes + 255) & ~(size_t)255; return p;
  };
  short* xn  = (short*)take(38541312);       // 25092*768 bf16
  short* wqb = (short*)take(1179648);        // wqb/wkb/wvb contiguous -> one [2304][768] matrix
  short* wkb = (short*)take(1179648);
  short* wvb = (short*)take(1179648);
  short* wpb = (short*)take(1179648);
  short* w1b = (short*)take(4718592);
  short* w2b = (short*)take(4718592);
  float* bcat= (float*)take(9216);           // packed [bq|bk|bv]
  char*  big = take(115623936);              // phase1: linear qkv [25092][2304]; phase2: oattn/oproj/x2/xn2/h1
  short* qkv  = (short*)(big);               // 115623936 B exactly
  short* oattn= (short*)(big);               // 9639936 B
  float* oproj= (float*)(big + 9639936);     // 19279872 B
  float* x2   = (float*)(big + 28919808);    // 19279872 B
  short* xn2  = (short*)(big + 48199680);    // 9639936 B
  short* h1   = (short*)(big + 57839616);    // 38559744 B
  short* qp   = (short*)take(9830400);       // 32*1600*96 bf16
  short* kp   = (short*)take(9830400);
  short* vT   = (short*)take(9830400);

  castw<<<dim3(2304,6), 256, 0, stream>>>(wq,wk,wv,proj_w,fc1_w,fc2_w, wqb,wkb,wvb,wpb,w1b,w2b);
  packb<<<9, 256, 0, stream>>>(bq, bk, bv, bcat);
  ln768<<<6273, 256, 0, stream>>>(x, n1_w, n1_b, xn);

  // fused QKV: 256x256 gemm8, 8-phase schedule; grid 9x99 = 891 blocks
  gemm8<<<dim3(9,99), 512, 0, stream>>>(xn, wqb, bcat, qkv, MROWS, 2304, 768);

  pool_conv3<<<dim3(32,14,3), 256, 0, stream>>>(qkv, pq_w, pk_w, pv_w,
                                                nq_w, nq_b, nk_w, nk_b, nv_w, nv_b, qp, kp, vT);
  cls3<<<dim3(B_), 128, 0, stream>>>(qkv, nq_w, nq_b, nk_w, nk_b, nv_w, nv_b, qp, kp, vT);
  padfill<<<dim3(31,32), 96, 0, stream>>>(qp, kp, vT);

  attn_k<<<dim3(13,32), 512, 0, stream>>>(qp, kp, vT, oattn);

  // proj: 50x6 tiles, supertile 10x6
  gemm_bt<0,0,0,10,6><<<dim3(6,50), 256, 0, stream>>>(oattn, wpb, proj_b, nullptr, oproj, nullptr, M2, 768, 768);

  skip_ln2<<<dim3(NPOOL,B_), 256, 0, stream>>>(x, oproj, n2_w, n2_b, x2, xn2);

  // fc1: 50x24 tiles, supertile 10x8 (bf16 out -> wide epilogue)
  gemm_bt<1,1,0,10,8><<<dim3(24,50), 256, 0, stream>>>(xn2, w1b, fc1_b, nullptr, nullptr, h1, M2, HID, 768);
  // fc2: 50x6 tiles, K=3072 -> supertile 2x3
  gemm_bt<0,0,1,2,3><<<dim3(6,50), 256, 0, stream>>>(h1, w2b, fc2_b, x2, out, nullptr, M2, 768, HID);
}

// Round 7
// 599.639 us; speedup vs baseline: 1.0523x; 1.0523x over previous
//
#include <hip/hip_runtime.h>
#include <math.h>

#define B_ 4
#define NTOK 6273
#define DIMD 768
#define HEADS 8
#define HD 96
#define NPOOL 1569
#define NPAD 1600
#define HID 3072
#define MROWS (B_*NTOK)   // 25092
#define M2 (B_*NPOOL)     // 6276
#define SCALE_ 0.10206207261596575f

typedef float f32x4 __attribute__((ext_vector_type(4)));
typedef short s16x8 __attribute__((ext_vector_type(8)));
typedef short s16x4 __attribute__((ext_vector_type(4)));
typedef unsigned u32x3 __attribute__((ext_vector_type(3)));

__device__ __forceinline__ short f2bf(float f){
  unsigned u = __builtin_bit_cast(unsigned, f);
  u = (u + 0x7fffu + ((u >> 16) & 1u)) >> 16;
  return (short)u;
}
__device__ __forceinline__ float bf2f(short s){
  unsigned u = ((unsigned)(unsigned short)s) << 16;
  return __builtin_bit_cast(float, u);
}
__device__ __forceinline__ float bfsel(unsigned u, int hi){
  unsigned r = hi ? (u & 0xffff0000u) : (u << 16);
  return __builtin_bit_cast(float, r);
}
__device__ __forceinline__ unsigned pack2(float lo, float hi){
  return (unsigned)(unsigned short)f2bf(lo) | ((unsigned)(unsigned short)f2bf(hi) << 16);
}

__device__ __forceinline__ void gld16(const void* g, void* l){
  __builtin_amdgcn_global_load_lds((const __attribute__((address_space(1))) unsigned*)g,
                                   (__attribute__((address_space(3))) unsigned*)l, 16, 0, 0);
}

#if defined(__has_builtin)
#if __has_builtin(__builtin_amdgcn_mfma_f32_16x16x16bf16_1k)
#define MFMA16K(a,b,c) __builtin_amdgcn_mfma_f32_16x16x16bf16_1k(a,b,c,0,0,0)
#endif
#endif
#ifndef MFMA16K
__device__ __forceinline__ f32x4 mfma16k_asm(s16x4 a, s16x4 b, f32x4 c){
  asm volatile("v_mfma_f32_16x16x16_bf16 %0, %1, %2, %0\n\ts_nop 7\n\ts_nop 7"
               : "+v"(c) : "v"(a), "v"(b));
  return c;
}
#define MFMA16K(a,b,c) mfma16k_asm(a,b,c)
#endif

template<int NT>
__device__ __forceinline__ float block_sum(float v, float* red){
  int t = threadIdx.x;
  red[t] = v; __syncthreads();
  #pragma unroll
  for (int s = NT/2; s > 0; s >>= 1){
    if (t < s) red[t] += red[t+s];
    __syncthreads();
  }
  float r = red[0];
  __syncthreads();
  return r;
}

// ---- XCD-chunked serial (m204 bijection): contiguous serial range per XCD ----
__device__ __forceinline__ unsigned xcd_serial(unsigned bid, unsigned nwg){
  unsigned q = nwg >> 3, r8 = nwg & 7;
  unsigned xcd = bid & 7, idx = bid >> 3;
  return (xcd < r8 ? xcd*(q+1) : r8*(q+1) + (xcd-r8)*q) + idx;
}

// supertile decode: STR x STC tiles per supertile, row-fast within col.
template<int STR, int STC>
__device__ __forceinline__ void tile_decode(unsigned serial, int& rowT, int& colT){
  const int nStC = (int)gridDim.x / STC;
  int st = (int)serial / (STR*STC);
  int t  = (int)serial - st*(STR*STC);
  int stR = st / nStC, stC = st - stR*nStC;
  int c = t / STR, r = t - c*STR;
  rowT = stR*STR + r;
  colT = stC*STC + c;
}

// ---- cast 6 weight matrices fp32 -> bf16 ----
__global__ void castw(const float* s0,const float* s1,const float* s2,const float* s3,
                      const float* s4,const float* s5,
                      short* d0,short* d1,short* d2,short* d3,short* d4,short* d5){
  const float* s; short* d; int n;
  switch(blockIdx.y){
    case 0: s=s0; d=d0; n=589824; break;
    case 1: s=s1; d=d1; n=589824; break;
    case 2: s=s2; d=d2; n=589824; break;
    case 3: s=s3; d=d3; n=589824; break;
    case 4: s=s4; d=d4; n=2359296; break;
    default: s=s5; d=d5; n=2359296; break;
  }
  for (int i = blockIdx.x*blockDim.x + threadIdx.x; i < n; i += gridDim.x*blockDim.x)
    d[i] = f2bf(s[i]);
}

// ---- pack 3 bias vectors into one contiguous [2304] buffer ----
__global__ __launch_bounds__(256) void packb(const float* b0, const float* b1, const float* b2, float* o){
  int i = blockIdx.x*256 + threadIdx.x;   // 9 blocks -> 2304
  if (i < 768) o[i] = b0[i];
  else if (i < 1536) o[i] = b1[i-768];
  else if (i < 2304) o[i] = b2[i-1536];
}

// ---- LayerNorm over 768, wave-per-row (4 rows/block): zero LDS, zero barriers ----
__global__ __launch_bounds__(256) void ln768(const float* __restrict__ x, const float* __restrict__ w,
                      const float* __restrict__ b, short* __restrict__ out){
  int row = blockIdx.x*4 + (threadIdx.x >> 6);
  int lane = threadIdx.x & 63;
  const float* xr = x + (size_t)row*DIMD + lane*12;
  f32x4 v0 = *(const f32x4*)(xr);
  f32x4 v1 = *(const f32x4*)(xr + 4);
  f32x4 v2 = *(const f32x4*)(xr + 8);
  float v[12] = { v0[0],v0[1],v0[2],v0[3], v1[0],v1[1],v1[2],v1[3], v2[0],v2[1],v2[2],v2[3] };
  float s = 0.f;
  #pragma unroll
  for (int j=0;j<12;j++) s += v[j];
  #pragma unroll
  for (int m=1; m<64; m<<=1) s += __shfl_xor(s, m);
  float mu = s * (1.f/768.f);
  float sq = 0.f;
  #pragma unroll
  for (int j=0;j<12;j++){ float d = v[j]-mu; sq += d*d; }
  #pragma unroll
  for (int m=1; m<64; m<<=1) sq += __shfl_xor(sq, m);
  float rstd = rsqrtf(sq*(1.f/768.f) + 1e-5f);
  int c0 = lane*12;
  float o[12];
  #pragma unroll
  for (int j=0;j<12;j++) o[j] = (v[j]-mu)*rstd*w[c0+j] + b[c0+j];
  unsigned* po = (unsigned*)(out + (size_t)row*DIMD + c0);
  #pragma unroll
  for (int k=0;k<6;k++) po[k] = pack2(o[2*k], o[2*k+1]);
}

// ================= 256x256 GEMM, 8 waves, 4-slot BK=32 depth-3 pipeline (R5, PROVEN 144.7us) ====
// R6 post-mortem: 8-phase restructure was NULL (147us, MfmaUtil 24.6 vs 25.5) — T4 counted-vmcnt
// was already present here and T2 has no lever (staging is conflict-free). This version stands.
__global__ __launch_bounds__(512) void gemm8(const short* __restrict__ A, const short* __restrict__ Bw,
                        const float* __restrict__ bias, short* __restrict__ Cb,
                        int M, int N, int K){
  __shared__ short lds[4][16384];   // slot: A 0..8191 | B 8192..16383 (BK=32); epilogue: 128KB C tile
  int tid = threadIdx.x;
  int w = tid >> 6, lane = tid & 63;
  int l15 = lane & 15, g = (lane >> 4) & 3;
  int wr = w >> 2, wc = w & 3;

  unsigned nwg = gridDim.x * gridDim.y;
  unsigned bid = blockIdx.y * gridDim.x + blockIdx.x;
  unsigned serial = bid;
  if (nwg >= 512) serial = xcd_serial(bid, nwg);
  int rowBase = (int)(serial / gridDim.x) * 256;
  int colBase = (int)(serial % gridDim.x) * 256;

  const short* pa[2]; const short* pb[2];
  #pragma unroll
  for (int j=0;j<2;j++){
    int mr = rowBase + (w + j*8)*16 + l15; if (mr >= M) mr = M-1;
    int nr = colBase + (w + j*8)*16 + l15;           // N always multiple of 256
    pa[j] = A  + (size_t)mr*K + g*8;
    pb[j] = Bw + (size_t)nr*K + g*8;
  }
  int sd = tid*8;

  auto stage = [&](int slot, int p){
    int koff = p*32;
    short* base = &lds[slot][0];
    #pragma unroll
    for (int j=0;j<2;j++){
      gld16(pa[j] + koff, base + sd + j*4096);
      gld16(pb[j] + koff, base + 8192 + sd + j*4096);
    }
  };

  f32x4 acc[8][4] = {};
  int np = K >> 5;   // 24 phases of BK=32
  stage(0, 0);
  if (np > 1) stage(1, 1);
  if (np > 2) stage(2, 2);          // 12 loads outstanding, 3 phases deep
  for (int p = 0; p < np; p++){
    if (p <= np-3)
      asm volatile("s_waitcnt vmcnt(8)" ::: "memory");   // retire phase-p's 4; p+1,p+2 in flight
    else if (p == np-2)
      asm volatile("s_waitcnt vmcnt(4)" ::: "memory");
    else
      asm volatile("s_waitcnt vmcnt(0)" ::: "memory");
    __builtin_amdgcn_s_barrier();
    if (p + 3 < np) stage((p+3)&3, p+3);
    const short* lA = &lds[p&3][0];
    const short* lB = lA + 8192;
    s16x8 bfr[4];
    #pragma unroll
    for (int nf=0; nf<4; nf++)
      bfr[nf] = *(const s16x8*)(lB + (wc*4+nf)*512 + lane*8);
    __builtin_amdgcn_s_setprio(1);
    #pragma unroll
    for (int mf=0; mf<8; mf++){
      s16x8 af = *(const s16x8*)(lA + (wr*8+mf)*512 + lane*8);
      #pragma unroll
      for (int nf=0; nf<4; nf++)
        acc[mf][nf] = __builtin_amdgcn_mfma_f32_16x16x32_bf16(af, bfr[nf], acc[mf][nf], 0,0,0);
    }
    __builtin_amdgcn_s_setprio(0);
  }

  // ---- wide epilogue: all waves done reading slots, reuse full 128KB as C tile ----
  __syncthreads();
  short* ldsC = &lds[0][0];   // 65536 shorts; row = 256 shorts (512B), chunk = 8 shorts (16B)
  #pragma unroll
  for (int mf=0; mf<8; mf++){
    int rowL0 = wr*128 + mf*16 + g*4;
    #pragma unroll
    for (int nf=0; nf<4; nf++){
      int colL = wc*64 + nf*16 + l15;
      float bv = bias[colBase + colL];
      int ch = colL >> 3, in8 = colL & 7;
      #pragma unroll
      for (int r=0;r<4;r++){
        int rL = rowL0 + r;
        int chs = ch ^ ((rL >> 2) & 7);   // bank-XOR: spreads the 4 g-rows across chunk groups
        ldsC[rL*256 + chs*8 + in8] = f2bf(acc[mf][nf][r] + bv);
      }
    }
  }
  __syncthreads();
  int ch2 = tid & 31, rg = tid >> 5;   // 32 chunks/row; 16 rows per pass
  #pragma unroll
  for (int i=0;i<16;i++){
    int rowL = rg + i*16;
    int chs = ch2 ^ ((rowL >> 2) & 7);
    s16x8 v = *(const s16x8*)(ldsC + rowL*256 + chs*8);
    int rr = rowBase + rowL;
    if (rr < M) *(s16x8*)(Cb + (size_t)rr*N + colBase + ch2*8) = v;
  }
}

// ---- bf16 GEMM, 2-phase 128x128 (proven m97 structure): fc1.
// bf16 outputs via R4 wide LDS-transposed epilogue.
template<int GELU, int OUTBF16, int RESID, int STR, int STC>
__global__ __launch_bounds__(256) void gemm_bt(const short* __restrict__ A, const short* __restrict__ Bw,
                        const float* __restrict__ bias, const float* __restrict__ resid,
                        float* __restrict__ Cf, short* __restrict__ Cb,
                        int M, int N, int K){
  __shared__ short lds[3][8192];   // [buf][ A:0..4095 | B:4096..8191 ]; epilogue reuses 32KB as C tile
  int tid = threadIdx.x;
  int lane = tid & 63, wv = tid >> 6;
  int wr = wv >> 1, wc = wv & 1;
  int l15 = lane & 15, g = lane >> 4;

  unsigned nwg = gridDim.x * gridDim.y;
  unsigned bid = blockIdx.y * gridDim.x + blockIdx.x;
  unsigned serial = xcd_serial(bid, nwg);
  int rowT, colT;
  tile_decode<STR,STC>(serial, rowT, colT);
  int rowBase = rowT * 128;
  int colBase = colT * 128;

  f32x4 acc[4][4] = {};
  int srow = (tid & 15) | ((tid >> 6) << 4);   // 0..63
  int scol = ((tid >> 4) & 3) * 8;
  int ldsoff = tid * 8;

  int ar0 = rowBase + srow;      if (ar0 >= M) ar0 = M-1;
  int ar1 = rowBase + srow + 64; if (ar1 >= M) ar1 = M-1;
  int br0 = colBase + srow;      // N always multiple of 128
  const short* pa0 = A  + (size_t)ar0*K + scol;
  const short* pa1 = A  + (size_t)ar1*K + scol;
  const short* pb0 = Bw + (size_t)br0*K + scol;
  const short* pb1 = Bw + (size_t)(br0+64)*K + scol;

  auto stage = [&](int s, int kt){
    gld16(pa0 + kt, &lds[s][ldsoff]);
    gld16(pa1 + kt, &lds[s][ldsoff + 2048]);
    gld16(pb0 + kt, &lds[s][4096 + ldsoff]);
    gld16(pb1 + kt, &lds[s][4096 + ldsoff + 2048]);
  };

  int nk = K >> 5;
  stage(0, 0);
  if (nk > 1) stage(1, 32);
  for (int kt = 0; kt < nk; kt++){
    int cur = kt % 3;
    if (kt + 2 < nk){
      stage((kt+2)%3, (kt+2)*32);
      asm volatile("s_waitcnt vmcnt(8)" ::: "memory");
    } else if (kt + 1 < nk){
      asm volatile("s_waitcnt vmcnt(4)" ::: "memory");
    } else {
      asm volatile("s_waitcnt vmcnt(0)" ::: "memory");
    }
    __builtin_amdgcn_s_barrier();
    const short* la = lds[cur];
    const short* lb = lds[cur] + 4096;
    s16x8 af[4], bfr[4];
    #pragma unroll
    for (int m=0;m<4;m++) af[m]  = *(const s16x8*)(la + (wr*4 + m)*512 + g*128 + l15*8);
    #pragma unroll
    for (int n=0;n<4;n++) bfr[n] = *(const s16x8*)(lb + (wc*4 + n)*512 + g*128 + l15*8);
    #pragma unroll
    for (int m=0;m<4;m++)
      #pragma unroll
      for (int n=0;n<4;n++)
        acc[m][n] = __builtin_amdgcn_mfma_f32_16x16x32_bf16(af[m], bfr[n], acc[m][n], 0,0,0);
    __builtin_amdgcn_s_barrier();
  }

  if (OUTBF16){
    short* ldsC = &lds[0][0];
    #pragma unroll
    for (int n=0;n<4;n++){
      int colL = wc*64 + n*16 + l15;
      float bv = bias[colBase + colL];
      #pragma unroll
      for (int m=0;m<4;m++){
        #pragma unroll
        for (int r=0;r<4;r++){
          int rowL = wr*64 + m*16 + g*4 + r;
          float v = acc[m][n][r] + bv;
          if (GELU) v = 0.5f*v*(1.f + erff(v*0.70710678118654752f));
          int ch = colL >> 3, in8 = colL & 7;
          int chs = ch ^ (((rowL >> 2) & 3) << 2);
          ldsC[rowL*128 + chs*8 + in8] = f2bf(v);
        }
      }
    }
    __syncthreads();
    int ch = tid & 15, rg = tid >> 4;
    #pragma unroll
    for (int i=0;i<8;i++){
      int rowL = rg + i*16;
      int chs = ch ^ (((rowL >> 2) & 3) << 2);
      s16x8 v = *(const s16x8*)(ldsC + rowL*128 + chs*8);
      int rr = rowBase + rowL;
      if (rr < M) *(s16x8*)(Cb + (size_t)rr*N + colBase + ch*8) = v;
    }
  } else {
    #pragma unroll
    for (int m=0;m<4;m++){
      int row = rowBase + wr*64 + m*16 + g*4;
      #pragma unroll
      for (int n=0;n<4;n++){
        int col = colBase + wc*64 + n*16 + l15;
        float bv = bias[col];
        #pragma unroll
        for (int r=0;r<4;r++){
          int rr = row + r;
          if (rr < M){
            float v = acc[m][n][r] + bv;
            if (GELU) v = 0.5f*v*(1.f + erff(v*0.70710678118654752f));
            if (RESID) v += resid[(size_t)rr*N + col];
            Cf[(size_t)rr*N + col] = v;
          }
        }
      }
    }
  }
}

// ---- 64x128-tile fp32-out GEMM (proj, fc2): 4 waves spanning N, 18KB LDS.
// R6 theory: proj/fc2 at 300 blocks run ~1 block/CU = 1 wave/SIMD (no TLP, 1.17-round
// quantization). 64-row tiles -> grid 6x99 = 594 blocks, 2-3 blocks/CU = 8-12 waves/CU.
// Same counted-vmcnt depth-3 pipeline; 3 gld16/stage -> vmcnt(6/3/0).
template<int RESID>
__global__ __launch_bounds__(256) void gemm_n64(const short* __restrict__ A, const short* __restrict__ Bw,
                        const float* __restrict__ bias, const float* __restrict__ resid,
                        float* __restrict__ Cf, int M, int N, int K){
  __shared__ short lds[3][6144];   // [buf][ A:0..2047 (64x32) | B:2048..6143 (128x32) ]
  int tid = threadIdx.x;
  int lane = tid & 63, wc = tid >> 6;       // 4 waves across the 128 cols
  int l15 = lane & 15, g = lane >> 4;

  unsigned nwg = gridDim.x * gridDim.y;     // 6*99 = 594
  unsigned bid = blockIdx.y * gridDim.x + blockIdx.x;
  unsigned serial = xcd_serial(bid, nwg);
  int rowBase = (int)(serial / gridDim.x) * 64;    // col-fast within each XCD chunk
  int colBase = (int)(serial % gridDim.x) * 128;

  f32x4 acc[4][2] = {};
  int srow = (tid & 15) | ((tid >> 6) << 4);   // 0..63  ([rowblock][kseg][row15] LDS layout)
  int scol = ((tid >> 4) & 3) * 8;
  int ldsoff = tid * 8;

  int ar = rowBase + srow; if (ar >= M) ar = M-1;
  int br = colBase + srow;                      // N multiple of 128
  const short* pa  = A  + (size_t)ar*K + scol;
  const short* pb0 = Bw + (size_t)br*K + scol;
  const short* pb1 = Bw + (size_t)(br+64)*K + scol;

  auto stage = [&](int s, int kt){
    gld16(pa  + kt, &lds[s][ldsoff]);
    gld16(pb0 + kt, &lds[s][2048 + ldsoff]);
    gld16(pb1 + kt, &lds[s][4096 + ldsoff]);
  };

  int nk = K >> 5;
  stage(0, 0);
  if (nk > 1) stage(1, 32);
  for (int kt = 0; kt < nk; kt++){
    int cur = kt % 3;
    if (kt + 2 < nk){
      stage((kt+2)%3, (kt+2)*32);
      asm volatile("s_waitcnt vmcnt(6)" ::: "memory");   // oldest 3 = stage(kt) landed
    } else if (kt + 1 < nk){
      asm volatile("s_waitcnt vmcnt(3)" ::: "memory");
    } else {
      asm volatile("s_waitcnt vmcnt(0)" ::: "memory");
    }
    __builtin_amdgcn_s_barrier();
    const short* la = lds[cur];
    const short* lb = lds[cur] + 2048;
    s16x8 af[4], bfr[2];
    #pragma unroll
    for (int m=0;m<4;m++) af[m]  = *(const s16x8*)(la + m*512 + g*128 + l15*8);
    #pragma unroll
    for (int n=0;n<2;n++) bfr[n] = *(const s16x8*)(lb + (wc*2 + n)*512 + g*128 + l15*8);
    #pragma unroll
    for (int m=0;m<4;m++)
      #pragma unroll
      for (int n=0;n<2;n++)
        acc[m][n] = __builtin_amdgcn_mfma_f32_16x16x32_bf16(af[m], bfr[n], acc[m][n], 0,0,0);
    __builtin_amdgcn_s_barrier();
  }
  #pragma unroll
  for (int m=0;m<4;m++){
    int row = rowBase + m*16 + g*4;
    #pragma unroll
    for (int n=0;n<2;n++){
      int col = colBase + wc*32 + n*16 + l15;
      float bv = bias[col];
      #pragma unroll
      for (int r=0;r<4;r++){
        int rr = row + r;
        if (rr < M){
          float v = acc[m][n][r] + bv;
          if (RESID) v += resid[(size_t)rr*N + col];
          Cf[(size_t)rr*N + col] = v;
        }
      }
    }
  }
}

// ---- fused attention pooling conv for q,k,v (one launch) + LN over 96.
// Reads the LINEAR qkv buffer [b*NTOK+tok][2304] (col = z*768 + h*96 + d).
__global__ __launch_bounds__(256, 2) void pool_conv3(
    const short* __restrict__ raw,
    const float* __restrict__ cwq, const float* __restrict__ cwk, const float* __restrict__ cwv,
    const float* __restrict__ nqw, const float* __restrict__ nqb,
    const float* __restrict__ nkw, const float* __restrict__ nkb,
    const float* __restrict__ nvw, const float* __restrict__ nvb,
    short* __restrict__ qo, short* __restrict__ ko, short* __restrict__ vo){
  unsigned nwg = gridDim.x * gridDim.y * gridDim.z;   // 1344
  unsigned lin = (blockIdx.z*gridDim.y + blockIdx.y)*gridDim.x + blockIdx.x;
  unsigned serial = xcd_serial(lin, nwg);
  int ho = (int)(serial % 14);
  unsigned rest = serial / 14;
  int bh = (int)(rest & 31);
  int z  = (int)(rest >> 5);
  int t = threadIdx.x;
  int g = t >> 4;        // wo
  if (g >= 14) return;
  int s = t & 15, d = s*6;
  const float* cw = (z==0) ? cwq : (z==1) ? cwk : cwv;
  const float* nw = (z==0) ? nqw : (z==1) ? nkw : nvw;
  const float* nb = (z==0) ? nqb : (z==1) ? nkb : nvb;
  const short* base = raw + (size_t)(bh>>3)*NTOK*2304 + z*768 + (bh&7)*96 + d;
  float acc[8][6] = {};
  #pragma unroll
  for (int dh=0; dh<3; dh++){
    int ih = 2*ho - 1 + dh;
    if (ih < 0 || ih >= 28) continue;
    #pragma unroll
    for (int dw=0; dw<3; dw++){
      int iw = 2*g - 1 + dw;
      if (iw < 0 || iw >= 28) continue;
      float w[3][6];
      #pragma unroll
      for (int dt=0; dt<3; dt++)
        #pragma unroll
        for (int j=0;j<6;j++)
          w[dt][j] = cw[(d+j)*27 + dt*9 + dh*3 + dw];
      #pragma unroll
      for (int it=0; it<8; it++){
        u32x3 u = *(const u32x3*)(base + (size_t)(1 + (it*28+ih)*28 + iw)*2304);
        float in[6] = { bfsel(u[0],0), bfsel(u[0],1), bfsel(u[1],0),
                        bfsel(u[1],1), bfsel(u[2],0), bfsel(u[2],1) };
        #pragma unroll
        for (int dt=0; dt<3; dt++){
          int to = it + 1 - dt;                // compile-time per unrolled iter
          if (to < 0 || to > 7) continue;
          #pragma unroll
          for (int j=0;j<6;j++) acc[to][j] = fmaf(in[j], w[dt][j], acc[to][j]);
        }
      }
    }
  }
  float nwv[6], nbv[6];
  #pragma unroll
  for (int j=0;j<6;j++){ nwv[j] = nw[d+j]; nbv[j] = nb[d+j]; }
  #pragma unroll
  for (int to=0; to<8; to++){
    float sm = acc[to][0]+acc[to][1]+acc[to][2]+acc[to][3]+acc[to][4]+acc[to][5];
    #pragma unroll
    for (int m=1; m<16; m<<=1) sm += __shfl_xor(sm, m);
    float mu = sm*(1.f/96.f);
    float vr = 0.f;
    #pragma unroll
    for (int j=0;j<6;j++){ float dd = acc[to][j]-mu; vr += dd*dd; }
    #pragma unroll
    for (int m=1; m<16; m<<=1) vr += __shfl_xor(vr, m);
    float rstd = rsqrtf(vr*(1.f/96.f) + 1e-5f);
    int tok = 1 + to*196 + ho*14 + g;
    if (z == 0){
      short o[6];
      #pragma unroll
      for (int j=0;j<6;j++) o[j] = f2bf((acc[to][j]-mu)*rstd*nwv[j] + nbv[j]);
      unsigned* q32 = (unsigned*)(qo + ((size_t)bh*NPAD + tok)*96 + d);
      #pragma unroll
      for (int w2=0; w2<3; w2++)
        q32[w2] = (unsigned)(unsigned short)o[2*w2] | ((unsigned)(unsigned short)o[2*w2+1] << 16);
    } else if (z == 1){
      size_t kb = (size_t)bh*NPAD*96 + (size_t)(tok>>4)*1536 + (tok&15)*8;
      #pragma unroll
      for (int j=0;j<6;j++){
        int dj = d + j;
        ko[kb + (dj>>5)*512 + ((dj>>3)&3)*128 + (dj&7)] = f2bf((acc[to][j]-mu)*rstd*nwv[j] + nbv[j]);
      }
    } else {
      size_t vb = (size_t)bh*NPAD*96 + (size_t)(tok>>6)*6144 + ((tok>>4)&3)*256 + ((tok>>2)&3)*64 + (tok&3);
      #pragma unroll
      for (int j=0;j<6;j++){
        int dj = d + j;
        vo[vb + (dj>>4)*1024 + (dj&15)*4] = f2bf((acc[to][j]-mu)*rstd*nwv[j] + nbv[j]);
      }
    }
  }
}

// ---- cls token (tok=0): LN of linear-qkv row 0 for q,k,v; 4 blocks x 128 threads ----
__global__ __launch_bounds__(128) void cls3(
    const short* __restrict__ raw,
    const float* __restrict__ nqw, const float* __restrict__ nqb,
    const float* __restrict__ nkw, const float* __restrict__ nkb,
    const float* __restrict__ nvw, const float* __restrict__ nvb,
    short* __restrict__ qo, short* __restrict__ ko, short* __restrict__ vo){
  int b = blockIdx.x, t = threadIdx.x;
  int h = t >> 4, s = t & 15, d = s*6;
  int bh = b*8 + h;
  const float* nws[3] = { nqw, nkw, nvw };
  const float* nbs[3] = { nqb, nkb, nvb };
  #pragma unroll
  for (int ten=0; ten<3; ten++){
    const short* row = raw + (size_t)b*NTOK*2304 + ten*768 + h*96 + d;
    u32x3 u = *(const u32x3*)(row);
    float a[6] = { bfsel(u[0],0), bfsel(u[0],1), bfsel(u[1],0), bfsel(u[1],1), bfsel(u[2],0), bfsel(u[2],1) };
    float sm = a[0]+a[1]+a[2]+a[3]+a[4]+a[5];
    #pragma unroll
    for (int m=1; m<16; m<<=1) sm += __shfl_xor(sm, m);
    float mu = sm*(1.f/96.f);
    float vr2 = 0.f;
    #pragma unroll
    for (int j=0;j<6;j++){ float dd = a[j]-mu; vr2 += dd*dd; }
    #pragma unroll
    for (int m=1; m<16; m<<=1) vr2 += __shfl_xor(vr2, m);
    float rstd = rsqrtf(vr2*(1.f/96.f) + 1e-5f);
    #pragma unroll
    for (int j=0;j<6;j++){
      int dj = d + j;
      short o = f2bf((a[j]-mu)*rstd*nws[ten][dj] + nbs[ten][dj]);
      if (ten == 0)      qo[((size_t)bh*NPAD)*96 + dj] = o;
      else if (ten == 1) ko[(size_t)bh*NPAD*96 + (dj>>5)*512 + ((dj>>3)&3)*128 + (dj&7)] = o;
      else               vo[(size_t)bh*NPAD*96 + (dj>>4)*1024 + (dj&15)*4] = o;
    }
  }
}

// ---- zero-fill padded tokens NPOOL..NPAD-1 in all three layouts ----
__global__ __launch_bounds__(96) void padfill(short* __restrict__ qo, short* __restrict__ ko, short* __restrict__ vo){
  int tok = NPOOL + blockIdx.x;   // 31 blocks
  int bh = blockIdx.y;
  int d = threadIdx.x;            // 96
  qo[((size_t)bh*NPAD + tok)*96 + d] = 0;
  size_t kb = (size_t)bh*NPAD*96 + (size_t)(tok>>4)*1536 + (tok&15)*8;
  ko[kb + (d>>5)*512 + ((d>>3)&3)*128 + (d&7)] = 0;
  size_t vb = (size_t)bh*NPAD*96 + (size_t)(tok>>6)*6144 + ((tok>>4)&3)*256 + ((tok>>2)&3)*64 + (tok&3);
  vo[vb + (d>>4)*1024 + (d&15)*4] = 0;
}

// ---- flash attention, 8 waves/block (128 q-rows).
// XCD mapping: bh-major chunks -> each XCD owns exactly 4 bh; K/V L2-resident.
__global__ __launch_bounds__(512) void attn_k(const short* __restrict__ qp, const short* __restrict__ kp,
                       const short* __restrict__ vp, short* __restrict__ oattn){
  const float M0 = 6.0f;
  __shared__ short lkv[2][12288];   // [buf][ K:0..6143 | V:6144..12287 ]
  unsigned nwg = gridDim.x * gridDim.y;   // 13*32 = 416
  unsigned bid0 = blockIdx.y * gridDim.x + blockIdx.x;
  unsigned serial = xcd_serial(bid0, nwg);
  int bh = (int)(serial / 13);
  int qblk = (int)(serial - (unsigned)bh*13);
  int b = bh >> 3, h = bh & 7;
  int tid = threadIdx.x;
  int lane = tid & 63, wv = tid >> 6;
  int l15 = lane & 15, g = lane >> 4;
  int qi = qblk*128 + wv*16 + l15;
  int qi_ld = qi < NPAD ? qi : NPAD-1;        // clamp; pad rows are zeroed, writes masked below
  const short* qbase = qp + (size_t)bh*NPAD*HD;
  const short* kbase = kp + (size_t)bh*NPAD*HD;
  const short* vbase = vp + (size_t)bh*NPAD*HD;
  s16x8 qf[3];
  #pragma unroll
  for (int f=0; f<3; f++)
    qf[f] = *(const s16x8*)(qbase + (size_t)qi_ld*HD + f*32 + g*8);

  // stage chunk t: 12288 shorts (K 6144 | V 6144); 512 threads x 3 gld16, wave-uniform K/V branch
  auto stage = [&](int bsel, int t){
    #pragma unroll
    for (int i=0;i<3;i++){
      int off = i*4096 + tid*8;
      const short* src = (off < 6144) ? (kbase + t*6144 + off) : (vbase + t*6144 + off - 6144);
      gld16(src, &lkv[bsel][off]);
    }
  };

  f32x4 accO[6] = {};
  float tsum = 0.f;

  stage(0, 0);
  asm volatile("s_waitcnt vmcnt(0)" ::: "memory");
  __builtin_amdgcn_s_barrier();

  for (int kt = 0; kt < 25; kt++){
    int cur = kt & 1;
    if (kt < 24){
      stage(cur^1, kt+1);
      asm volatile("s_waitcnt vmcnt(3)" ::: "memory");   // current chunk done; next 3 in flight
    } else {
      asm volatile("s_waitcnt vmcnt(0)" ::: "memory");
    }
    __builtin_amdgcn_s_barrier();

    const short* lkc = &lkv[cur][0];
    const short* lvc = &lkv[cur][6144];
    f32x4 sacc[4];
    #pragma unroll
    for (int sub=0; sub<4; sub++){
      sacc[sub] = (f32x4){0.f,0.f,0.f,0.f};
      #pragma unroll
      for (int f=0; f<3; f++){
        s16x8 kf = *(const s16x8*)(lkc + sub*1536 + f*512 + lane*8);
        sacc[sub] = __builtin_amdgcn_mfma_f32_16x16x32_bf16(kf, qf[f], sacc[sub], 0,0,0);
      }
    }
    s16x4 pf[4];
    if (kt < 24){
      #pragma unroll
      for (int sub=0; sub<4; sub++){
        #pragma unroll
        for (int r=0; r<4; r++){
          float p = __expf(sacc[sub][r]*SCALE_ - M0);
          tsum += p;
          pf[sub][r] = f2bf(p);
        }
      }
    } else {
      #pragma unroll
      for (int sub=0; sub<4; sub++){
        #pragma unroll
        for (int r=0; r<4; r++){
          int ki = kt*64 + sub*16 + g*4 + r;
          float p = (ki < NPOOL) ? __expf(sacc[sub][r]*SCALE_ - M0) : 0.f;
          tsum += p;
          pf[sub][r] = f2bf(p);
        }
      }
    }
    #pragma unroll
    for (int dt=0; dt<6; dt++){
      #pragma unroll
      for (int sub=0; sub<4; sub++){
        s16x4 vf = *(const s16x4*)(lvc + dt*1024 + sub*256 + lane*4);
        accO[dt] = MFMA16K(vf, pf[sub], accO[dt]);
      }
    }
    __builtin_amdgcn_s_barrier();
  }

  tsum += __shfl_xor(tsum, 16);
  tsum += __shfl_xor(tsum, 32);
  if (qi < NPOOL){
    float inv = 1.f / tsum;
    #pragma unroll
    for (int dt=0; dt<6; dt++){
      #pragma unroll
      for (int r=0; r<4; r++){
        int dd = dt*16 + g*4 + r;
        oattn[((size_t)b*NPOOL + qi)*DIMD + h*96 + dd] = f2bf(accO[dt][r] * inv);
      }
    }
  }
}

// ---- maxpool(3x3/s2 over h,w) skip + add proj-out + LN2; writes x2 fp32 and xn2 bf16 ----
__global__ __launch_bounds__(256) void skip_ln2(const float* __restrict__ x, const float* __restrict__ oproj,
                         const float* __restrict__ w, const float* __restrict__ bb,
                         float* __restrict__ x2, short* __restrict__ xn2){
  unsigned nwg = gridDim.x * gridDim.y;   // NPOOL*4
  unsigned bid = blockIdx.y * gridDim.x + blockIdx.x;
  unsigned serial = xcd_serial(bid, nwg);
  int b = (int)(serial / NPOOL);
  int tok = (int)(serial - (unsigned)b*NPOOL);
  int t = threadIdx.x;
  __shared__ float red[256];
  float v[3];
  int ot = tok - 1;
  int to = ot/196, rem = ot%196, ho = rem/14, wo = rem%14;
  #pragma unroll
  for (int i=0;i<3;i++){
    int c = t + i*256;
    float mv;
    if (tok == 0){
      mv = x[(size_t)b*NTOK*DIMD + c];
    } else {
      mv = -INFINITY;
      #pragma unroll
      for (int dh=0; dh<3; dh++){
        int ih = 2*ho - 1 + dh; if (ih < 0 || ih >= 28) continue;
        #pragma unroll
        for (int dw=0; dw<3; dw++){
          int iw = 2*wo - 1 + dw; if (iw < 0 || iw >= 28) continue;
          int n = 1 + (to*28 + ih)*28 + iw;
          mv = fmaxf(mv, x[((size_t)b*NTOK + n)*DIMD + c]);
        }
      }
    }
    float val = mv + oproj[((size_t)b*NPOOL + tok)*DIMD + c];
    x2[((size_t)b*NPOOL + tok)*DIMD + c] = val;
    v[i] = val;
  }
  float s = v[0]+v[1]+v[2];
  s = block_sum<256>(s, red);
  float mu = s * (1.f/768.f);
  float sq = 0.f;
  #pragma unroll
  for (int i=0;i<3;i++){ float d = v[i]-mu; sq += d*d; }
  sq = block_sum<256>(sq, red);
  float rstd = rsqrtf(sq*(1.f/768.f) + 1e-5f);
  #pragma unroll
  for (int i=0;i<3;i++){
    int c = t + i*256;
    xn2[((size_t)b*NPOOL + tok)*DIMD + c] = f2bf((v[i]-mu)*rstd*w[c] + bb[c]);
  }
}

extern "C" void kernel_launch(void* const* d_in, const int* in_sizes, int n_in,
                              void* d_out, int out_size, void* d_ws, size_t ws_size,
                              hipStream_t stream){
  (void)in_sizes; (void)n_in; (void)out_size; (void)ws_size;
  const float* x      = (const float*)d_in[0];
  const float* n1_w   = (const float*)d_in[1];
  const float* n1_b   = (const float*)d_in[2];
  const float* wq     = (const float*)d_in[3];
  const float* bq     = (const float*)d_in[4];
  const float* wk     = (const float*)d_in[5];
  const float* bk     = (const float*)d_in[6];
  const float* wv     = (const float*)d_in[7];
  const float* bv     = (const float*)d_in[8];
  const float* pq_w   = (const float*)d_in[9];
  const float* pk_w   = (const float*)d_in[10];
  const float* pv_w   = (const float*)d_in[11];
  const float* nq_w   = (const float*)d_in[12];
  const float* nq_b   = (const float*)d_in[13];
  const float* nk_w   = (const float*)d_in[14];
  const float* nk_b   = (const float*)d_in[15];
  const float* nv_w   = (const float*)d_in[16];
  const float* nv_b   = (const float*)d_in[17];
  const float* proj_w = (const float*)d_in[18];
  const float* proj_b = (const float*)d_in[19];
  const float* n2_w   = (const float*)d_in[20];
  const float* n2_b   = (const float*)d_in[21];
  const float* fc1_w  = (const float*)d_in[22];
  const float* fc1_b  = (const float*)d_in[23];
  const float* fc2_w  = (const float*)d_in[24];
  const float* fc2_b  = (const float*)d_in[25];
  float* out = (float*)d_out;

  char* ws = (char*)d_ws;
  size_t off = 0;
  auto take = [&](size_t bytes)->char*{
    char* p = ws + off; off = (off + bytes + 255) & ~(size_t)255; return p;
  };
  short* xn  = (short*)take(38541312);       // 25092*768 bf16
  short* wqb = (short*)take(1179648);        // wqb/wkb/wvb contiguous -> one [2304][768] matrix
  short* wkb = (short*)take(1179648);
  short* wvb = (short*)take(1179648);
  short* wpb = (short*)take(1179648);
  short* w1b = (short*)take(4718592);
  short* w2b = (short*)take(4718592);
  float* bcat= (float*)take(9216);           // packed [bq|bk|bv]
  char*  big = take(115623936);              // phase1: linear qkv [25092][2304]; phase2: oattn/oproj/x2/xn2/h1
  short* qkv  = (short*)(big);               // 115623936 B exactly
  short* oattn= (short*)(big);               // 9639936 B
  float* oproj= (float*)(big + 9639936);     // 19279872 B
  float* x2   = (float*)(big + 28919808);    // 19279872 B
  short* xn2  = (short*)(big + 48199680);    // 9639936 B
  short* h1   = (short*)(big + 57839616);    // 38559744 B
  short* qp   = (short*)take(9830400);       // 32*1600*96 bf16
  short* kp   = (short*)take(9830400);
  short* vT   = (short*)take(9830400);

  castw<<<dim3(2304,6), 256, 0, stream>>>(wq,wk,wv,proj_w,fc1_w,fc2_w, wqb,wkb,wvb,wpb,w1b,w2b);
  packb<<<9, 256, 0, stream>>>(bq, bk, bv, bcat);
  ln768<<<6273, 256, 0, stream>>>(x, n1_w, n1_b, xn);

  // fused QKV: 256x256 gemm8 (R5, 144.7us proven); grid 9x99 = 891 blocks
  gemm8<<<dim3(9,99), 512, 0, stream>>>(xn, wqb, bcat, qkv, MROWS, 2304, 768);

  pool_conv3<<<dim3(32,14,3), 256, 0, stream>>>(qkv, pq_w, pk_w, pv_w,
                                                nq_w, nq_b, nk_w, nk_b, nv_w, nv_b, qp, kp, vT);
  cls3<<<dim3(B_), 128, 0, stream>>>(qkv, nq_w, nq_b, nk_w, nk_b, nv_w, nv_b, qp, kp, vT);
  padfill<<<dim3(31,32), 96, 0, stream>>>(qp, kp, vT);

  attn_k<<<dim3(13,32), 512, 0, stream>>>(qp, kp, vT, oattn);

  // proj: 64-row tiles -> grid 6x99 = 594 blocks (2-3 blocks/CU vs 1 before)
  gemm_n64<0><<<dim3(6,99), 256, 0, stream>>>(oattn, wpb, proj_b, nullptr, oproj, M2, 768, 768);

  skip_ln2<<<dim3(NPOOL,B_), 256, 0, stream>>>(x, oproj, n2_w, n2_b, x2, xn2);

  // fc1: 50x24 tiles, supertile 10x8 (bf16 out -> wide epilogue)
  gemm_bt<1,1,0,10,8><<<dim3(24,50), 256, 0, stream>>>(xn2, w1b, fc1_b, nullptr, nullptr, h1, M2, HID, 768);
  // fc2: 64-row tiles, K=3072 -> grid 6x99 = 594 blocks
  gemm_n64<1><<<dim3(6,99), 256, 0, stream>>>(h1, w2b, fc2_b, x2, out, M2, 768, 3072);
}

// Round 8
// 571.250 us; speedup vs baseline: 1.1046x; 1.0497x over previous
//
#include <hip/hip_runtime.h>
#include <math.h>

#define B_ 4
#define NTOK 6273
#define DIMD 768
#define HEADS 8
#define HD 96
#define NPOOL 1569
#define NPAD 1600
#define HID 3072
#define MROWS (B_*NTOK)   // 25092
#define M2 (B_*NPOOL)     // 6276
#define SCALE_ 0.10206207261596575f

typedef float f32x4 __attribute__((ext_vector_type(4)));
typedef short s16x8 __attribute__((ext_vector_type(8)));
typedef short s16x4 __attribute__((ext_vector_type(4)));
typedef unsigned u32x3 __attribute__((ext_vector_type(3)));

__device__ __forceinline__ short f2bf(float f){
  unsigned u = __builtin_bit_cast(unsigned, f);
  u = (u + 0x7fffu + ((u >> 16) & 1u)) >> 16;
  return (short)u;
}
__device__ __forceinline__ float bf2f(short s){
  unsigned u = ((unsigned)(unsigned short)s) << 16;
  return __builtin_bit_cast(float, u);
}
__device__ __forceinline__ float bfsel(unsigned u, int hi){
  unsigned r = hi ? (u & 0xffff0000u) : (u << 16);
  return __builtin_bit_cast(float, r);
}
__device__ __forceinline__ unsigned pack2(float lo, float hi){
  return (unsigned)(unsigned short)f2bf(lo) | ((unsigned)(unsigned short)f2bf(hi) << 16);
}

__device__ __forceinline__ void gld16(const void* g, void* l){
  __builtin_amdgcn_global_load_lds((const __attribute__((address_space(1))) unsigned*)g,
                                   (__attribute__((address_space(3))) unsigned*)l, 16, 0, 0);
}

#if defined(__has_builtin)
#if __has_builtin(__builtin_amdgcn_mfma_f32_16x16x16bf16_1k)
#define MFMA16K(a,b,c) __builtin_amdgcn_mfma_f32_16x16x16bf16_1k(a,b,c,0,0,0)
#endif
#endif
#ifndef MFMA16K
__device__ __forceinline__ f32x4 mfma16k_asm(s16x4 a, s16x4 b, f32x4 c){
  asm volatile("v_mfma_f32_16x16x16_bf16 %0, %1, %2, %0\n\ts_nop 7\n\ts_nop 7"
               : "+v"(c) : "v"(a), "v"(b));
  return c;
}
#define MFMA16K(a,b,c) mfma16k_asm(a,b,c)
#endif

// ---- XCD-chunked serial (m204 bijection): contiguous serial range per XCD ----
__device__ __forceinline__ unsigned xcd_serial(unsigned bid, unsigned nwg){
  unsigned q = nwg >> 3, r8 = nwg & 7;
  unsigned xcd = bid & 7, idx = bid >> 3;
  return (xcd < r8 ? xcd*(q+1) : r8*(q+1) + (xcd-r8)*q) + idx;
}

// supertile decode: STR x STC tiles per supertile, row-fast within col.
template<int STR, int STC>
__device__ __forceinline__ void tile_decode(unsigned serial, int& rowT, int& colT){
  const int nStC = (int)gridDim.x / STC;
  int st = (int)serial / (STR*STC);
  int t  = (int)serial - st*(STR*STC);
  int stR = st / nStC, stC = st - stR*nStC;
  int c = t / STR, r = t - c*STR;
  rowT = stR*STR + r;
  colT = stC*STC + c;
}

// ---- fused prologue (R8): y==0 -> ln768 (wave-per-row, zero barriers);
//      y==1 -> weight cast fp32->bf16 (grid-stride over all 6 matrices) + bias pack.
// Replaces 3 launches (castw, packb, ln768) with 1; the two memory-bound phases overlap.
__global__ __launch_bounds__(256) void prologue(
    const float* __restrict__ x, const float* __restrict__ n1w, const float* __restrict__ n1b,
    short* __restrict__ xn,
    const float* __restrict__ wq, const float* __restrict__ wk, const float* __restrict__ wv,
    const float* __restrict__ wp, const float* __restrict__ w1, const float* __restrict__ w2,
    short* __restrict__ wqb, short* __restrict__ wkb, short* __restrict__ wvb,
    short* __restrict__ wpb, short* __restrict__ w1b, short* __restrict__ w2b,
    const float* __restrict__ bq, const float* __restrict__ bk, const float* __restrict__ bv,
    float* __restrict__ bcat){
  if (blockIdx.y == 0){
    int row = blockIdx.x*4 + (threadIdx.x >> 6);
    int lane = threadIdx.x & 63;
    const float* xr = x + (size_t)row*DIMD + lane*12;
    f32x4 v0 = *(const f32x4*)(xr);
    f32x4 v1 = *(const f32x4*)(xr + 4);
    f32x4 v2 = *(const f32x4*)(xr + 8);
    float v[12] = { v0[0],v0[1],v0[2],v0[3], v1[0],v1[1],v1[2],v1[3], v2[0],v2[1],v2[2],v2[3] };
    float s = 0.f;
    #pragma unroll
    for (int j=0;j<12;j++) s += v[j];
    #pragma unroll
    for (int m=1; m<64; m<<=1) s += __shfl_xor(s, m);
    float mu = s * (1.f/768.f);
    float sq = 0.f;
    #pragma unroll
    for (int j=0;j<12;j++){ float d = v[j]-mu; sq += d*d; }
    #pragma unroll
    for (int m=1; m<64; m<<=1) sq += __shfl_xor(sq, m);
    float rstd = rsqrtf(sq*(1.f/768.f) + 1e-5f);
    int c0 = lane*12;
    float o[12];
    #pragma unroll
    for (int j=0;j<12;j++) o[j] = (v[j]-mu)*rstd*n1w[c0+j] + n1b[c0+j];
    unsigned* po = (unsigned*)(xn + (size_t)row*DIMD + c0);
    #pragma unroll
    for (int k=0;k<6;k++) po[k] = pack2(o[2*k], o[2*k+1]);
  } else {
    unsigned gid = blockIdx.x*256u + threadIdx.x;
    if (gid < 768u) bcat[gid] = bq[gid];
    else if (gid < 1536u) bcat[gid] = bk[gid-768u];
    else if (gid < 2304u) bcat[gid] = bv[gid-1536u];
    for (unsigned i = gid; i < 7077888u; i += 6273u*256u){
      const float* s; short* d; unsigned off;
      if (i < 2359296u){
        unsigned r = i / 589824u; off = i - r*589824u;
        s = (r==0)?wq:(r==1)?wk:(r==2)?wv:wp;
        d = (r==0)?wqb:(r==1)?wkb:(r==2)?wvb:wpb;
      } else if (i < 4718592u){ off = i - 2359296u; s = w1; d = w1b; }
      else                    { off = i - 4718592u; s = w2; d = w2b; }
      d[off] = f2bf(s[off]);
    }
  }
}

// ================= 256x256 GEMM, 8 waves, 4-slot BK=32 depth-3 pipeline (R5, PROVEN 144.7us) ====
// R6: 8-phase restructure NULL; R0-R2 schedule variants null once write path fixed. Stands.
__global__ __launch_bounds__(512) void gemm8(const short* __restrict__ A, const short* __restrict__ Bw,
                        const float* __restrict__ bias, short* __restrict__ Cb,
                        int M, int N, int K){
  __shared__ short lds[4][16384];   // slot: A 0..8191 | B 8192..16383 (BK=32); epilogue: 128KB C tile
  int tid = threadIdx.x;
  int w = tid >> 6, lane = tid & 63;
  int l15 = lane & 15, g = (lane >> 4) & 3;
  int wr = w >> 2, wc = w & 3;

  unsigned nwg = gridDim.x * gridDim.y;
  unsigned bid = blockIdx.y * gridDim.x + blockIdx.x;
  unsigned serial = bid;
  if (nwg >= 512) serial = xcd_serial(bid, nwg);
  int rowBase = (int)(serial / gridDim.x) * 256;
  int colBase = (int)(serial % gridDim.x) * 256;

  const short* pa[2]; const short* pb[2];
  #pragma unroll
  for (int j=0;j<2;j++){
    int mr = rowBase + (w + j*8)*16 + l15; if (mr >= M) mr = M-1;
    int nr = colBase + (w + j*8)*16 + l15;           // N always multiple of 256
    pa[j] = A  + (size_t)mr*K + g*8;
    pb[j] = Bw + (size_t)nr*K + g*8;
  }
  int sd = tid*8;

  auto stage = [&](int slot, int p){
    int koff = p*32;
    short* base = &lds[slot][0];
    #pragma unroll
    for (int j=0;j<2;j++){
      gld16(pa[j] + koff, base + sd + j*4096);
      gld16(pb[j] + koff, base + 8192 + sd + j*4096);
    }
  };

  f32x4 acc[8][4] = {};
  int np = K >> 5;   // 24 phases of BK=32
  stage(0, 0);
  if (np > 1) stage(1, 1);
  if (np > 2) stage(2, 2);          // 12 loads outstanding, 3 phases deep
  for (int p = 0; p < np; p++){
    if (p <= np-3)
      asm volatile("s_waitcnt vmcnt(8)" ::: "memory");   // retire phase-p's 4; p+1,p+2 in flight
    else if (p == np-2)
      asm volatile("s_waitcnt vmcnt(4)" ::: "memory");
    else
      asm volatile("s_waitcnt vmcnt(0)" ::: "memory");
    __builtin_amdgcn_s_barrier();
    if (p + 3 < np) stage((p+3)&3, p+3);
    const short* lA = &lds[p&3][0];
    const short* lB = lA + 8192;
    s16x8 bfr[4];
    #pragma unroll
    for (int nf=0; nf<4; nf++)
      bfr[nf] = *(const s16x8*)(lB + (wc*4+nf)*512 + lane*8);
    __builtin_amdgcn_s_setprio(1);
    #pragma unroll
    for (int mf=0; mf<8; mf++){
      s16x8 af = *(const s16x8*)(lA + (wr*8+mf)*512 + lane*8);
      #pragma unroll
      for (int nf=0; nf<4; nf++)
        acc[mf][nf] = __builtin_amdgcn_mfma_f32_16x16x32_bf16(af, bfr[nf], acc[mf][nf], 0,0,0);
    }
    __builtin_amdgcn_s_setprio(0);
  }

  // ---- wide epilogue: all waves done reading slots, reuse full 128KB as C tile ----
  __syncthreads();
  short* ldsC = &lds[0][0];   // 65536 shorts; row = 256 shorts (512B), chunk = 8 shorts (16B)
  #pragma unroll
  for (int mf=0; mf<8; mf++){
    int rowL0 = wr*128 + mf*16 + g*4;
    #pragma unroll
    for (int nf=0; nf<4; nf++){
      int colL = wc*64 + nf*16 + l15;
      float bv = bias[colBase + colL];
      int ch = colL >> 3, in8 = colL & 7;
      #pragma unroll
      for (int r=0;r<4;r++){
        int rL = rowL0 + r;
        int chs = ch ^ ((rL >> 2) & 7);   // bank-XOR: spreads the 4 g-rows across chunk groups
        ldsC[rL*256 + chs*8 + in8] = f2bf(acc[mf][nf][r] + bv);
      }
    }
  }
  __syncthreads();
  int ch2 = tid & 31, rg = tid >> 5;   // 32 chunks/row; 16 rows per pass
  #pragma unroll
  for (int i=0;i<16;i++){
    int rowL = rg + i*16;
    int chs = ch2 ^ ((rowL >> 2) & 7);
    s16x8 v = *(const s16x8*)(ldsC + rowL*256 + chs*8);
    int rr = rowBase + rowL;
    if (rr < M) *(s16x8*)(Cb + (size_t)rr*N + colBase + ch2*8) = v;
  }
}

// ---- bf16 GEMM, 2-phase 128x128 (proven m97 structure): fc1.
// bf16 outputs via R4 wide LDS-transposed epilogue.
template<int GELU, int OUTBF16, int RESID, int STR, int STC>
__global__ __launch_bounds__(256) void gemm_bt(const short* __restrict__ A, const short* __restrict__ Bw,
                        const float* __restrict__ bias, const float* __restrict__ resid,
                        float* __restrict__ Cf, short* __restrict__ Cb,
                        int M, int N, int K){
  __shared__ short lds[3][8192];   // [buf][ A:0..4095 | B:4096..8191 ]; epilogue reuses 32KB as C tile
  int tid = threadIdx.x;
  int lane = tid & 63, wv = tid >> 6;
  int wr = wv >> 1, wc = wv & 1;
  int l15 = lane & 15, g = lane >> 4;

  unsigned nwg = gridDim.x * gridDim.y;
  unsigned bid = blockIdx.y * gridDim.x + blockIdx.x;
  unsigned serial = xcd_serial(bid, nwg);
  int rowT, colT;
  tile_decode<STR,STC>(serial, rowT, colT);
  int rowBase = rowT * 128;
  int colBase = colT * 128;

  f32x4 acc[4][4] = {};
  int srow = (tid & 15) | ((tid >> 6) << 4);   // 0..63
  int scol = ((tid >> 4) & 3) * 8;
  int ldsoff = tid * 8;

  int ar0 = rowBase + srow;      if (ar0 >= M) ar0 = M-1;
  int ar1 = rowBase + srow + 64; if (ar1 >= M) ar1 = M-1;
  int br0 = colBase + srow;      // N always multiple of 128
  const short* pa0 = A  + (size_t)ar0*K + scol;
  const short* pa1 = A  + (size_t)ar1*K + scol;
  const short* pb0 = Bw + (size_t)br0*K + scol;
  const short* pb1 = Bw + (size_t)(br0+64)*K + scol;

  auto stage = [&](int s, int kt){
    gld16(pa0 + kt, &lds[s][ldsoff]);
    gld16(pa1 + kt, &lds[s][ldsoff + 2048]);
    gld16(pb0 + kt, &lds[s][4096 + ldsoff]);
    gld16(pb1 + kt, &lds[s][4096 + ldsoff + 2048]);
  };

  int nk = K >> 5;
  stage(0, 0);
  if (nk > 1) stage(1, 32);
  for (int kt = 0; kt < nk; kt++){
    int cur = kt % 3;
    if (kt + 2 < nk){
      stage((kt+2)%3, (kt+2)*32);
      asm volatile("s_waitcnt vmcnt(8)" ::: "memory");
    } else if (kt + 1 < nk){
      asm volatile("s_waitcnt vmcnt(4)" ::: "memory");
    } else {
      asm volatile("s_waitcnt vmcnt(0)" ::: "memory");
    }
    __builtin_amdgcn_s_barrier();
    const short* la = lds[cur];
    const short* lb = lds[cur] + 4096;
    s16x8 af[4], bfr[4];
    #pragma unroll
    for (int m=0;m<4;m++) af[m]  = *(const s16x8*)(la + (wr*4 + m)*512 + g*128 + l15*8);
    #pragma unroll
    for (int n=0;n<4;n++) bfr[n] = *(const s16x8*)(lb + (wc*4 + n)*512 + g*128 + l15*8);
    #pragma unroll
    for (int m=0;m<4;m++)
      #pragma unroll
      for (int n=0;n<4;n++)
        acc[m][n] = __builtin_amdgcn_mfma_f32_16x16x32_bf16(af[m], bfr[n], acc[m][n], 0,0,0);
    __builtin_amdgcn_s_barrier();
  }

  if (OUTBF16){
    short* ldsC = &lds[0][0];
    #pragma unroll
    for (int n=0;n<4;n++){
      int colL = wc*64 + n*16 + l15;
      float bv = bias[colBase + colL];
      #pragma unroll
      for (int m=0;m<4;m++){
        #pragma unroll
        for (int r=0;r<4;r++){
          int rowL = wr*64 + m*16 + g*4 + r;
          float v = acc[m][n][r] + bv;
          if (GELU) v = 0.5f*v*(1.f + erff(v*0.70710678118654752f));
          int ch = colL >> 3, in8 = colL & 7;
          int chs = ch ^ (((rowL >> 2) & 3) << 2);
          ldsC[rowL*128 + chs*8 + in8] = f2bf(v);
        }
      }
    }
    __syncthreads();
    int ch = tid & 15, rg = tid >> 4;
    #pragma unroll
    for (int i=0;i<8;i++){
      int rowL = rg + i*16;
      int chs = ch ^ (((rowL >> 2) & 3) << 2);
      s16x8 v = *(const s16x8*)(ldsC + rowL*128 + chs*8);
      int rr = rowBase + rowL;
      if (rr < M) *(s16x8*)(Cb + (size_t)rr*N + colBase + ch*8) = v;
    }
  } else {
    #pragma unroll
    for (int m=0;m<4;m++){
      int row = rowBase + wr*64 + m*16 + g*4;
      #pragma unroll
      for (int n=0;n<4;n++){
        int col = colBase + wc*64 + n*16 + l15;
        float bv = bias[col];
        #pragma unroll
        for (int r=0;r<4;r++){
          int rr = row + r;
          if (rr < M){
            float v = acc[m][n][r] + bv;
            if (GELU) v = 0.5f*v*(1.f + erff(v*0.70710678118654752f));
            if (RESID) v += resid[(size_t)rr*N + col];
            Cf[(size_t)rr*N + col] = v;
          }
        }
      }
    }
  }
}

// ---- 64x128-tile fp32-out GEMM (proj, fc2): proven R7 (+15us total) ----
template<int RESID>
__global__ __launch_bounds__(256) void gemm_n64(const short* __restrict__ A, const short* __restrict__ Bw,
                        const float* __restrict__ bias, const float* __restrict__ resid,
                        float* __restrict__ Cf, int M, int N, int K){
  __shared__ short lds[3][6144];   // [buf][ A:0..2047 (64x32) | B:2048..6143 (128x32) ]
  int tid = threadIdx.x;
  int lane = tid & 63, wc = tid >> 6;       // 4 waves across the 128 cols
  int l15 = lane & 15, g = lane >> 4;

  unsigned nwg = gridDim.x * gridDim.y;     // 6*99 = 594
  unsigned bid = blockIdx.y * gridDim.x + blockIdx.x;
  unsigned serial = xcd_serial(bid, nwg);
  int rowBase = (int)(serial / gridDim.x) * 64;    // col-fast within each XCD chunk
  int colBase = (int)(serial % gridDim.x) * 128;

  f32x4 acc[4][2] = {};
  int srow = (tid & 15) | ((tid >> 6) << 4);   // 0..63
  int scol = ((tid >> 4) & 3) * 8;
  int ldsoff = tid * 8;

  int ar = rowBase + srow; if (ar >= M) ar = M-1;
  int br = colBase + srow;                      // N multiple of 128
  const short* pa  = A  + (size_t)ar*K + scol;
  const short* pb0 = Bw + (size_t)br*K + scol;
  const short* pb1 = Bw + (size_t)(br+64)*K + scol;

  auto stage = [&](int s, int kt){
    gld16(pa  + kt, &lds[s][ldsoff]);
    gld16(pb0 + kt, &lds[s][2048 + ldsoff]);
    gld16(pb1 + kt, &lds[s][4096 + ldsoff]);
  };

  int nk = K >> 5;
  stage(0, 0);
  if (nk > 1) stage(1, 32);
  for (int kt = 0; kt < nk; kt++){
    int cur = kt % 3;
    if (kt + 2 < nk){
      stage((kt+2)%3, (kt+2)*32);
      asm volatile("s_waitcnt vmcnt(6)" ::: "memory");   // oldest 3 = stage(kt) landed
    } else if (kt + 1 < nk){
      asm volatile("s_waitcnt vmcnt(3)" ::: "memory");
    } else {
      asm volatile("s_waitcnt vmcnt(0)" ::: "memory");
    }
    __builtin_amdgcn_s_barrier();
    const short* la = lds[cur];
    const short* lb = lds[cur] + 2048;
    s16x8 af[4], bfr[2];
    #pragma unroll
    for (int m=0;m<4;m++) af[m]  = *(const s16x8*)(la + m*512 + g*128 + l15*8);
    #pragma unroll
    for (int n=0;n<2;n++) bfr[n] = *(const s16x8*)(lb + (wc*2 + n)*512 + g*128 + l15*8);
    #pragma unroll
    for (int m=0;m<4;m++)
      #pragma unroll
      for (int n=0;n<2;n++)
        acc[m][n] = __builtin_amdgcn_mfma_f32_16x16x32_bf16(af[m], bfr[n], acc[m][n], 0,0,0);
    __builtin_amdgcn_s_barrier();
  }
  #pragma unroll
  for (int m=0;m<4;m++){
    int row = rowBase + m*16 + g*4;
    #pragma unroll
    for (int n=0;n<2;n++){
      int col = colBase + wc*32 + n*16 + l15;
      float bv = bias[col];
      #pragma unroll
      for (int r=0;r<4;r++){
        int rr = row + r;
        if (rr < M){
          float v = acc[m][n][r] + bv;
          if (RESID) v += resid[(size_t)rr*N + col];
          Cf[(size_t)rr*N + col] = v;
        }
      }
    }
  }
}

// ---- fused attention pooling conv for q,k,v (one launch) + LN over 96.
// Reads the LINEAR qkv buffer [b*NTOK+tok][2304] (col = z*768 + h*96 + d).
// R8: ho==14 plane (96 aux blocks) absorbs cls3 + padfill -> 2 fewer launches.
__global__ __launch_bounds__(256, 2) void pool_conv3(
    const short* __restrict__ raw,
    const float* __restrict__ cwq, const float* __restrict__ cwk, const float* __restrict__ cwv,
    const float* __restrict__ nqw, const float* __restrict__ nqb,
    const float* __restrict__ nkw, const float* __restrict__ nkb,
    const float* __restrict__ nvw, const float* __restrict__ nvb,
    short* __restrict__ qo, short* __restrict__ ko, short* __restrict__ vo){
  unsigned nwg = gridDim.x * gridDim.y * gridDim.z;   // 32*15*3 = 1440
  unsigned lin = (blockIdx.z*gridDim.y + blockIdx.y)*gridDim.x + blockIdx.x;
  unsigned serial = xcd_serial(lin, nwg);
  int ho = (int)(serial % 15);
  unsigned rest = serial / 15;
  int bh = (int)(rest & 31);
  int z  = (int)(rest >> 5);
  int t = threadIdx.x;
  const float* nw = (z==0) ? nqw : (z==1) ? nkw : nvw;
  const float* nb = (z==0) ? nqb : (z==1) ? nkb : nvb;

  if (ho == 14){
    // --- aux block: cls-token LN + pad-fill for this (bh, z) ---
    if (t < 16){
      int s2 = t, d2 = s2*6;
      const short* row = raw + (size_t)(bh>>3)*NTOK*2304 + z*768 + (bh&7)*96 + d2;
      u32x3 u = *(const u32x3*)(row);
      float a[6] = { bfsel(u[0],0), bfsel(u[0],1), bfsel(u[1],0), bfsel(u[1],1), bfsel(u[2],0), bfsel(u[2],1) };
      float sm = a[0]+a[1]+a[2]+a[3]+a[4]+a[5];
      #pragma unroll
      for (int m=1; m<16; m<<=1) sm += __shfl_xor(sm, m);
      float mu = sm*(1.f/96.f);
      float vr2 = 0.f;
      #pragma unroll
      for (int j=0;j<6;j++){ float dd = a[j]-mu; vr2 += dd*dd; }
      #pragma unroll
      for (int m=1; m<16; m<<=1) vr2 += __shfl_xor(vr2, m);
      float rstd = rsqrtf(vr2*(1.f/96.f) + 1e-5f);
      #pragma unroll
      for (int j=0;j<6;j++){
        int dj = d2 + j;
        short o = f2bf((a[j]-mu)*rstd*nw[dj] + nb[dj]);
        if (z == 0)      qo[((size_t)bh*NPAD)*96 + dj] = o;
        else if (z == 1) ko[(size_t)bh*NPAD*96 + (dj>>5)*512 + ((dj>>3)&3)*128 + (dj&7)] = o;
        else             vo[(size_t)bh*NPAD*96 + (dj>>4)*1024 + (dj&15)*4] = o;
      }
    }
    for (int i = t; i < 31*96; i += 256){
      int tok = NPOOL + i/96;
      int dd = i - (i/96)*96;
      if (z == 0) qo[((size_t)bh*NPAD + tok)*96 + dd] = 0;
      else if (z == 1){
        size_t kb = (size_t)bh*NPAD*96 + (size_t)(tok>>4)*1536 + (tok&15)*8;
        ko[kb + (dd>>5)*512 + ((dd>>3)&3)*128 + (dd&7)] = 0;
      } else {
        size_t vb = (size_t)bh*NPAD*96 + (size_t)(tok>>6)*6144 + ((tok>>4)&3)*256 + ((tok>>2)&3)*64 + (tok&3);
        vo[vb + (dd>>4)*1024 + (dd&15)*4] = 0;
      }
    }
    return;
  }

  int g = t >> 4;        // wo
  if (g >= 14) return;
  int s = t & 15, d = s*6;
  const float* cw = (z==0) ? cwq : (z==1) ? cwk : cwv;
  const short* base = raw + (size_t)(bh>>3)*NTOK*2304 + z*768 + (bh&7)*96 + d;
  float acc[8][6] = {};
  #pragma unroll
  for (int dh=0; dh<3; dh++){
    int ih = 2*ho - 1 + dh;
    if (ih < 0 || ih >= 28) continue;
    #pragma unroll
    for (int dw=0; dw<3; dw++){
      int iw = 2*g - 1 + dw;
      if (iw < 0 || iw >= 28) continue;
      float w[3][6];
      #pragma unroll
      for (int dt=0; dt<3; dt++)
        #pragma unroll
        for (int j=0;j<6;j++)
          w[dt][j] = cw[(d+j)*27 + dt*9 + dh*3 + dw];
      #pragma unroll
      for (int it=0; it<8; it++){
        u32x3 u = *(const u32x3*)(base + (size_t)(1 + (it*28+ih)*28 + iw)*2304);
        float in[6] = { bfsel(u[0],0), bfsel(u[0],1), bfsel(u[1],0),
                        bfsel(u[1],1), bfsel(u[2],0), bfsel(u[2],1) };
        #pragma unroll
        for (int dt=0; dt<3; dt++){
          int to = it + 1 - dt;                // compile-time per unrolled iter
          if (to < 0 || to > 7) continue;
          #pragma unroll
          for (int j=0;j<6;j++) acc[to][j] = fmaf(in[j], w[dt][j], acc[to][j]);
        }
      }
    }
  }
  float nwv[6], nbv[6];
  #pragma unroll
  for (int j=0;j<6;j++){ nwv[j] = nw[d+j]; nbv[j] = nb[d+j]; }
  #pragma unroll
  for (int to=0; to<8; to++){
    float sm = acc[to][0]+acc[to][1]+acc[to][2]+acc[to][3]+acc[to][4]+acc[to][5];
    #pragma unroll
    for (int m=1; m<16; m<<=1) sm += __shfl_xor(sm, m);
    float mu = sm*(1.f/96.f);
    float vr = 0.f;
    #pragma unroll
    for (int j=0;j<6;j++){ float dd = acc[to][j]-mu; vr += dd*dd; }
    #pragma unroll
    for (int m=1; m<16; m<<=1) vr += __shfl_xor(vr, m);
    float rstd = rsqrtf(vr*(1.f/96.f) + 1e-5f);
    int tok = 1 + to*196 + ho*14 + g;
    if (z == 0){
      short o[6];
      #pragma unroll
      for (int j=0;j<6;j++) o[j] = f2bf((acc[to][j]-mu)*rstd*nwv[j] + nbv[j]);
      unsigned* q32 = (unsigned*)(qo + ((size_t)bh*NPAD + tok)*96 + d);
      #pragma unroll
      for (int w2=0; w2<3; w2++)
        q32[w2] = (unsigned)(unsigned short)o[2*w2] | ((unsigned)(unsigned short)o[2*w2+1] << 16);
    } else if (z == 1){
      size_t kb = (size_t)bh*NPAD*96 + (size_t)(tok>>4)*1536 + (tok&15)*8;
      #pragma unroll
      for (int j=0;j<6;j++){
        int dj = d + j;
        ko[kb + (dj>>5)*512 + ((dj>>3)&3)*128 + (dj&7)] = f2bf((acc[to][j]-mu)*rstd*nwv[j] + nbv[j]);
      }
    } else {
      size_t vb = (size_t)bh*NPAD*96 + (size_t)(tok>>6)*6144 + ((tok>>4)&3)*256 + ((tok>>2)&3)*64 + (tok&3);
      #pragma unroll
      for (int j=0;j<6;j++){
        int dj = d + j;
        vo[vb + (dj>>4)*1024 + (dj&15)*4] = f2bf((acc[to][j]-mu)*rstd*nwv[j] + nbv[j]);
      }
    }
  }
}

// ---- flash attention, 8 waves/block (128 q-rows).
// XCD mapping: bh-major chunks -> each XCD owns exactly 4 bh; K/V L2-resident.
__global__ __launch_bounds__(512) void attn_k(const short* __restrict__ qp, const short* __restrict__ kp,
                       const short* __restrict__ vp, short* __restrict__ oattn){
  const float M0 = 6.0f;
  __shared__ short lkv[2][12288];   // [buf][ K:0..6143 | V:6144..12287 ]
  unsigned nwg = gridDim.x * gridDim.y;   // 13*32 = 416
  unsigned bid0 = blockIdx.y * gridDim.x + blockIdx.x;
  unsigned serial = xcd_serial(bid0, nwg);
  int bh = (int)(serial / 13);
  int qblk = (int)(serial - (unsigned)bh*13);
  int b = bh >> 3, h = bh & 7;
  int tid = threadIdx.x;
  int lane = tid & 63, wv = tid >> 6;
  int l15 = lane & 15, g = lane >> 4;
  int qi = qblk*128 + wv*16 + l15;
  int qi_ld = qi < NPAD ? qi : NPAD-1;        // clamp; pad rows are zeroed, writes masked below
  const short* qbase = qp + (size_t)bh*NPAD*HD;
  const short* kbase = kp + (size_t)bh*NPAD*HD;
  const short* vbase = vp + (size_t)bh*NPAD*HD;
  s16x8 qf[3];
  #pragma unroll
  for (int f=0; f<3; f++)
    qf[f] = *(const s16x8*)(qbase + (size_t)qi_ld*HD + f*32 + g*8);

  // stage chunk t: 12288 shorts (K 6144 | V 6144); 512 threads x 3 gld16, wave-uniform K/V branch
  auto stage = [&](int bsel, int t){
    #pragma unroll
    for (int i=0;i<3;i++){
      int off = i*4096 + tid*8;
      const short* src = (off < 6144) ? (kbase + t*6144 + off) : (vbase + t*6144 + off - 6144);
      gld16(src, &lkv[bsel][off]);
    }
  };

  f32x4 accO[6] = {};
  float tsum = 0.f;

  stage(0, 0);
  asm volatile("s_waitcnt vmcnt(0)" ::: "memory");
  __builtin_amdgcn_s_barrier();

  for (int kt = 0; kt < 25; kt++){
    int cur = kt & 1;
    if (kt < 24){
      stage(cur^1, kt+1);
      asm volatile("s_waitcnt vmcnt(3)" ::: "memory");   // current chunk done; next 3 in flight
    } else {
      asm volatile("s_waitcnt vmcnt(0)" ::: "memory");
    }
    __builtin_amdgcn_s_barrier();

    const short* lkc = &lkv[cur][0];
    const short* lvc = &lkv[cur][6144];
    f32x4 sacc[4];
    #pragma unroll
    for (int sub=0; sub<4; sub++){
      sacc[sub] = (f32x4){0.f,0.f,0.f,0.f};
      #pragma unroll
      for (int f=0; f<3; f++){
        s16x8 kf = *(const s16x8*)(lkc + sub*1536 + f*512 + lane*8);
        sacc[sub] = __builtin_amdgcn_mfma_f32_16x16x32_bf16(kf, qf[f], sacc[sub], 0,0,0);
      }
    }
    s16x4 pf[4];
    if (kt < 24){
      #pragma unroll
      for (int sub=0; sub<4; sub++){
        #pragma unroll
        for (int r=0; r<4; r++){
          float p = __expf(sacc[sub][r]*SCALE_ - M0);
          tsum += p;
          pf[sub][r] = f2bf(p);
        }
      }
    } else {
      #pragma unroll
      for (int sub=0; sub<4; sub++){
        #pragma unroll
        for (int r=0; r<4; r++){
          int ki = kt*64 + sub*16 + g*4 + r;
          float p = (ki < NPOOL) ? __expf(sacc[sub][r]*SCALE_ - M0) : 0.f;
          tsum += p;
          pf[sub][r] = f2bf(p);
        }
      }
    }
    #pragma unroll
    for (int dt=0; dt<6; dt++){
      #pragma unroll
      for (int sub=0; sub<4; sub++){
        s16x4 vf = *(const s16x4*)(lvc + dt*1024 + sub*256 + lane*4);
        accO[dt] = MFMA16K(vf, pf[sub], accO[dt]);
      }
    }
    __builtin_amdgcn_s_barrier();
  }

  tsum += __shfl_xor(tsum, 16);
  tsum += __shfl_xor(tsum, 32);
  if (qi < NPOOL){
    float inv = 1.f / tsum;
    #pragma unroll
    for (int dt=0; dt<6; dt++){
      #pragma unroll
      for (int r=0; r<4; r++){
        int dd = dt*16 + g*4 + r;
        oattn[((size_t)b*NPOOL + qi)*DIMD + h*96 + dd] = f2bf(accO[dt][r] * inv);
      }
    }
  }
}

// ---- maxpool(3x3/s2) skip + proj-out add + LN2 (R8: wave-per-token, ZERO barriers).
// 4 tokens/block, 12 ch/lane, f32x4 loads, shuffle reductions (proven ln768 pattern;
// replaces the 8-barrier tree-reduce version).
__global__ __launch_bounds__(256) void skip_ln2(const float* __restrict__ x, const float* __restrict__ oproj,
                         const float* __restrict__ w, const float* __restrict__ bb,
                         float* __restrict__ x2, short* __restrict__ xn2){
  unsigned serial = xcd_serial(blockIdx.x, gridDim.x);   // 1569 blocks x 4 tokens = 6276
  int ti = (int)serial*4 + (int)(threadIdx.x >> 6);
  int b = ti / NPOOL;
  int tok = ti - b*NPOOL;
  int lane = threadIdx.x & 63;
  int c0 = lane*12;
  float v[12];
  if (tok == 0){
    const float* xr = x + (size_t)b*NTOK*DIMD + c0;
    f32x4 a0 = *(const f32x4*)xr, a1 = *(const f32x4*)(xr+4), a2 = *(const f32x4*)(xr+8);
    #pragma unroll
    for (int j=0;j<4;j++){ v[j]=a0[j]; v[4+j]=a1[j]; v[8+j]=a2[j]; }
  } else {
    int ot = tok - 1;
    int to = ot/196, rem = ot%196, ho = rem/14, wo = rem%14;
    #pragma unroll
    for (int j=0;j<12;j++) v[j] = -INFINITY;
    #pragma unroll
    for (int dh=0; dh<3; dh++){
      int ih = 2*ho - 1 + dh; if (ih < 0 || ih >= 28) continue;
      #pragma unroll
      for (int dw=0; dw<3; dw++){
        int iw = 2*wo - 1 + dw; if (iw < 0 || iw >= 28) continue;
        const float* xr = x + ((size_t)b*NTOK + 1 + (to*28 + ih)*28 + iw)*DIMD + c0;
        f32x4 a0 = *(const f32x4*)xr, a1 = *(const f32x4*)(xr+4), a2 = *(const f32x4*)(xr+8);
        #pragma unroll
        for (int j=0;j<4;j++){
          v[j]   = fmaxf(v[j],   a0[j]);
          v[4+j] = fmaxf(v[4+j], a1[j]);
          v[8+j] = fmaxf(v[8+j], a2[j]);
        }
      }
    }
  }
  const float* opr = oproj + ((size_t)b*NPOOL + tok)*DIMD + c0;
  f32x4 p0 = *(const f32x4*)opr, p1 = *(const f32x4*)(opr+4), p2 = *(const f32x4*)(opr+8);
  #pragma unroll
  for (int j=0;j<4;j++){ v[j]+=p0[j]; v[4+j]+=p1[j]; v[8+j]+=p2[j]; }
  float* x2r = x2 + ((size_t)b*NPOOL + tok)*DIMD + c0;
  f32x4 o0 = {v[0],v[1],v[2],v[3]}, o1 = {v[4],v[5],v[6],v[7]}, o2 = {v[8],v[9],v[10],v[11]};
  *(f32x4*)x2r = o0; *(f32x4*)(x2r+4) = o1; *(f32x4*)(x2r+8) = o2;
  float s = 0.f;
  #pragma unroll
  for (int j=0;j<12;j++) s += v[j];
  #pragma unroll
  for (int m=1; m<64; m<<=1) s += __shfl_xor(s, m);
  float mu = s * (1.f/768.f);
  float sq = 0.f;
  #pragma unroll
  for (int j=0;j<12;j++){ float d = v[j]-mu; sq += d*d; }
  #pragma unroll
  for (int m=1; m<64; m<<=1) sq += __shfl_xor(sq, m);
  float rstd = rsqrtf(sq*(1.f/768.f) + 1e-5f);
  float o[12];
  #pragma unroll
  for (int j=0;j<12;j++) o[j] = (v[j]-mu)*rstd*w[c0+j] + bb[c0+j];
  unsigned* po = (unsigned*)(xn2 + ((size_t)b*NPOOL + tok)*DIMD + c0);
  #pragma unroll
  for (int k=0;k<6;k++) po[k] = pack2(o[2*k], o[2*k+1]);
}

extern "C" void kernel_launch(void* const* d_in, const int* in_sizes, int n_in,
                              void* d_out, int out_size, void* d_ws, size_t ws_size,
                              hipStream_t stream){
  (void)in_sizes; (void)n_in; (void)out_size; (void)ws_size;
  const float* x      = (const float*)d_in[0];
  const float* n1_w   = (const float*)d_in[1];
  const float* n1_b   = (const float*)d_in[2];
  const float* wq     = (const float*)d_in[3];
  const float* bq     = (const float*)d_in[4];
  const float* wk     = (const float*)d_in[5];
  const float* bk     = (const float*)d_in[6];
  const float* wv     = (const float*)d_in[7];
  const float* bv     = (const float*)d_in[8];
  const float* pq_w   = (const float*)d_in[9];
  const float* pk_w   = (const float*)d_in[10];
  const float* pv_w   = (const float*)d_in[11];
  const float* nq_w   = (const float*)d_in[12];
  const float* nq_b   = (const float*)d_in[13];
  const float* nk_w   = (const float*)d_in[14];
  const float* nk_b   = (const float*)d_in[15];
  const float* nv_w   = (const float*)d_in[16];
  const float* nv_b   = (const float*)d_in[17];
  const float* proj_w = (const float*)d_in[18];
  const float* proj_b = (const float*)d_in[19];
  const float* n2_w   = (const float*)d_in[20];
  const float* n2_b   = (const float*)d_in[21];
  const float* fc1_w  = (const float*)d_in[22];
  const float* fc1_b  = (const float*)d_in[23];
  const float* fc2_w  = (const float*)d_in[24];
  const float* fc2_b  = (const float*)d_in[25];
  float* out = (float*)d_out;

  char* ws = (char*)d_ws;
  size_t off = 0;
  auto take = [&](size_t bytes)->char*{
    char* p = ws + off; off = (off + bytes + 255) & ~(size_t)255; return p;
  };
  short* xn  = (short*)take(38541312);       // 25092*768 bf16
  short* wqb = (short*)take(1179648);        // wqb/wkb/wvb contiguous -> one [2304][768] matrix
  short* wkb = (short*)take(1179648);
  short* wvb = (short*)take(1179648);
  short* wpb = (short*)take(1179648);
  short* w1b = (short*)take(4718592);
  short* w2b = (short*)take(4718592);
  float* bcat= (float*)take(9216);           // packed [bq|bk|bv]
  char*  big = take(115623936);              // phase1: linear qkv [25092][2304]; phase2: oattn/oproj/x2/xn2/h1
  short* qkv  = (short*)(big);               // 115623936 B exactly
  short* oattn= (short*)(big);               // 9639936 B
  float* oproj= (float*)(big + 9639936);     // 19279872 B
  float* x2   = (float*)(big + 28919808);    // 19279872 B
  short* xn2  = (short*)(big + 48199680);    // 9639936 B
  short* h1   = (short*)(big + 57839616);    // 38559744 B
  short* qp   = (short*)take(9830400);       // 32*1600*96 bf16
  short* kp   = (short*)take(9830400);
  short* vT   = (short*)take(9830400);

  // fused prologue: LN1 (y=0) + weight cast + bias pack (y=1)
  prologue<<<dim3(6273,2), 256, 0, stream>>>(x, n1_w, n1_b, xn,
      wq, wk, wv, proj_w, fc1_w, fc2_w, wqb, wkb, wvb, wpb, w1b, w2b,
      bq, bk, bv, bcat);

  // fused QKV: 256x256 gemm8 (R5, 144.7us proven); grid 9x99 = 891 blocks
  gemm8<<<dim3(9,99), 512, 0, stream>>>(xn, wqb, bcat, qkv, MROWS, 2304, 768);

  // pool conv + LN(96) + cls + padfill (aux ho==14 plane)
  pool_conv3<<<dim3(32,15,3), 256, 0, stream>>>(qkv, pq_w, pk_w, pv_w,
                                                nq_w, nq_b, nk_w, nk_b, nv_w, nv_b, qp, kp, vT);

  attn_k<<<dim3(13,32), 512, 0, stream>>>(qp, kp, vT, oattn);

  // proj: 64-row tiles -> grid 6x99 = 594 blocks
  gemm_n64<0><<<dim3(6,99), 256, 0, stream>>>(oattn, wpb, proj_b, nullptr, oproj, M2, 768, 768);

  // maxpool skip + LN2: wave-per-token, 1569 blocks, zero barriers
  skip_ln2<<<1569, 256, 0, stream>>>(x, oproj, n2_w, n2_b, x2, xn2);

  // fc1: 50x24 tiles, supertile 10x8 (bf16 out -> wide epilogue)
  gemm_bt<1,1,0,10,8><<<dim3(24,50), 256, 0, stream>>>(xn2, w1b, fc1_b, nullptr, nullptr, h1, M2, HID, 768);
  // fc2: 64-row tiles, K=3072 -> grid 6x99 = 594 blocks
  gemm_n64<1><<<dim3(6,99), 256, 0, stream>>>(h1, w2b, fc2_b, x2, out, M2, 768, 3072);
}

// Round 9
// 568.677 us; speedup vs baseline: 1.1096x; 1.0045x over previous
//
#include <hip/hip_runtime.h>
#include <math.h>

#define B_ 4
#define NTOK 6273
#define DIMD 768
#define HEADS 8
#define HD 96
#define NPOOL 1569
#define NPAD 1600
#define HID 3072
#define MROWS (B_*NTOK)   // 25092
#define M2 (B_*NPOOL)     // 6276
#define SCALE_ 0.10206207261596575f

typedef float f32x4 __attribute__((ext_vector_type(4)));
typedef short s16x8 __attribute__((ext_vector_type(8)));
typedef short s16x4 __attribute__((ext_vector_type(4)));
typedef unsigned u32x3 __attribute__((ext_vector_type(3)));

__device__ __forceinline__ short f2bf(float f){
  unsigned u = __builtin_bit_cast(unsigned, f);
  u = (u + 0x7fffu + ((u >> 16) & 1u)) >> 16;
  return (short)u;
}
__device__ __forceinline__ float bf2f(short s){
  unsigned u = ((unsigned)(unsigned short)s) << 16;
  return __builtin_bit_cast(float, u);
}
__device__ __forceinline__ float bfsel(unsigned u, int hi){
  unsigned r = hi ? (u & 0xffff0000u) : (u << 16);
  return __builtin_bit_cast(float, r);
}
__device__ __forceinline__ unsigned pack2(float lo, float hi){
  return (unsigned)(unsigned short)f2bf(lo) | ((unsigned)(unsigned short)f2bf(hi) << 16);
}

__device__ __forceinline__ void gld16(const void* g, void* l){
  __builtin_amdgcn_global_load_lds((const __attribute__((address_space(1))) unsigned*)g,
                                   (__attribute__((address_space(3))) unsigned*)l, 16, 0, 0);
}

#if defined(__has_builtin)
#if __has_builtin(__builtin_amdgcn_mfma_f32_16x16x16bf16_1k)
#define MFMA16K(a,b,c) __builtin_amdgcn_mfma_f32_16x16x16bf16_1k(a,b,c,0,0,0)
#endif
#endif
#ifndef MFMA16K
__device__ __forceinline__ f32x4 mfma16k_asm(s16x4 a, s16x4 b, f32x4 c){
  asm volatile("v_mfma_f32_16x16x16_bf16 %0, %1, %2, %0\n\ts_nop 7\n\ts_nop 7"
               : "+v"(c) : "v"(a), "v"(b));
  return c;
}
#define MFMA16K(a,b,c) mfma16k_asm(a,b,c)
#endif

// ---- XCD-chunked serial (m204 bijection): contiguous serial range per XCD ----
__device__ __forceinline__ unsigned xcd_serial(unsigned bid, unsigned nwg){
  unsigned q = nwg >> 3, r8 = nwg & 7;
  unsigned xcd = bid & 7, idx = bid >> 3;
  return (xcd < r8 ? xcd*(q+1) : r8*(q+1) + (xcd-r8)*q) + idx;
}

// supertile decode: STR x STC tiles per supertile, row-fast within col.
template<int STR, int STC>
__device__ __forceinline__ void tile_decode(unsigned serial, int& rowT, int& colT){
  const int nStC = (int)gridDim.x / STC;
  int st = (int)serial / (STR*STC);
  int t  = (int)serial - st*(STR*STC);
  int stR = st / nStC, stC = st - stR*nStC;
  int c = t / STR, r = t - c*STR;
  rowT = stR*STR + r;
  colT = stC*STC + c;
}

// ---- fused prologue (R8): y==0 -> ln768 (wave-per-row, zero barriers);
//      y==1 -> weight cast fp32->bf16 (grid-stride over all 6 matrices) + bias pack.
__global__ __launch_bounds__(256) void prologue(
    const float* __restrict__ x, const float* __restrict__ n1w, const float* __restrict__ n1b,
    short* __restrict__ xn,
    const float* __restrict__ wq, const float* __restrict__ wk, const float* __restrict__ wv,
    const float* __restrict__ wp, const float* __restrict__ w1, const float* __restrict__ w2,
    short* __restrict__ wqb, short* __restrict__ wkb, short* __restrict__ wvb,
    short* __restrict__ wpb, short* __restrict__ w1b, short* __restrict__ w2b,
    const float* __restrict__ bq, const float* __restrict__ bk, const float* __restrict__ bv,
    float* __restrict__ bcat){
  if (blockIdx.y == 0){
    int row = blockIdx.x*4 + (threadIdx.x >> 6);
    int lane = threadIdx.x & 63;
    const float* xr = x + (size_t)row*DIMD + lane*12;
    f32x4 v0 = *(const f32x4*)(xr);
    f32x4 v1 = *(const f32x4*)(xr + 4);
    f32x4 v2 = *(const f32x4*)(xr + 8);
    float v[12] = { v0[0],v0[1],v0[2],v0[3], v1[0],v1[1],v1[2],v1[3], v2[0],v2[1],v2[2],v2[3] };
    float s = 0.f;
    #pragma unroll
    for (int j=0;j<12;j++) s += v[j];
    #pragma unroll
    for (int m=1; m<64; m<<=1) s += __shfl_xor(s, m);
    float mu = s * (1.f/768.f);
    float sq = 0.f;
    #pragma unroll
    for (int j=0;j<12;j++){ float d = v[j]-mu; sq += d*d; }
    #pragma unroll
    for (int m=1; m<64; m<<=1) sq += __shfl_xor(sq, m);
    float rstd = rsqrtf(sq*(1.f/768.f) + 1e-5f);
    int c0 = lane*12;
    float o[12];
    #pragma unroll
    for (int j=0;j<12;j++) o[j] = (v[j]-mu)*rstd*n1w[c0+j] + n1b[c0+j];
    unsigned* po = (unsigned*)(xn + (size_t)row*DIMD + c0);
    #pragma unroll
    for (int k=0;k<6;k++) po[k] = pack2(o[2*k], o[2*k+1]);
  } else {
    unsigned gid = blockIdx.x*256u + threadIdx.x;
    if (gid < 768u) bcat[gid] = bq[gid];
    else if (gid < 1536u) bcat[gid] = bk[gid-768u];
    else if (gid < 2304u) bcat[gid] = bv[gid-1536u];
    for (unsigned i = gid; i < 7077888u; i += 6273u*256u){
      const float* s; short* d; unsigned off;
      if (i < 2359296u){
        unsigned r = i / 589824u; off = i - r*589824u;
        s = (r==0)?wq:(r==1)?wk:(r==2)?wv:wp;
        d = (r==0)?wqb:(r==1)?wkb:(r==2)?wvb:wpb;
      } else if (i < 4718592u){ off = i - 2359296u; s = w1; d = w1b; }
      else                    { off = i - 4718592u; s = w2; d = w2b; }
      d[off] = f2bf(s[off]);
    }
  }
}

// ================= 256x256 GEMM, 8 waves, 4-slot BK=32 depth-3 pipeline (R5, PROVEN 144.7us) ====
__global__ __launch_bounds__(512) void gemm8(const short* __restrict__ A, const short* __restrict__ Bw,
                        const float* __restrict__ bias, short* __restrict__ Cb,
                        int M, int N, int K){
  __shared__ short lds[4][16384];   // slot: A 0..8191 | B 8192..16383 (BK=32); epilogue: 128KB C tile
  int tid = threadIdx.x;
  int w = tid >> 6, lane = tid & 63;
  int l15 = lane & 15, g = (lane >> 4) & 3;
  int wr = w >> 2, wc = w & 3;

  unsigned nwg = gridDim.x * gridDim.y;
  unsigned bid = blockIdx.y * gridDim.x + blockIdx.x;
  unsigned serial = bid;
  if (nwg >= 512) serial = xcd_serial(bid, nwg);
  int rowBase = (int)(serial / gridDim.x) * 256;
  int colBase = (int)(serial % gridDim.x) * 256;

  const short* pa[2]; const short* pb[2];
  #pragma unroll
  for (int j=0;j<2;j++){
    int mr = rowBase + (w + j*8)*16 + l15; if (mr >= M) mr = M-1;
    int nr = colBase + (w + j*8)*16 + l15;           // N always multiple of 256
    pa[j] = A  + (size_t)mr*K + g*8;
    pb[j] = Bw + (size_t)nr*K + g*8;
  }
  int sd = tid*8;

  auto stage = [&](int slot, int p){
    int koff = p*32;
    short* base = &lds[slot][0];
    #pragma unroll
    for (int j=0;j<2;j++){
      gld16(pa[j] + koff, base + sd + j*4096);
      gld16(pb[j] + koff, base + 8192 + sd + j*4096);
    }
  };

  f32x4 acc[8][4] = {};
  int np = K >> 5;   // 24 phases of BK=32
  stage(0, 0);
  if (np > 1) stage(1, 1);
  if (np > 2) stage(2, 2);          // 12 loads outstanding, 3 phases deep
  for (int p = 0; p < np; p++){
    if (p <= np-3)
      asm volatile("s_waitcnt vmcnt(8)" ::: "memory");   // retire phase-p's 4; p+1,p+2 in flight
    else if (p == np-2)
      asm volatile("s_waitcnt vmcnt(4)" ::: "memory");
    else
      asm volatile("s_waitcnt vmcnt(0)" ::: "memory");
    __builtin_amdgcn_s_barrier();
    if (p + 3 < np) stage((p+3)&3, p+3);
    const short* lA = &lds[p&3][0];
    const short* lB = lA + 8192;
    s16x8 bfr[4];
    #pragma unroll
    for (int nf=0; nf<4; nf++)
      bfr[nf] = *(const s16x8*)(lB + (wc*4+nf)*512 + lane*8);
    __builtin_amdgcn_s_setprio(1);
    #pragma unroll
    for (int mf=0; mf<8; mf++){
      s16x8 af = *(const s16x8*)(lA + (wr*8+mf)*512 + lane*8);
      #pragma unroll
      for (int nf=0; nf<4; nf++)
        acc[mf][nf] = __builtin_amdgcn_mfma_f32_16x16x32_bf16(af, bfr[nf], acc[mf][nf], 0,0,0);
    }
    __builtin_amdgcn_s_setprio(0);
  }

  // ---- wide epilogue: all waves done reading slots, reuse full 128KB as C tile ----
  __syncthreads();
  short* ldsC = &lds[0][0];   // 65536 shorts; row = 256 shorts (512B), chunk = 8 shorts (16B)
  #pragma unroll
  for (int mf=0; mf<8; mf++){
    int rowL0 = wr*128 + mf*16 + g*4;
    #pragma unroll
    for (int nf=0; nf<4; nf++){
      int colL = wc*64 + nf*16 + l15;
      float bv = bias[colBase + colL];
      int ch = colL >> 3, in8 = colL & 7;
      #pragma unroll
      for (int r=0;r<4;r++){
        int rL = rowL0 + r;
        int chs = ch ^ ((rL >> 2) & 7);   // bank-XOR: spreads the 4 g-rows across chunk groups
        ldsC[rL*256 + chs*8 + in8] = f2bf(acc[mf][nf][r] + bv);
      }
    }
  }
  __syncthreads();
  int ch2 = tid & 31, rg = tid >> 5;   // 32 chunks/row; 16 rows per pass
  #pragma unroll
  for (int i=0;i<16;i++){
    int rowL = rg + i*16;
    int chs = ch2 ^ ((rowL >> 2) & 7);
    s16x8 v = *(const s16x8*)(ldsC + rowL*256 + chs*8);
    int rr = rowBase + rowL;
    if (rr < M) *(s16x8*)(Cb + (size_t)rr*N + colBase + ch2*8) = v;
  }
}

// ---- bf16 GEMM, 2-phase 128x128 (proven m97 structure): fc1.
// bf16 outputs via R4 wide LDS-transposed epilogue.
template<int GELU, int OUTBF16, int RESID, int STR, int STC>
__global__ __launch_bounds__(256) void gemm_bt(const short* __restrict__ A, const short* __restrict__ Bw,
                        const float* __restrict__ bias, const float* __restrict__ resid,
                        float* __restrict__ Cf, short* __restrict__ Cb,
                        int M, int N, int K){
  __shared__ short lds[3][8192];   // [buf][ A:0..4095 | B:4096..8191 ]; epilogue reuses 32KB as C tile
  int tid = threadIdx.x;
  int lane = tid & 63, wv = tid >> 6;
  int wr = wv >> 1, wc = wv & 1;
  int l15 = lane & 15, g = lane >> 4;

  unsigned nwg = gridDim.x * gridDim.y;
  unsigned bid = blockIdx.y * gridDim.x + blockIdx.x;
  unsigned serial = xcd_serial(bid, nwg);
  int rowT, colT;
  tile_decode<STR,STC>(serial, rowT, colT);
  int rowBase = rowT * 128;
  int colBase = colT * 128;

  f32x4 acc[4][4] = {};
  int srow = (tid & 15) | ((tid >> 6) << 4);   // 0..63
  int scol = ((tid >> 4) & 3) * 8;
  int ldsoff = tid * 8;

  int ar0 = rowBase + srow;      if (ar0 >= M) ar0 = M-1;
  int ar1 = rowBase + srow + 64; if (ar1 >= M) ar1 = M-1;
  int br0 = colBase + srow;      // N always multiple of 128
  const short* pa0 = A  + (size_t)ar0*K + scol;
  const short* pa1 = A  + (size_t)ar1*K + scol;
  const short* pb0 = Bw + (size_t)br0*K + scol;
  const short* pb1 = Bw + (size_t)(br0+64)*K + scol;

  auto stage = [&](int s, int kt){
    gld16(pa0 + kt, &lds[s][ldsoff]);
    gld16(pa1 + kt, &lds[s][ldsoff + 2048]);
    gld16(pb0 + kt, &lds[s][4096 + ldsoff]);
    gld16(pb1 + kt, &lds[s][4096 + ldsoff + 2048]);
  };

  int nk = K >> 5;
  stage(0, 0);
  if (nk > 1) stage(1, 32);
  for (int kt = 0; kt < nk; kt++){
    int cur = kt % 3;
    if (kt + 2 < nk){
      stage((kt+2)%3, (kt+2)*32);
      asm volatile("s_waitcnt vmcnt(8)" ::: "memory");
    } else if (kt + 1 < nk){
      asm volatile("s_waitcnt vmcnt(4)" ::: "memory");
    } else {
      asm volatile("s_waitcnt vmcnt(0)" ::: "memory");
    }
    __builtin_amdgcn_s_barrier();
    const short* la = lds[cur];
    const short* lb = lds[cur] + 4096;
    s16x8 af[4], bfr[4];
    #pragma unroll
    for (int m=0;m<4;m++) af[m]  = *(const s16x8*)(la + (wr*4 + m)*512 + g*128 + l15*8);
    #pragma unroll
    for (int n=0;n<4;n++) bfr[n] = *(const s16x8*)(lb + (wc*4 + n)*512 + g*128 + l15*8);
    #pragma unroll
    for (int m=0;m<4;m++)
      #pragma unroll
      for (int n=0;n<4;n++)
        acc[m][n] = __builtin_amdgcn_mfma_f32_16x16x32_bf16(af[m], bfr[n], acc[m][n], 0,0,0);
    __builtin_amdgcn_s_barrier();
  }

  if (OUTBF16){
    short* ldsC = &lds[0][0];
    #pragma unroll
    for (int n=0;n<4;n++){
      int colL = wc*64 + n*16 + l15;
      float bv = bias[colBase + colL];
      #pragma unroll
      for (int m=0;m<4;m++){
        #pragma unroll
        for (int r=0;r<4;r++){
          int rowL = wr*64 + m*16 + g*4 + r;
          float v = acc[m][n][r] + bv;
          if (GELU) v = 0.5f*v*(1.f + erff(v*0.70710678118654752f));
          int ch = colL >> 3, in8 = colL & 7;
          int chs = ch ^ (((rowL >> 2) & 3) << 2);
          ldsC[rowL*128 + chs*8 + in8] = f2bf(v);
        }
      }
    }
    __syncthreads();
    int ch = tid & 15, rg = tid >> 4;
    #pragma unroll
    for (int i=0;i<8;i++){
      int rowL = rg + i*16;
      int chs = ch ^ (((rowL >> 2) & 3) << 2);
      s16x8 v = *(const s16x8*)(ldsC + rowL*128 + chs*8);
      int rr = rowBase + rowL;
      if (rr < M) *(s16x8*)(Cb + (size_t)rr*N + colBase + ch*8) = v;
    }
  } else {
    #pragma unroll
    for (int m=0;m<4;m++){
      int row = rowBase + wr*64 + m*16 + g*4;
      #pragma unroll
      for (int n=0;n<4;n++){
        int col = colBase + wc*64 + n*16 + l15;
        float bv = bias[col];
        #pragma unroll
        for (int r=0;r<4;r++){
          int rr = row + r;
          if (rr < M){
            float v = acc[m][n][r] + bv;
            if (GELU) v = 0.5f*v*(1.f + erff(v*0.70710678118654752f));
            if (RESID) v += resid[(size_t)rr*N + col];
            Cf[(size_t)rr*N + col] = v;
          }
        }
      }
    }
  }
}

// ---- 64x128-tile fp32-out GEMM (proj, fc2): proven R7.
// R9: COL-MAJOR block ordering. fc2's B (4.7MB) exceeds one XCD's 4MB L2; the old
// row-major/col-fast order re-swept full B per row-tile (~466MB L3/HBM re-reads — the
// R0 disease, on the right kernel this time). Col-major keeps ONE 786KB B-panel
// L2-resident per XCD chunk; A streams (L3-warm: h1 just written by fc1). proj (B=1.18MB
// L2-fit) predicted neutral.
template<int RESID>
__global__ __launch_bounds__(256) void gemm_n64(const short* __restrict__ A, const short* __restrict__ Bw,
                        const float* __restrict__ bias, const float* __restrict__ resid,
                        float* __restrict__ Cf, int M, int N, int K){
  __shared__ short lds[3][6144];   // [buf][ A:0..2047 (64x32) | B:2048..6143 (128x32) ]
  int tid = threadIdx.x;
  int lane = tid & 63, wc = tid >> 6;       // 4 waves across the 128 cols
  int l15 = lane & 15, g = lane >> 4;

  unsigned nwg = gridDim.x * gridDim.y;     // 6*99 = 594
  unsigned bid = blockIdx.y * gridDim.x + blockIdx.x;
  unsigned serial = xcd_serial(bid, nwg);
  int rowBase = (int)(serial % gridDim.y) * 64;    // col-major: row-fast within one col
  int colBase = (int)(serial / gridDim.y) * 128;

  f32x4 acc[4][2] = {};
  int srow = (tid & 15) | ((tid >> 6) << 4);   // 0..63
  int scol = ((tid >> 4) & 3) * 8;
  int ldsoff = tid * 8;

  int ar = rowBase + srow; if (ar >= M) ar = M-1;
  int br = colBase + srow;                      // N multiple of 128
  const short* pa  = A  + (size_t)ar*K + scol;
  const short* pb0 = Bw + (size_t)br*K + scol;
  const short* pb1 = Bw + (size_t)(br+64)*K + scol;

  auto stage = [&](int s, int kt){
    gld16(pa  + kt, &lds[s][ldsoff]);
    gld16(pb0 + kt, &lds[s][2048 + ldsoff]);
    gld16(pb1 + kt, &lds[s][4096 + ldsoff]);
  };

  int nk = K >> 5;
  stage(0, 0);
  if (nk > 1) stage(1, 32);
  for (int kt = 0; kt < nk; kt++){
    int cur = kt % 3;
    if (kt + 2 < nk){
      stage((kt+2)%3, (kt+2)*32);
      asm volatile("s_waitcnt vmcnt(6)" ::: "memory");   // oldest 3 = stage(kt) landed
    } else if (kt + 1 < nk){
      asm volatile("s_waitcnt vmcnt(3)" ::: "memory");
    } else {
      asm volatile("s_waitcnt vmcnt(0)" ::: "memory");
    }
    __builtin_amdgcn_s_barrier();
    const short* la = lds[cur];
    const short* lb = lds[cur] + 2048;
    s16x8 af[4], bfr[2];
    #pragma unroll
    for (int m=0;m<4;m++) af[m]  = *(const s16x8*)(la + m*512 + g*128 + l15*8);
    #pragma unroll
    for (int n=0;n<2;n++) bfr[n] = *(const s16x8*)(lb + (wc*2 + n)*512 + g*128 + l15*8);
    #pragma unroll
    for (int m=0;m<4;m++)
      #pragma unroll
      for (int n=0;n<2;n++)
        acc[m][n] = __builtin_amdgcn_mfma_f32_16x16x32_bf16(af[m], bfr[n], acc[m][n], 0,0,0);
    __builtin_amdgcn_s_barrier();
  }
  #pragma unroll
  for (int m=0;m<4;m++){
    int row = rowBase + m*16 + g*4;
    #pragma unroll
    for (int n=0;n<2;n++){
      int col = colBase + wc*32 + n*16 + l15;
      float bv = bias[col];
      #pragma unroll
      for (int r=0;r<4;r++){
        int rr = row + r;
        if (rr < M){
          float v = acc[m][n][r] + bv;
          if (RESID) v += resid[(size_t)rr*N + col];
          Cf[(size_t)rr*N + col] = v;
        }
      }
    }
  }
}

// ---- fused attention pooling conv for q,k,v (one launch) + LN over 96.
// Reads the LINEAR qkv buffer [b*NTOK+tok][2304] (col = z*768 + h*96 + d).
// R8: ho==14 plane (96 aux blocks) absorbs cls3 + padfill.
__global__ __launch_bounds__(256, 2) void pool_conv3(
    const short* __restrict__ raw,
    const float* __restrict__ cwq, const float* __restrict__ cwk, const float* __restrict__ cwv,
    const float* __restrict__ nqw, const float* __restrict__ nqb,
    const float* __restrict__ nkw, const float* __restrict__ nkb,
    const float* __restrict__ nvw, const float* __restrict__ nvb,
    short* __restrict__ qo, short* __restrict__ ko, short* __restrict__ vo){
  unsigned nwg = gridDim.x * gridDim.y * gridDim.z;   // 32*15*3 = 1440
  unsigned lin = (blockIdx.z*gridDim.y + blockIdx.y)*gridDim.x + blockIdx.x;
  unsigned serial = xcd_serial(lin, nwg);
  int ho = (int)(serial % 15);
  unsigned rest = serial / 15;
  int bh = (int)(rest & 31);
  int z  = (int)(rest >> 5);
  int t = threadIdx.x;
  const float* nw = (z==0) ? nqw : (z==1) ? nkw : nvw;
  const float* nb = (z==0) ? nqb : (z==1) ? nkb : nvb;

  if (ho == 14){
    // --- aux block: cls-token LN + pad-fill for this (bh, z) ---
    if (t < 16){
      int s2 = t, d2 = s2*6;
      const short* row = raw + (size_t)(bh>>3)*NTOK*2304 + z*768 + (bh&7)*96 + d2;
      u32x3 u = *(const u32x3*)(row);
      float a[6] = { bfsel(u[0],0), bfsel(u[0],1), bfsel(u[1],0), bfsel(u[1],1), bfsel(u[2],0), bfsel(u[2],1) };
      float sm = a[0]+a[1]+a[2]+a[3]+a[4]+a[5];
      #pragma unroll
      for (int m=1; m<16; m<<=1) sm += __shfl_xor(sm, m);
      float mu = sm*(1.f/96.f);
      float vr2 = 0.f;
      #pragma unroll
      for (int j=0;j<6;j++){ float dd = a[j]-mu; vr2 += dd*dd; }
      #pragma unroll
      for (int m=1; m<16; m<<=1) vr2 += __shfl_xor(vr2, m);
      float rstd = rsqrtf(vr2*(1.f/96.f) + 1e-5f);
      #pragma unroll
      for (int j=0;j<6;j++){
        int dj = d2 + j;
        short o = f2bf((a[j]-mu)*rstd*nw[dj] + nb[dj]);
        if (z == 0)      qo[((size_t)bh*NPAD)*96 + dj] = o;
        else if (z == 1) ko[(size_t)bh*NPAD*96 + (dj>>5)*512 + ((dj>>3)&3)*128 + (dj&7)] = o;
        else             vo[(size_t)bh*NPAD*96 + (dj>>4)*1024 + (dj&15)*4] = o;
      }
    }
    for (int i = t; i < 31*96; i += 256){
      int tok = NPOOL + i/96;
      int dd = i - (i/96)*96;
      if (z == 0) qo[((size_t)bh*NPAD + tok)*96 + dd] = 0;
      else if (z == 1){
        size_t kb = (size_t)bh*NPAD*96 + (size_t)(tok>>4)*1536 + (tok&15)*8;
        ko[kb + (dd>>5)*512 + ((dd>>3)&3)*128 + (dd&7)] = 0;
      } else {
        size_t vb = (size_t)bh*NPAD*96 + (size_t)(tok>>6)*6144 + ((tok>>4)&3)*256 + ((tok>>2)&3)*64 + (tok&3);
        vo[vb + (dd>>4)*1024 + (dd&15)*4] = 0;
      }
    }
    return;
  }

  int g = t >> 4;        // wo
  if (g >= 14) return;
  int s = t & 15, d = s*6;
  const float* cw = (z==0) ? cwq : (z==1) ? cwk : cwv;
  const short* base = raw + (size_t)(bh>>3)*NTOK*2304 + z*768 + (bh&7)*96 + d;
  float acc[8][6] = {};
  #pragma unroll
  for (int dh=0; dh<3; dh++){
    int ih = 2*ho - 1 + dh;
    if (ih < 0 || ih >= 28) continue;
    #pragma unroll
    for (int dw=0; dw<3; dw++){
      int iw = 2*g - 1 + dw;
      if (iw < 0 || iw >= 28) continue;
      float w[3][6];
      #pragma unroll
      for (int dt=0; dt<3; dt++)
        #pragma unroll
        for (int j=0;j<6;j++)
          w[dt][j] = cw[(d+j)*27 + dt*9 + dh*3 + dw];
      #pragma unroll
      for (int it=0; it<8; it++){
        u32x3 u = *(const u32x3*)(base + (size_t)(1 + (it*28+ih)*28 + iw)*2304);
        float in[6] = { bfsel(u[0],0), bfsel(u[0],1), bfsel(u[1],0),
                        bfsel(u[1],1), bfsel(u[2],0), bfsel(u[2],1) };
        #pragma unroll
        for (int dt=0; dt<3; dt++){
          int to = it + 1 - dt;                // compile-time per unrolled iter
          if (to < 0 || to > 7) continue;
          #pragma unroll
          for (int j=0;j<6;j++) acc[to][j] = fmaf(in[j], w[dt][j], acc[to][j]);
        }
      }
    }
  }
  float nwv[6], nbv[6];
  #pragma unroll
  for (int j=0;j<6;j++){ nwv[j] = nw[d+j]; nbv[j] = nb[d+j]; }
  #pragma unroll
  for (int to=0; to<8; to++){
    float sm = acc[to][0]+acc[to][1]+acc[to][2]+acc[to][3]+acc[to][4]+acc[to][5];
    #pragma unroll
    for (int m=1; m<16; m<<=1) sm += __shfl_xor(sm, m);
    float mu = sm*(1.f/96.f);
    float vr = 0.f;
    #pragma unroll
    for (int j=0;j<6;j++){ float dd = acc[to][j]-mu; vr += dd*dd; }
    #pragma unroll
    for (int m=1; m<16; m<<=1) vr += __shfl_xor(vr, m);
    float rstd = rsqrtf(vr*(1.f/96.f) + 1e-5f);
    int tok = 1 + to*196 + ho*14 + g;
    if (z == 0){
      short o[6];
      #pragma unroll
      for (int j=0;j<6;j++) o[j] = f2bf((acc[to][j]-mu)*rstd*nwv[j] + nbv[j]);
      unsigned* q32 = (unsigned*)(qo + ((size_t)bh*NPAD + tok)*96 + d);
      #pragma unroll
      for (int w2=0; w2<3; w2++)
        q32[w2] = (unsigned)(unsigned short)o[2*w2] | ((unsigned)(unsigned short)o[2*w2+1] << 16);
    } else if (z == 1){
      size_t kb = (size_t)bh*NPAD*96 + (size_t)(tok>>4)*1536 + (tok&15)*8;
      #pragma unroll
      for (int j=0;j<6;j++){
        int dj = d + j;
        ko[kb + (dj>>5)*512 + ((dj>>3)&3)*128 + (dj&7)] = f2bf((acc[to][j]-mu)*rstd*nwv[j] + nbv[j]);
      }
    } else {
      size_t vb = (size_t)bh*NPAD*96 + (size_t)(tok>>6)*6144 + ((tok>>4)&3)*256 + ((tok>>2)&3)*64 + (tok&3);
      #pragma unroll
      for (int j=0;j<6;j++){
        int dj = d + j;
        vo[vb + (dj>>4)*1024 + (dj&15)*4] = f2bf((acc[to][j]-mu)*rstd*nwv[j] + nbv[j]);
      }
    }
  }
}

// ---- flash attention, 8 waves/block (128 q-rows).
// XCD mapping: bh-major chunks -> each XCD owns exactly 4 bh; K/V L2-resident.
__global__ __launch_bounds__(512) void attn_k(const short* __restrict__ qp, const short* __restrict__ kp,
                       const short* __restrict__ vp, short* __restrict__ oattn){
  const float M0 = 6.0f;
  __shared__ short lkv[2][12288];   // [buf][ K:0..6143 | V:6144..12287 ]
  unsigned nwg = gridDim.x * gridDim.y;   // 13*32 = 416
  unsigned bid0 = blockIdx.y * gridDim.x + blockIdx.x;
  unsigned serial = xcd_serial(bid0, nwg);
  int bh = (int)(serial / 13);
  int qblk = (int)(serial - (unsigned)bh*13);
  int b = bh >> 3, h = bh & 7;
  int tid = threadIdx.x;
  int lane = tid & 63, wv = tid >> 6;
  int l15 = lane & 15, g = lane >> 4;
  int qi = qblk*128 + wv*16 + l15;
  int qi_ld = qi < NPAD ? qi : NPAD-1;        // clamp; pad rows are zeroed, writes masked below
  const short* qbase = qp + (size_t)bh*NPAD*HD;
  const short* kbase = kp + (size_t)bh*NPAD*HD;
  const short* vbase = vp + (size_t)bh*NPAD*HD;
  s16x8 qf[3];
  #pragma unroll
  for (int f=0; f<3; f++)
    qf[f] = *(const s16x8*)(qbase + (size_t)qi_ld*HD + f*32 + g*8);

  // stage chunk t: 12288 shorts (K 6144 | V 6144); 512 threads x 3 gld16, wave-uniform K/V branch
  auto stage = [&](int bsel, int t){
    #pragma unroll
    for (int i=0;i<3;i++){
      int off = i*4096 + tid*8;
      const short* src = (off < 6144) ? (kbase + t*6144 + off) : (vbase + t*6144 + off - 6144);
      gld16(src, &lkv[bsel][off]);
    }
  };

  f32x4 accO[6] = {};
  float tsum = 0.f;

  stage(0, 0);
  asm volatile("s_waitcnt vmcnt(0)" ::: "memory");
  __builtin_amdgcn_s_barrier();

  for (int kt = 0; kt < 25; kt++){
    int cur = kt & 1;
    if (kt < 24){
      stage(cur^1, kt+1);
      asm volatile("s_waitcnt vmcnt(3)" ::: "memory");   // current chunk done; next 3 in flight
    } else {
      asm volatile("s_waitcnt vmcnt(0)" ::: "memory");
    }
    __builtin_amdgcn_s_barrier();

    const short* lkc = &lkv[cur][0];
    const short* lvc = &lkv[cur][6144];
    f32x4 sacc[4];
    #pragma unroll
    for (int sub=0; sub<4; sub++){
      sacc[sub] = (f32x4){0.f,0.f,0.f,0.f};
      #pragma unroll
      for (int f=0; f<3; f++){
        s16x8 kf = *(const s16x8*)(lkc + sub*1536 + f*512 + lane*8);
        sacc[sub] = __builtin_amdgcn_mfma_f32_16x16x32_bf16(kf, qf[f], sacc[sub], 0,0,0);
      }
    }
    s16x4 pf[4];
    if (kt < 24){
      #pragma unroll
      for (int sub=0; sub<4; sub++){
        #pragma unroll
        for (int r=0; r<4; r++){
          float p = __expf(sacc[sub][r]*SCALE_ - M0);
          tsum += p;
          pf[sub][r] = f2bf(p);
        }
      }
    } else {
      #pragma unroll
      for (int sub=0; sub<4; sub++){
        #pragma unroll
        for (int r=0; r<4; r++){
          int ki = kt*64 + sub*16 + g*4 + r;
          float p = (ki < NPOOL) ? __expf(sacc[sub][r]*SCALE_ - M0) : 0.f;
          tsum += p;
          pf[sub][r] = f2bf(p);
        }
      }
    }
    #pragma unroll
    for (int dt=0; dt<6; dt++){
      #pragma unroll
      for (int sub=0; sub<4; sub++){
        s16x4 vf = *(const s16x4*)(lvc + dt*1024 + sub*256 + lane*4);
        accO[dt] = MFMA16K(vf, pf[sub], accO[dt]);
      }
    }
    __builtin_amdgcn_s_barrier();
  }

  tsum += __shfl_xor(tsum, 16);
  tsum += __shfl_xor(tsum, 32);
  if (qi < NPOOL){
    float inv = 1.f / tsum;
    #pragma unroll
    for (int dt=0; dt<6; dt++){
      #pragma unroll
      for (int r=0; r<4; r++){
        int dd = dt*16 + g*4 + r;
        oattn[((size_t)b*NPOOL + qi)*DIMD + h*96 + dd] = f2bf(accO[dt][r] * inv);
      }
    }
  }
}

// ---- maxpool(3x3/s2) skip + proj-out add + LN2 (R8: wave-per-token, ZERO barriers) ----
__global__ __launch_bounds__(256) void skip_ln2(const float* __restrict__ x, const float* __restrict__ oproj,
                         const float* __restrict__ w, const float* __restrict__ bb,
                         float* __restrict__ x2, short* __restrict__ xn2){
  unsigned serial = xcd_serial(blockIdx.x, gridDim.x);   // 1569 blocks x 4 tokens = 6276
  int ti = (int)serial*4 + (int)(threadIdx.x >> 6);
  int b = ti / NPOOL;
  int tok = ti - b*NPOOL;
  int lane = threadIdx.x & 63;
  int c0 = lane*12;
  float v[12];
  if (tok == 0){
    const float* xr = x + (size_t)b*NTOK*DIMD + c0;
    f32x4 a0 = *(const f32x4*)xr, a1 = *(const f32x4*)(xr+4), a2 = *(const f32x4*)(xr+8);
    #pragma unroll
    for (int j=0;j<4;j++){ v[j]=a0[j]; v[4+j]=a1[j]; v[8+j]=a2[j]; }
  } else {
    int ot = tok - 1;
    int to = ot/196, rem = ot%196, ho = rem/14, wo = rem%14;
    #pragma unroll
    for (int j=0;j<12;j++) v[j] = -INFINITY;
    #pragma unroll
    for (int dh=0; dh<3; dh++){
      int ih = 2*ho - 1 + dh; if (ih < 0 || ih >= 28) continue;
      #pragma unroll
      for (int dw=0; dw<3; dw++){
        int iw = 2*wo - 1 + dw; if (iw < 0 || iw >= 28) continue;
        const float* xr = x + ((size_t)b*NTOK + 1 + (to*28 + ih)*28 + iw)*DIMD + c0;
        f32x4 a0 = *(const f32x4*)xr, a1 = *(const f32x4*)(xr+4), a2 = *(const f32x4*)(xr+8);
        #pragma unroll
        for (int j=0;j<4;j++){
          v[j]   = fmaxf(v[j],   a0[j]);
          v[4+j] = fmaxf(v[4+j], a1[j]);
          v[8+j] = fmaxf(v[8+j], a2[j]);
        }
      }
    }
  }
  const float* opr = oproj + ((size_t)b*NPOOL + tok)*DIMD + c0;
  f32x4 p0 = *(const f32x4*)opr, p1 = *(const f32x4*)(opr+4), p2 = *(const f32x4*)(opr+8);
  #pragma unroll
  for (int j=0;j<4;j++){ v[j]+=p0[j]; v[4+j]+=p1[j]; v[8+j]+=p2[j]; }
  float* x2r = x2 + ((size_t)b*NPOOL + tok)*DIMD + c0;
  f32x4 o0 = {v[0],v[1],v[2],v[3]}, o1 = {v[4],v[5],v[6],v[7]}, o2 = {v[8],v[9],v[10],v[11]};
  *(f32x4*)x2r = o0; *(f32x4*)(x2r+4) = o1; *(f32x4*)(x2r+8) = o2;
  float s = 0.f;
  #pragma unroll
  for (int j=0;j<12;j++) s += v[j];
  #pragma unroll
  for (int m=1; m<64; m<<=1) s += __shfl_xor(s, m);
  float mu = s * (1.f/768.f);
  float sq = 0.f;
  #pragma unroll
  for (int j=0;j<12;j++){ float d = v[j]-mu; sq += d*d; }
  #pragma unroll
  for (int m=1; m<64; m<<=1) sq += __shfl_xor(sq, m);
  float rstd = rsqrtf(sq*(1.f/768.f) + 1e-5f);
  float o[12];
  #pragma unroll
  for (int j=0;j<12;j++) o[j] = (v[j]-mu)*rstd*w[c0+j] + bb[c0+j];
  unsigned* po = (unsigned*)(xn2 + ((size_t)b*NPOOL + tok)*DIMD + c0);
  #pragma unroll
  for (int k=0;k<6;k++) po[k] = pack2(o[2*k], o[2*k+1]);
}

extern "C" void kernel_launch(void* const* d_in, const int* in_sizes, int n_in,
                              void* d_out, int out_size, void* d_ws, size_t ws_size,
                              hipStream_t stream){
  (void)in_sizes; (void)n_in; (void)out_size; (void)ws_size;
  const float* x      = (const float*)d_in[0];
  const float* n1_w   = (const float*)d_in[1];
  const float* n1_b   = (const float*)d_in[2];
  const float* wq     = (const float*)d_in[3];
  const float* bq     = (const float*)d_in[4];
  const float* wk     = (const float*)d_in[5];
  const float* bk     = (const float*)d_in[6];
  const float* wv     = (const float*)d_in[7];
  const float* bv     = (const float*)d_in[8];
  const float* pq_w   = (const float*)d_in[9];
  const float* pk_w   = (const float*)d_in[10];
  const float* pv_w   = (const float*)d_in[11];
  const float* nq_w   = (const float*)d_in[12];
  const float* nq_b   = (const float*)d_in[13];
  const float* nk_w   = (const float*)d_in[14];
  const float* nk_b   = (const float*)d_in[15];
  const float* nv_w   = (const float*)d_in[16];
  const float* nv_b   = (const float*)d_in[17];
  const float* proj_w = (const float*)d_in[18];
  const float* proj_b = (const float*)d_in[19];
  const float* n2_w   = (const float*)d_in[20];
  const float* n2_b   = (const float*)d_in[21];
  const float* fc1_w  = (const float*)d_in[22];
  const float* fc1_b  = (const float*)d_in[23];
  const float* fc2_w  = (const float*)d_in[24];
  const float* fc2_b  = (const float*)d_in[25];
  float* out = (float*)d_out;

  char* ws = (char*)d_ws;
  size_t off = 0;
  auto take = [&](size_t bytes)->char*{
    char* p = ws + off; off = (off + bytes + 255) & ~(size_t)255; return p;
  };
  short* xn  = (short*)take(38541312);       // 25092*768 bf16
  short* wqb = (short*)take(1179648);        // wqb/wkb/wvb contiguous -> one [2304][768] matrix
  short* wkb = (short*)take(1179648);
  short* wvb = (short*)take(1179648);
  short* wpb = (short*)take(1179648);
  short* w1b = (short*)take(4718592);
  short* w2b = (short*)take(4718592);
  float* bcat= (float*)take(9216);           // packed [bq|bk|bv]
  char*  big = take(115623936);              // phase1: linear qkv [25092][2304]; phase2: oattn/oproj/x2/xn2/h1
  short* qkv  = (short*)(big);               // 115623936 B exactly
  short* oattn= (short*)(big);               // 9639936 B
  float* oproj= (float*)(big + 9639936);     // 19279872 B
  float* x2   = (float*)(big + 28919808);    // 19279872 B
  short* xn2  = (short*)(big + 48199680);    // 9639936 B
  short* h1   = (short*)(big + 57839616);    // 38559744 B
  short* qp   = (short*)take(9830400);       // 32*1600*96 bf16
  short* kp   = (short*)take(9830400);
  short* vT   = (short*)take(9830400);

  // fused prologue: LN1 (y=0) + weight cast + bias pack (y=1)
  prologue<<<dim3(6273,2), 256, 0, stream>>>(x, n1_w, n1_b, xn,
      wq, wk, wv, proj_w, fc1_w, fc2_w, wqb, wkb, wvb, wpb, w1b, w2b,
      bq, bk, bv, bcat);

  // fused QKV: 256x256 gemm8 (R5, 144.7us proven); grid 9x99 = 891 blocks
  gemm8<<<dim3(9,99), 512, 0, stream>>>(xn, wqb, bcat, qkv, MROWS, 2304, 768);

  // pool conv + LN(96) + cls + padfill (aux ho==14 plane)
  pool_conv3<<<dim3(32,15,3), 256, 0, stream>>>(qkv, pq_w, pk_w, pv_w,
                                                nq_w, nq_b, nk_w, nk_b, nv_w, nv_b, qp, kp, vT);

  attn_k<<<dim3(13,32), 512, 0, stream>>>(qp, kp, vT, oattn);

  // proj: 64-row tiles, col-major order -> grid 6x99 = 594 blocks
  gemm_n64<0><<<dim3(6,99), 256, 0, stream>>>(oattn, wpb, proj_b, nullptr, oproj, M2, 768, 768);

  // maxpool skip + LN2: wave-per-token, 1569 blocks, zero barriers
  skip_ln2<<<1569, 256, 0, stream>>>(x, oproj, n2_w, n2_b, x2, xn2);

  // fc1: 50x24 tiles, supertile 10x8 (bf16 out -> wide epilogue)
  gemm_bt<1,1,0,10,8><<<dim3(24,50), 256, 0, stream>>>(xn2, w1b, fc1_b, nullptr, nullptr, h1, M2, HID, 768);
  // fc2: 64-row tiles, K=3072, col-major order (B-panel L2-resident per XCD)
  gemm_n64<1><<<dim3(6,99), 256, 0, stream>>>(h1, w2b, fc2_b, x2, out, M2, 768, 3072);
}

// Round 10
// 558.498 us; speedup vs baseline: 1.1298x; 1.0182x over previous
//
#include <hip/hip_runtime.h>
#include <math.h>

#define B_ 4
#define NTOK 6273
#define DIMD 768
#define HEADS 8
#define HD 96
#define NPOOL 1569
#define NPAD 1600
#define HID 3072
#define MROWS (B_*NTOK)   // 25092
#define M2 (B_*NPOOL)     // 6276
#define SCALE_ 0.10206207261596575f

typedef float f32x4 __attribute__((ext_vector_type(4)));
typedef short s16x8 __attribute__((ext_vector_type(8)));
typedef short s16x4 __attribute__((ext_vector_type(4)));
typedef unsigned u32x3 __attribute__((ext_vector_type(3)));

__device__ __forceinline__ short f2bf(float f){
  unsigned u = __builtin_bit_cast(unsigned, f);
  u = (u + 0x7fffu + ((u >> 16) & 1u)) >> 16;
  return (short)u;
}
__device__ __forceinline__ float bf2f(short s){
  unsigned u = ((unsigned)(unsigned short)s) << 16;
  return __builtin_bit_cast(float, u);
}
__device__ __forceinline__ float bfsel(unsigned u, int hi){
  unsigned r = hi ? (u & 0xffff0000u) : (u << 16);
  return __builtin_bit_cast(float, r);
}
__device__ __forceinline__ unsigned pack2(float lo, float hi){
  return (unsigned)(unsigned short)f2bf(lo) | ((unsigned)(unsigned short)f2bf(hi) << 16);
}

__device__ __forceinline__ void gld16(const void* g, void* l){
  __builtin_amdgcn_global_load_lds((const __attribute__((address_space(1))) unsigned*)g,
                                   (__attribute__((address_space(3))) unsigned*)l, 16, 0, 0);
}

#if defined(__has_builtin)
#if __has_builtin(__builtin_amdgcn_mfma_f32_16x16x16bf16_1k)
#define MFMA16K(a,b,c) __builtin_amdgcn_mfma_f32_16x16x16bf16_1k(a,b,c,0,0,0)
#endif
#endif
#ifndef MFMA16K
__device__ __forceinline__ f32x4 mfma16k_asm(s16x4 a, s16x4 b, f32x4 c){
  asm volatile("v_mfma_f32_16x16x16_bf16 %0, %1, %2, %0\n\ts_nop 7\n\ts_nop 7"
               : "+v"(c) : "v"(a), "v"(b));
  return c;
}
#define MFMA16K(a,b,c) mfma16k_asm(a,b,c)
#endif

// ---- XCD-chunked serial (m204 bijection): contiguous serial range per XCD ----
__device__ __forceinline__ unsigned xcd_serial(unsigned bid, unsigned nwg){
  unsigned q = nwg >> 3, r8 = nwg & 7;
  unsigned xcd = bid & 7, idx = bid >> 3;
  return (xcd < r8 ? xcd*(q+1) : r8*(q+1) + (xcd-r8)*q) + idx;
}

// supertile decode: STR x STC tiles per supertile, row-fast within col.
template<int STR, int STC>
__device__ __forceinline__ void tile_decode(unsigned serial, int& rowT, int& colT){
  const int nStC = (int)gridDim.x / STC;
  int st = (int)serial / (STR*STC);
  int t  = (int)serial - st*(STR*STC);
  int stR = st / nStC, stC = st - stR*nStC;
  int c = t / STR, r = t - c*STR;
  rowT = stR*STR + r;
  colT = stC*STC + c;
}

// ---- fused prologue (R8): y==0 -> ln768 (wave-per-row, zero barriers);
//      y==1 -> weight cast fp32->bf16 (grid-stride over all 6 matrices) + bias pack.
__global__ __launch_bounds__(256) void prologue(
    const float* __restrict__ x, const float* __restrict__ n1w, const float* __restrict__ n1b,
    short* __restrict__ xn,
    const float* __restrict__ wq, const float* __restrict__ wk, const float* __restrict__ wv,
    const float* __restrict__ wp, const float* __restrict__ w1, const float* __restrict__ w2,
    short* __restrict__ wqb, short* __restrict__ wkb, short* __restrict__ wvb,
    short* __restrict__ wpb, short* __restrict__ w1b, short* __restrict__ w2b,
    const float* __restrict__ bq, const float* __restrict__ bk, const float* __restrict__ bv,
    float* __restrict__ bcat){
  if (blockIdx.y == 0){
    int row = blockIdx.x*4 + (threadIdx.x >> 6);
    int lane = threadIdx.x & 63;
    const float* xr = x + (size_t)row*DIMD + lane*12;
    f32x4 v0 = *(const f32x4*)(xr);
    f32x4 v1 = *(const f32x4*)(xr + 4);
    f32x4 v2 = *(const f32x4*)(xr + 8);
    float v[12] = { v0[0],v0[1],v0[2],v0[3], v1[0],v1[1],v1[2],v1[3], v2[0],v2[1],v2[2],v2[3] };
    float s = 0.f;
    #pragma unroll
    for (int j=0;j<12;j++) s += v[j];
    #pragma unroll
    for (int m=1; m<64; m<<=1) s += __shfl_xor(s, m);
    float mu = s * (1.f/768.f);
    float sq = 0.f;
    #pragma unroll
    for (int j=0;j<12;j++){ float d = v[j]-mu; sq += d*d; }
    #pragma unroll
    for (int m=1; m<64; m<<=1) sq += __shfl_xor(sq, m);
    float rstd = rsqrtf(sq*(1.f/768.f) + 1e-5f);
    int c0 = lane*12;
    float o[12];
    #pragma unroll
    for (int j=0;j<12;j++) o[j] = (v[j]-mu)*rstd*n1w[c0+j] + n1b[c0+j];
    unsigned* po = (unsigned*)(xn + (size_t)row*DIMD + c0);
    #pragma unroll
    for (int k=0;k<6;k++) po[k] = pack2(o[2*k], o[2*k+1]);
  } else {
    unsigned gid = blockIdx.x*256u + threadIdx.x;
    if (gid < 768u) bcat[gid] = bq[gid];
    else if (gid < 1536u) bcat[gid] = bk[gid-768u];
    else if (gid < 2304u) bcat[gid] = bv[gid-1536u];
    for (unsigned i = gid; i < 7077888u; i += 6273u*256u){
      const float* s; short* d; unsigned off;
      if (i < 2359296u){
        unsigned r = i / 589824u; off = i - r*589824u;
        s = (r==0)?wq:(r==1)?wk:(r==2)?wv:wp;
        d = (r==0)?wqb:(r==1)?wkb:(r==2)?wvb:wpb;
      } else if (i < 4718592u){ off = i - 2359296u; s = w1; d = w1b; }
      else                    { off = i - 4718592u; s = w2; d = w2b; }
      d[off] = f2bf(s[off]);
    }
  }
}

// ================= 256x256 GEMM, 8 waves, 4-slot BK=32 depth-3 pipeline (R5, PROVEN 144.7us) ====
__global__ __launch_bounds__(512) void gemm8(const short* __restrict__ A, const short* __restrict__ Bw,
                        const float* __restrict__ bias, short* __restrict__ Cb,
                        int M, int N, int K){
  __shared__ short lds[4][16384];   // slot: A 0..8191 | B 8192..16383 (BK=32); epilogue: 128KB C tile
  int tid = threadIdx.x;
  int w = tid >> 6, lane = tid & 63;
  int l15 = lane & 15, g = (lane >> 4) & 3;
  int wr = w >> 2, wc = w & 3;

  unsigned nwg = gridDim.x * gridDim.y;
  unsigned bid = blockIdx.y * gridDim.x + blockIdx.x;
  unsigned serial = bid;
  if (nwg >= 512) serial = xcd_serial(bid, nwg);
  int rowBase = (int)(serial / gridDim.x) * 256;
  int colBase = (int)(serial % gridDim.x) * 256;

  const short* pa[2]; const short* pb[2];
  #pragma unroll
  for (int j=0;j<2;j++){
    int mr = rowBase + (w + j*8)*16 + l15; if (mr >= M) mr = M-1;
    int nr = colBase + (w + j*8)*16 + l15;           // N always multiple of 256
    pa[j] = A  + (size_t)mr*K + g*8;
    pb[j] = Bw + (size_t)nr*K + g*8;
  }
  int sd = tid*8;

  auto stage = [&](int slot, int p){
    int koff = p*32;
    short* base = &lds[slot][0];
    #pragma unroll
    for (int j=0;j<2;j++){
      gld16(pa[j] + koff, base + sd + j*4096);
      gld16(pb[j] + koff, base + 8192 + sd + j*4096);
    }
  };

  f32x4 acc[8][4] = {};
  int np = K >> 5;   // 24 phases of BK=32
  stage(0, 0);
  if (np > 1) stage(1, 1);
  if (np > 2) stage(2, 2);          // 12 loads outstanding, 3 phases deep
  for (int p = 0; p < np; p++){
    if (p <= np-3)
      asm volatile("s_waitcnt vmcnt(8)" ::: "memory");   // retire phase-p's 4; p+1,p+2 in flight
    else if (p == np-2)
      asm volatile("s_waitcnt vmcnt(4)" ::: "memory");
    else
      asm volatile("s_waitcnt vmcnt(0)" ::: "memory");
    __builtin_amdgcn_s_barrier();
    if (p + 3 < np) stage((p+3)&3, p+3);
    const short* lA = &lds[p&3][0];
    const short* lB = lA + 8192;
    s16x8 bfr[4];
    #pragma unroll
    for (int nf=0; nf<4; nf++)
      bfr[nf] = *(const s16x8*)(lB + (wc*4+nf)*512 + lane*8);
    __builtin_amdgcn_s_setprio(1);
    #pragma unroll
    for (int mf=0; mf<8; mf++){
      s16x8 af = *(const s16x8*)(lA + (wr*8+mf)*512 + lane*8);
      #pragma unroll
      for (int nf=0; nf<4; nf++)
        acc[mf][nf] = __builtin_amdgcn_mfma_f32_16x16x32_bf16(af, bfr[nf], acc[mf][nf], 0,0,0);
    }
    __builtin_amdgcn_s_setprio(0);
  }

  // ---- wide epilogue: all waves done reading slots, reuse full 128KB as C tile ----
  __syncthreads();
  short* ldsC = &lds[0][0];   // 65536 shorts; row = 256 shorts (512B), chunk = 8 shorts (16B)
  #pragma unroll
  for (int mf=0; mf<8; mf++){
    int rowL0 = wr*128 + mf*16 + g*4;
    #pragma unroll
    for (int nf=0; nf<4; nf++){
      int colL = wc*64 + nf*16 + l15;
      float bv = bias[colBase + colL];
      int ch = colL >> 3, in8 = colL & 7;
      #pragma unroll
      for (int r=0;r<4;r++){
        int rL = rowL0 + r;
        int chs = ch ^ ((rL >> 2) & 7);   // bank-XOR: spreads the 4 g-rows across chunk groups
        ldsC[rL*256 + chs*8 + in8] = f2bf(acc[mf][nf][r] + bv);
      }
    }
  }
  __syncthreads();
  int ch2 = tid & 31, rg = tid >> 5;   // 32 chunks/row; 16 rows per pass
  #pragma unroll
  for (int i=0;i<16;i++){
    int rowL = rg + i*16;
    int chs = ch2 ^ ((rowL >> 2) & 7);
    s16x8 v = *(const s16x8*)(ldsC + rowL*256 + chs*8);
    int rr = rowBase + rowL;
    if (rr < M) *(s16x8*)(Cb + (size_t)rr*N + colBase + ch2*8) = v;
  }
}

// ---- bf16 GEMM, 2-phase 128x128 (proven m97 structure): fc1.
// bf16 outputs via R4 wide LDS-transposed epilogue.
template<int GELU, int OUTBF16, int RESID, int STR, int STC>
__global__ __launch_bounds__(256) void gemm_bt(const short* __restrict__ A, const short* __restrict__ Bw,
                        const float* __restrict__ bias, const float* __restrict__ resid,
                        float* __restrict__ Cf, short* __restrict__ Cb,
                        int M, int N, int K){
  __shared__ short lds[3][8192];   // [buf][ A:0..4095 | B:4096..8191 ]; epilogue reuses 32KB as C tile
  int tid = threadIdx.x;
  int lane = tid & 63, wv = tid >> 6;
  int wr = wv >> 1, wc = wv & 1;
  int l15 = lane & 15, g = lane >> 4;

  unsigned nwg = gridDim.x * gridDim.y;
  unsigned bid = blockIdx.y * gridDim.x + blockIdx.x;
  unsigned serial = xcd_serial(bid, nwg);
  int rowT, colT;
  tile_decode<STR,STC>(serial, rowT, colT);
  int rowBase = rowT * 128;
  int colBase = colT * 128;

  f32x4 acc[4][4] = {};
  int srow = (tid & 15) | ((tid >> 6) << 4);   // 0..63
  int scol = ((tid >> 4) & 3) * 8;
  int ldsoff = tid * 8;

  int ar0 = rowBase + srow;      if (ar0 >= M) ar0 = M-1;
  int ar1 = rowBase + srow + 64; if (ar1 >= M) ar1 = M-1;
  int br0 = colBase + srow;      // N always multiple of 128
  const short* pa0 = A  + (size_t)ar0*K + scol;
  const short* pa1 = A  + (size_t)ar1*K + scol;
  const short* pb0 = Bw + (size_t)br0*K + scol;
  const short* pb1 = Bw + (size_t)(br0+64)*K + scol;

  auto stage = [&](int s, int kt){
    gld16(pa0 + kt, &lds[s][ldsoff]);
    gld16(pa1 + kt, &lds[s][ldsoff + 2048]);
    gld16(pb0 + kt, &lds[s][4096 + ldsoff]);
    gld16(pb1 + kt, &lds[s][4096 + ldsoff + 2048]);
  };

  int nk = K >> 5;
  stage(0, 0);
  if (nk > 1) stage(1, 32);
  for (int kt = 0; kt < nk; kt++){
    int cur = kt % 3;
    if (kt + 2 < nk){
      stage((kt+2)%3, (kt+2)*32);
      asm volatile("s_waitcnt vmcnt(8)" ::: "memory");
    } else if (kt + 1 < nk){
      asm volatile("s_waitcnt vmcnt(4)" ::: "memory");
    } else {
      asm volatile("s_waitcnt vmcnt(0)" ::: "memory");
    }
    __builtin_amdgcn_s_barrier();
    const short* la = lds[cur];
    const short* lb = lds[cur] + 4096;
    s16x8 af[4], bfr[4];
    #pragma unroll
    for (int m=0;m<4;m++) af[m]  = *(const s16x8*)(la + (wr*4 + m)*512 + g*128 + l15*8);
    #pragma unroll
    for (int n=0;n<4;n++) bfr[n] = *(const s16x8*)(lb + (wc*4 + n)*512 + g*128 + l15*8);
    #pragma unroll
    for (int m=0;m<4;m++)
      #pragma unroll
      for (int n=0;n<4;n++)
        acc[m][n] = __builtin_amdgcn_mfma_f32_16x16x32_bf16(af[m], bfr[n], acc[m][n], 0,0,0);
    __builtin_amdgcn_s_barrier();
  }

  if (OUTBF16){
    short* ldsC = &lds[0][0];
    #pragma unroll
    for (int n=0;n<4;n++){
      int colL = wc*64 + n*16 + l15;
      float bv = bias[colBase + colL];
      #pragma unroll
      for (int m=0;m<4;m++){
        #pragma unroll
        for (int r=0;r<4;r++){
          int rowL = wr*64 + m*16 + g*4 + r;
          float v = acc[m][n][r] + bv;
          if (GELU) v = 0.5f*v*(1.f + erff(v*0.70710678118654752f));
          int ch = colL >> 3, in8 = colL & 7;
          int chs = ch ^ (((rowL >> 2) & 3) << 2);
          ldsC[rowL*128 + chs*8 + in8] = f2bf(v);
        }
      }
    }
    __syncthreads();
    int ch = tid & 15, rg = tid >> 4;
    #pragma unroll
    for (int i=0;i<8;i++){
      int rowL = rg + i*16;
      int chs = ch ^ (((rowL >> 2) & 3) << 2);
      s16x8 v = *(const s16x8*)(ldsC + rowL*128 + chs*8);
      int rr = rowBase + rowL;
      if (rr < M) *(s16x8*)(Cb + (size_t)rr*N + colBase + ch*8) = v;
    }
  } else {
    #pragma unroll
    for (int m=0;m<4;m++){
      int row = rowBase + wr*64 + m*16 + g*4;
      #pragma unroll
      for (int n=0;n<4;n++){
        int col = colBase + wc*64 + n*16 + l15;
        float bv = bias[col];
        #pragma unroll
        for (int r=0;r<4;r++){
          int rr = row + r;
          if (rr < M){
            float v = acc[m][n][r] + bv;
            if (GELU) v = 0.5f*v*(1.f + erff(v*0.70710678118654752f));
            if (RESID) v += resid[(size_t)rr*N + col];
            Cf[(size_t)rr*N + col] = v;
          }
        }
      }
    }
  }
}

// ---- 64x128-tile fp32-out GEMM (proj, fc2): proven R7; col-major order (R9, neutral) ----
template<int RESID>
__global__ __launch_bounds__(256) void gemm_n64(const short* __restrict__ A, const short* __restrict__ Bw,
                        const float* __restrict__ bias, const float* __restrict__ resid,
                        float* __restrict__ Cf, int M, int N, int K){
  __shared__ short lds[3][6144];   // [buf][ A:0..2047 (64x32) | B:2048..6143 (128x32) ]
  int tid = threadIdx.x;
  int lane = tid & 63, wc = tid >> 6;       // 4 waves across the 128 cols
  int l15 = lane & 15, g = lane >> 4;

  unsigned nwg = gridDim.x * gridDim.y;     // 6*99 = 594
  unsigned bid = blockIdx.y * gridDim.x + blockIdx.x;
  unsigned serial = xcd_serial(bid, nwg);
  int rowBase = (int)(serial % gridDim.y) * 64;    // col-major: row-fast within one col
  int colBase = (int)(serial / gridDim.y) * 128;

  f32x4 acc[4][2] = {};
  int srow = (tid & 15) | ((tid >> 6) << 4);   // 0..63
  int scol = ((tid >> 4) & 3) * 8;
  int ldsoff = tid * 8;

  int ar = rowBase + srow; if (ar >= M) ar = M-1;
  int br = colBase + srow;                      // N multiple of 128
  const short* pa  = A  + (size_t)ar*K + scol;
  const short* pb0 = Bw + (size_t)br*K + scol;
  const short* pb1 = Bw + (size_t)(br+64)*K + scol;

  auto stage = [&](int s, int kt){
    gld16(pa  + kt, &lds[s][ldsoff]);
    gld16(pb0 + kt, &lds[s][2048 + ldsoff]);
    gld16(pb1 + kt, &lds[s][4096 + ldsoff]);
  };

  int nk = K >> 5;
  stage(0, 0);
  if (nk > 1) stage(1, 32);
  for (int kt = 0; kt < nk; kt++){
    int cur = kt % 3;
    if (kt + 2 < nk){
      stage((kt+2)%3, (kt+2)*32);
      asm volatile("s_waitcnt vmcnt(6)" ::: "memory");   // oldest 3 = stage(kt) landed
    } else if (kt + 1 < nk){
      asm volatile("s_waitcnt vmcnt(3)" ::: "memory");
    } else {
      asm volatile("s_waitcnt vmcnt(0)" ::: "memory");
    }
    __builtin_amdgcn_s_barrier();
    const short* la = lds[cur];
    const short* lb = lds[cur] + 2048;
    s16x8 af[4], bfr[2];
    #pragma unroll
    for (int m=0;m<4;m++) af[m]  = *(const s16x8*)(la + m*512 + g*128 + l15*8);
    #pragma unroll
    for (int n=0;n<2;n++) bfr[n] = *(const s16x8*)(lb + (wc*2 + n)*512 + g*128 + l15*8);
    #pragma unroll
    for (int m=0;m<4;m++)
      #pragma unroll
      for (int n=0;n<2;n++)
        acc[m][n] = __builtin_amdgcn_mfma_f32_16x16x32_bf16(af[m], bfr[n], acc[m][n], 0,0,0);
    __builtin_amdgcn_s_barrier();
  }
  #pragma unroll
  for (int m=0;m<4;m++){
    int row = rowBase + m*16 + g*4;
    #pragma unroll
    for (int n=0;n<2;n++){
      int col = colBase + wc*32 + n*16 + l15;
      float bv = bias[col];
      #pragma unroll
      for (int r=0;r<4;r++){
        int rr = row + r;
        if (rr < M){
          float v = acc[m][n][r] + bv;
          if (RESID) v += resid[(size_t)rr*N + col];
          Cf[(size_t)rr*N + col] = v;
        }
      }
    }
  }
}

// ---- fused attention pooling conv for q,k,v (one launch) + LN over 96.
// Reads the LINEAR qkv buffer [b*NTOK+tok][2304] (col = z*768 + h*96 + d).
// R8: ho==14 plane (96 aux blocks) absorbs cls3 + padfill.
// R10: conv weights preloaded to LDS (10.4KB) — replaces 162 scattered 4B global
// loads/thread with conflict-free LDS reads; barrier placed BEFORE idle-thread exit.
__global__ __launch_bounds__(256, 2) void pool_conv3(
    const short* __restrict__ raw,
    const float* __restrict__ cwq, const float* __restrict__ cwk, const float* __restrict__ cwv,
    const float* __restrict__ nqw, const float* __restrict__ nqb,
    const float* __restrict__ nkw, const float* __restrict__ nkb,
    const float* __restrict__ nvw, const float* __restrict__ nvb,
    short* __restrict__ qo, short* __restrict__ ko, short* __restrict__ vo){
  unsigned nwg = gridDim.x * gridDim.y * gridDim.z;   // 32*15*3 = 1440
  unsigned lin = (blockIdx.z*gridDim.y + blockIdx.y)*gridDim.x + blockIdx.x;
  unsigned serial = xcd_serial(lin, nwg);
  int ho = (int)(serial % 15);
  unsigned rest = serial / 15;
  int bh = (int)(rest & 31);
  int z  = (int)(rest >> 5);
  int t = threadIdx.x;
  const float* nw = (z==0) ? nqw : (z==1) ? nkw : nvw;
  const float* nb = (z==0) ? nqb : (z==1) ? nkb : nvb;

  if (ho == 14){
    // --- aux block: cls-token LN + pad-fill for this (bh, z); whole block returns ---
    if (t < 16){
      int s2 = t, d2 = s2*6;
      const short* row = raw + (size_t)(bh>>3)*NTOK*2304 + z*768 + (bh&7)*96 + d2;
      u32x3 u = *(const u32x3*)(row);
      float a[6] = { bfsel(u[0],0), bfsel(u[0],1), bfsel(u[1],0), bfsel(u[1],1), bfsel(u[2],0), bfsel(u[2],1) };
      float sm = a[0]+a[1]+a[2]+a[3]+a[4]+a[5];
      #pragma unroll
      for (int m=1; m<16; m<<=1) sm += __shfl_xor(sm, m);
      float mu = sm*(1.f/96.f);
      float vr2 = 0.f;
      #pragma unroll
      for (int j=0;j<6;j++){ float dd = a[j]-mu; vr2 += dd*dd; }
      #pragma unroll
      for (int m=1; m<16; m<<=1) vr2 += __shfl_xor(vr2, m);
      float rstd = rsqrtf(vr2*(1.f/96.f) + 1e-5f);
      #pragma unroll
      for (int j=0;j<6;j++){
        int dj = d2 + j;
        short o = f2bf((a[j]-mu)*rstd*nw[dj] + nb[dj]);
        if (z == 0)      qo[((size_t)bh*NPAD)*96 + dj] = o;
        else if (z == 1) ko[(size_t)bh*NPAD*96 + (dj>>5)*512 + ((dj>>3)&3)*128 + (dj&7)] = o;
        else             vo[(size_t)bh*NPAD*96 + (dj>>4)*1024 + (dj&15)*4] = o;
      }
    }
    for (int i = t; i < 31*96; i += 256){
      int tok = NPOOL + i/96;
      int dd = i - (i/96)*96;
      if (z == 0) qo[((size_t)bh*NPAD + tok)*96 + dd] = 0;
      else if (z == 1){
        size_t kb = (size_t)bh*NPAD*96 + (size_t)(tok>>4)*1536 + (tok&15)*8;
        ko[kb + (dd>>5)*512 + ((dd>>3)&3)*128 + (dd&7)] = 0;
      } else {
        size_t vb = (size_t)bh*NPAD*96 + (size_t)(tok>>6)*6144 + ((tok>>4)&3)*256 + ((tok>>2)&3)*64 + (tok&3);
        vo[vb + (dd>>4)*1024 + (dd&15)*4] = 0;
      }
    }
    return;
  }

  // --- main block: preload this z's conv weights to LDS (all 256 threads reach barrier) ---
  __shared__ float wlds[2592];   // 96 d x 27 taps, layout [d*27 + tap]
  {
    const float* cw = (z==0) ? cwq : (z==1) ? cwk : cwv;
    for (int i = t; i < 2592; i += 256) wlds[i] = cw[i];
  }
  __syncthreads();

  int g = t >> 4;        // wo
  if (g >= 14) return;
  int s = t & 15, d = s*6;
  const short* base = raw + (size_t)(bh>>3)*NTOK*2304 + z*768 + (bh&7)*96 + d;
  float acc[8][6] = {};
  #pragma unroll
  for (int dh=0; dh<3; dh++){
    int ih = 2*ho - 1 + dh;
    if (ih < 0 || ih >= 28) continue;
    #pragma unroll
    for (int dw=0; dw<3; dw++){
      int iw = 2*g - 1 + dw;
      if (iw < 0 || iw >= 28) continue;
      float w[3][6];
      #pragma unroll
      for (int dt=0; dt<3; dt++)
        #pragma unroll
        for (int j=0;j<6;j++)
          w[dt][j] = wlds[(d+j)*27 + dt*9 + dh*3 + dw];
      #pragma unroll
      for (int it=0; it<8; it++){
        u32x3 u = *(const u32x3*)(base + (size_t)(1 + (it*28+ih)*28 + iw)*2304);
        float in[6] = { bfsel(u[0],0), bfsel(u[0],1), bfsel(u[1],0),
                        bfsel(u[1],1), bfsel(u[2],0), bfsel(u[2],1) };
        #pragma unroll
        for (int dt=0; dt<3; dt++){
          int to = it + 1 - dt;                // compile-time per unrolled iter
          if (to < 0 || to > 7) continue;
          #pragma unroll
          for (int j=0;j<6;j++) acc[to][j] = fmaf(in[j], w[dt][j], acc[to][j]);
        }
      }
    }
  }
  float nwv[6], nbv[6];
  #pragma unroll
  for (int j=0;j<6;j++){ nwv[j] = nw[d+j]; nbv[j] = nb[d+j]; }
  #pragma unroll
  for (int to=0; to<8; to++){
    float sm = acc[to][0]+acc[to][1]+acc[to][2]+acc[to][3]+acc[to][4]+acc[to][5];
    #pragma unroll
    for (int m=1; m<16; m<<=1) sm += __shfl_xor(sm, m);
    float mu = sm*(1.f/96.f);
    float vr = 0.f;
    #pragma unroll
    for (int j=0;j<6;j++){ float dd = acc[to][j]-mu; vr += dd*dd; }
    #pragma unroll
    for (int m=1; m<16; m<<=1) vr += __shfl_xor(vr, m);
    float rstd = rsqrtf(vr*(1.f/96.f) + 1e-5f);
    int tok = 1 + to*196 + ho*14 + g;
    if (z == 0){
      short o[6];
      #pragma unroll
      for (int j=0;j<6;j++) o[j] = f2bf((acc[to][j]-mu)*rstd*nwv[j] + nbv[j]);
      unsigned* q32 = (unsigned*)(qo + ((size_t)bh*NPAD + tok)*96 + d);
      #pragma unroll
      for (int w2=0; w2<3; w2++)
        q32[w2] = (unsigned)(unsigned short)o[2*w2] | ((unsigned)(unsigned short)o[2*w2+1] << 16);
    } else if (z == 1){
      size_t kb = (size_t)bh*NPAD*96 + (size_t)(tok>>4)*1536 + (tok&15)*8;
      #pragma unroll
      for (int j=0;j<6;j++){
        int dj = d + j;
        ko[kb + (dj>>5)*512 + ((dj>>3)&3)*128 + (dj&7)] = f2bf((acc[to][j]-mu)*rstd*nwv[j] + nbv[j]);
      }
    } else {
      size_t vb = (size_t)bh*NPAD*96 + (size_t)(tok>>6)*6144 + ((tok>>4)&3)*256 + ((tok>>2)&3)*64 + (tok&3);
      #pragma unroll
      for (int j=0;j<6;j++){
        int dj = d + j;
        vo[vb + (dj>>4)*1024 + (dj&15)*4] = f2bf((acc[to][j]-mu)*rstd*nwv[j] + nbv[j]);
      }
    }
  }
}

// ---- flash attention, 8 waves/block (128 q-rows).
// XCD mapping: bh-major chunks -> each XCD owns exactly 4 bh; K/V L2-resident.
// R10: s_setprio around MFMA clusters (T5/m191: applies to attn — 3 independent
// blocks/CU at different phases give the scheduler something to arbitrate).
__global__ __launch_bounds__(512) void attn_k(const short* __restrict__ qp, const short* __restrict__ kp,
                       const short* __restrict__ vp, short* __restrict__ oattn){
  const float M0 = 6.0f;
  __shared__ short lkv[2][12288];   // [buf][ K:0..6143 | V:6144..12287 ]
  unsigned nwg = gridDim.x * gridDim.y;   // 13*32 = 416
  unsigned bid0 = blockIdx.y * gridDim.x + blockIdx.x;
  unsigned serial = xcd_serial(bid0, nwg);
  int bh = (int)(serial / 13);
  int qblk = (int)(serial - (unsigned)bh*13);
  int b = bh >> 3, h = bh & 7;
  int tid = threadIdx.x;
  int lane = tid & 63, wv = tid >> 6;
  int l15 = lane & 15, g = lane >> 4;
  int qi = qblk*128 + wv*16 + l15;
  int qi_ld = qi < NPAD ? qi : NPAD-1;        // clamp; pad rows are zeroed, writes masked below
  const short* qbase = qp + (size_t)bh*NPAD*HD;
  const short* kbase = kp + (size_t)bh*NPAD*HD;
  const short* vbase = vp + (size_t)bh*NPAD*HD;
  s16x8 qf[3];
  #pragma unroll
  for (int f=0; f<3; f++)
    qf[f] = *(const s16x8*)(qbase + (size_t)qi_ld*HD + f*32 + g*8);

  // stage chunk t: 12288 shorts (K 6144 | V 6144); 512 threads x 3 gld16, wave-uniform K/V branch
  auto stage = [&](int bsel, int t){
    #pragma unroll
    for (int i=0;i<3;i++){
      int off = i*4096 + tid*8;
      const short* src = (off < 6144) ? (kbase + t*6144 + off) : (vbase + t*6144 + off - 6144);
      gld16(src, &lkv[bsel][off]);
    }
  };

  f32x4 accO[6] = {};
  float tsum = 0.f;

  stage(0, 0);
  asm volatile("s_waitcnt vmcnt(0)" ::: "memory");
  __builtin_amdgcn_s_barrier();

  for (int kt = 0; kt < 25; kt++){
    int cur = kt & 1;
    if (kt < 24){
      stage(cur^1, kt+1);
      asm volatile("s_waitcnt vmcnt(3)" ::: "memory");   // current chunk done; next 3 in flight
    } else {
      asm volatile("s_waitcnt vmcnt(0)" ::: "memory");
    }
    __builtin_amdgcn_s_barrier();

    const short* lkc = &lkv[cur][0];
    const short* lvc = &lkv[cur][6144];
    f32x4 sacc[4];
    __builtin_amdgcn_s_setprio(1);
    #pragma unroll
    for (int sub=0; sub<4; sub++){
      sacc[sub] = (f32x4){0.f,0.f,0.f,0.f};
      #pragma unroll
      for (int f=0; f<3; f++){
        s16x8 kf = *(const s16x8*)(lkc + sub*1536 + f*512 + lane*8);
        sacc[sub] = __builtin_amdgcn_mfma_f32_16x16x32_bf16(kf, qf[f], sacc[sub], 0,0,0);
      }
    }
    __builtin_amdgcn_s_setprio(0);
    s16x4 pf[4];
    if (kt < 24){
      #pragma unroll
      for (int sub=0; sub<4; sub++){
        #pragma unroll
        for (int r=0; r<4; r++){
          float p = __expf(sacc[sub][r]*SCALE_ - M0);
          tsum += p;
          pf[sub][r] = f2bf(p);
        }
      }
    } else {
      #pragma unroll
      for (int sub=0; sub<4; sub++){
        #pragma unroll
        for (int r=0; r<4; r++){
          int ki = kt*64 + sub*16 + g*4 + r;
          float p = (ki < NPOOL) ? __expf(sacc[sub][r]*SCALE_ - M0) : 0.f;
          tsum += p;
          pf[sub][r] = f2bf(p);
        }
      }
    }
    __builtin_amdgcn_s_setprio(1);
    #pragma unroll
    for (int dt=0; dt<6; dt++){
      #pragma unroll
      for (int sub=0; sub<4; sub++){
        s16x4 vf = *(const s16x4*)(lvc + dt*1024 + sub*256 + lane*4);
        accO[dt] = MFMA16K(vf, pf[sub], accO[dt]);
      }
    }
    __builtin_amdgcn_s_setprio(0);
    __builtin_amdgcn_s_barrier();
  }

  tsum += __shfl_xor(tsum, 16);
  tsum += __shfl_xor(tsum, 32);
  if (qi < NPOOL){
    float inv = 1.f / tsum;
    #pragma unroll
    for (int dt=0; dt<6; dt++){
      #pragma unroll
      for (int r=0; r<4; r++){
        int dd = dt*16 + g*4 + r;
        oattn[((size_t)b*NPOOL + qi)*DIMD + h*96 + dd] = f2bf(accO[dt][r] * inv);
      }
    }
  }
}

// ---- maxpool(3x3/s2) skip + proj-out add + LN2 (R8: wave-per-token, ZERO barriers) ----
__global__ __launch_bounds__(256) void skip_ln2(const float* __restrict__ x, const float* __restrict__ oproj,
                         const float* __restrict__ w, const float* __restrict__ bb,
                         float* __restrict__ x2, short* __restrict__ xn2){
  unsigned serial = xcd_serial(blockIdx.x, gridDim.x);   // 1569 blocks x 4 tokens = 6276
  int ti = (int)serial*4 + (int)(threadIdx.x >> 6);
  int b = ti / NPOOL;
  int tok = ti - b*NPOOL;
  int lane = threadIdx.x & 63;
  int c0 = lane*12;
  float v[12];
  if (tok == 0){
    const float* xr = x + (size_t)b*NTOK*DIMD + c0;
    f32x4 a0 = *(const f32x4*)xr, a1 = *(const f32x4*)(xr+4), a2 = *(const f32x4*)(xr+8);
    #pragma unroll
    for (int j=0;j<4;j++){ v[j]=a0[j]; v[4+j]=a1[j]; v[8+j]=a2[j]; }
  } else {
    int ot = tok - 1;
    int to = ot/196, rem = ot%196, ho = rem/14, wo = rem%14;
    #pragma unroll
    for (int j=0;j<12;j++) v[j] = -INFINITY;
    #pragma unroll
    for (int dh=0; dh<3; dh++){
      int ih = 2*ho - 1 + dh; if (ih < 0 || ih >= 28) continue;
      #pragma unroll
      for (int dw=0; dw<3; dw++){
        int iw = 2*wo - 1 + dw; if (iw < 0 || iw >= 28) continue;
        const float* xr = x + ((size_t)b*NTOK + 1 + (to*28 + ih)*28 + iw)*DIMD + c0;
        f32x4 a0 = *(const f32x4*)xr, a1 = *(const f32x4*)(xr+4), a2 = *(const f32x4*)(xr+8);
        #pragma unroll
        for (int j=0;j<4;j++){
          v[j]   = fmaxf(v[j],   a0[j]);
          v[4+j] = fmaxf(v[4+j], a1[j]);
          v[8+j] = fmaxf(v[8+j], a2[j]);
        }
      }
    }
  }
  const float* opr = oproj + ((size_t)b*NPOOL + tok)*DIMD + c0;
  f32x4 p0 = *(const f32x4*)opr, p1 = *(const f32x4*)(opr+4), p2 = *(const f32x4*)(opr+8);
  #pragma unroll
  for (int j=0;j<4;j++){ v[j]+=p0[j]; v[4+j]+=p1[j]; v[8+j]+=p2[j]; }
  float* x2r = x2 + ((size_t)b*NPOOL + tok)*DIMD + c0;
  f32x4 o0 = {v[0],v[1],v[2],v[3]}, o1 = {v[4],v[5],v[6],v[7]}, o2 = {v[8],v[9],v[10],v[11]};
  *(f32x4*)x2r = o0; *(f32x4*)(x2r+4) = o1; *(f32x4*)(x2r+8) = o2;
  float s = 0.f;
  #pragma unroll
  for (int j=0;j<12;j++) s += v[j];
  #pragma unroll
  for (int m=1; m<64; m<<=1) s += __shfl_xor(s, m);
  float mu = s * (1.f/768.f);
  float sq = 0.f;
  #pragma unroll
  for (int j=0;j<12;j++){ float d = v[j]-mu; sq += d*d; }
  #pragma unroll
  for (int m=1; m<64; m<<=1) sq += __shfl_xor(sq, m);
  float rstd = rsqrtf(sq*(1.f/768.f) + 1e-5f);
  float o[12];
  #pragma unroll
  for (int j=0;j<12;j++) o[j] = (v[j]-mu)*rstd*w[c0+j] + bb[c0+j];
  unsigned* po = (unsigned*)(xn2 + ((size_t)b*NPOOL + tok)*DIMD + c0);
  #pragma unroll
  for (int k=0;k<6;k++) po[k] = pack2(o[2*k], o[2*k+1]);
}

extern "C" void kernel_launch(void* const* d_in, const int* in_sizes, int n_in,
                              void* d_out, int out_size, void* d_ws, size_t ws_size,
                              hipStream_t stream){
  (void)in_sizes; (void)n_in; (void)out_size; (void)ws_size;
  const float* x      = (const float*)d_in[0];
  const float* n1_w   = (const float*)d_in[1];
  const float* n1_b   = (const float*)d_in[2];
  const float* wq     = (const float*)d_in[3];
  const float* bq     = (const float*)d_in[4];
  const float* wk     = (const float*)d_in[5];
  const float* bk     = (const float*)d_in[6];
  const float* wv     = (const float*)d_in[7];
  const float* bv     = (const float*)d_in[8];
  const float* pq_w   = (const float*)d_in[9];
  const float* pk_w   = (const float*)d_in[10];
  const float* pv_w   = (const float*)d_in[11];
  const float* nq_w   = (const float*)d_in[12];
  const float* nq_b   = (const float*)d_in[13];
  const float* nk_w   = (const float*)d_in[14];
  const float* nk_b   = (const float*)d_in[15];
  const float* nv_w   = (const float*)d_in[16];
  const float* nv_b   = (const float*)d_in[17];
  const float* proj_w = (const float*)d_in[18];
  const float* proj_b = (const float*)d_in[19];
  const float* n2_w   = (const float*)d_in[20];
  const float* n2_b   = (const float*)d_in[21];
  const float* fc1_w  = (const float*)d_in[22];
  const float* fc1_b  = (const float*)d_in[23];
  const float* fc2_w  = (const float*)d_in[24];
  const float* fc2_b  = (const float*)d_in[25];
  float* out = (float*)d_out;

  char* ws = (char*)d_ws;
  size_t off = 0;
  auto take = [&](size_t bytes)->char*{
    char* p = ws + off; off = (off + bytes + 255) & ~(size_t)255; return p;
  };
  short* xn  = (short*)take(38541312);       // 25092*768 bf16
  short* wqb = (short*)take(1179648);        // wqb/wkb/wvb contiguous -> one [2304][768] matrix
  short* wkb = (short*)take(1179648);
  short* wvb = (short*)take(1179648);
  short* wpb = (short*)take(1179648);
  short* w1b = (short*)take(4718592);
  short* w2b = (short*)take(4718592);
  float* bcat= (float*)take(9216);           // packed [bq|bk|bv]
  char*  big = take(115623936);              // phase1: linear qkv [25092][2304]; phase2: oattn/oproj/x2/xn2/h1
  short* qkv  = (short*)(big);               // 115623936 B exactly
  short* oattn= (short*)(big);               // 9639936 B
  float* oproj= (float*)(big + 9639936);     // 19279872 B
  float* x2   = (float*)(big + 28919808);    // 19279872 B
  short* xn2  = (short*)(big + 48199680);    // 9639936 B
  short* h1   = (short*)(big + 57839616);    // 38559744 B
  short* qp   = (short*)take(9830400);       // 32*1600*96 bf16
  short* kp   = (short*)take(9830400);
  short* vT   = (short*)take(9830400);

  // fused prologue: LN1 (y=0) + weight cast + bias pack (y=1)
  prologue<<<dim3(6273,2), 256, 0, stream>>>(x, n1_w, n1_b, xn,
      wq, wk, wv, proj_w, fc1_w, fc2_w, wqb, wkb, wvb, wpb, w1b, w2b,
      bq, bk, bv, bcat);

  // fused QKV: 256x256 gemm8 (R5, 144.7us proven); grid 9x99 = 891 blocks
  gemm8<<<dim3(9,99), 512, 0, stream>>>(xn, wqb, bcat, qkv, MROWS, 2304, 768);

  // pool conv + LN(96) + cls + padfill (aux ho==14 plane); weights in LDS
  pool_conv3<<<dim3(32,15,3), 256, 0, stream>>>(qkv, pq_w, pk_w, pv_w,
                                                nq_w, nq_b, nk_w, nk_b, nv_w, nv_b, qp, kp, vT);

  attn_k<<<dim3(13,32), 512, 0, stream>>>(qp, kp, vT, oattn);

  // proj: 64-row tiles, col-major order -> grid 6x99 = 594 blocks
  gemm_n64<0><<<dim3(6,99), 256, 0, stream>>>(oattn, wpb, proj_b, nullptr, oproj, M2, 768, 768);

  // maxpool skip + LN2: wave-per-token, 1569 blocks, zero barriers
  skip_ln2<<<1569, 256, 0, stream>>>(x, oproj, n2_w, n2_b, x2, xn2);

  // fc1: 50x24 tiles, supertile 10x8 (bf16 out -> wide epilogue)
  gemm_bt<1,1,0,10,8><<<dim3(24,50), 256, 0, stream>>>(xn2, w1b, fc1_b, nullptr, nullptr, h1, M2, HID, 768);
  // fc2: 64-row tiles, K=3072, col-major order
  gemm_n64<1><<<dim3(6,99), 256, 0, stream>>>(h1, w2b, fc2_b, x2, out, M2, 768, 3072);
}